// Round 1
// baseline (694.722 us; speedup 1.0000x reference)
//
#include <hip/hip_runtime.h>
#include <hip/hip_bf16.h>

using bf16 = __hip_bfloat16;
typedef __attribute__((ext_vector_type(8))) short bf16x8;
typedef __attribute__((ext_vector_type(4))) float f32x4;

#define D_MODEL 1024
#define NHEAD 16
#define HEAD_DIM 64
#define D_FF 4096
#define SEQ 2048
#define NTOK 8192  // 4 * 2048

__device__ __forceinline__ void gload16(const void* g, void* l) {
  __builtin_amdgcn_global_load_lds((const __attribute__((address_space(1))) void*)g,
                                   (__attribute__((address_space(3))) void*)l, 16, 0, 0);
}

// ---------------------------------------------------------------------------
// f32 -> bf16 conversion (weights)
// ---------------------------------------------------------------------------
__global__ void cvt_f32_bf16(const float* __restrict__ in, bf16* __restrict__ out, int n) {
  int i = (blockIdx.x * 256 + threadIdx.x) * 4;
  if (i >= n) return;
  const float4 v = *(const float4*)&in[i];
  out[i + 0] = __float2bfloat16(v.x);
  out[i + 1] = __float2bfloat16(v.y);
  out[i + 2] = __float2bfloat16(v.z);
  out[i + 3] = __float2bfloat16(v.w);
}

// ---------------------------------------------------------------------------
// LayerNorm over D=1024, fp32 in -> bf16 out. One block (256 thr) per row.
// ---------------------------------------------------------------------------
__global__ __launch_bounds__(256) void layernorm_kernel(
    const float* __restrict__ xin, const float* __restrict__ g,
    const float* __restrict__ bta, bf16* __restrict__ out) {
  const int row = blockIdx.x, t = threadIdx.x;
  const float4 v = *(const float4*)&xin[(size_t)row * D_MODEL + t * 4];
  float s = v.x + v.y + v.z + v.w;
#pragma unroll
  for (int m = 1; m < 64; m <<= 1) s += __shfl_xor(s, m);
  __shared__ float red[4], red2[4];
  const int w = t >> 6, l = t & 63;
  if (l == 0) red[w] = s;
  __syncthreads();
  const float mu = (red[0] + red[1] + red[2] + red[3]) * (1.f / 1024.f);
  const float d0 = v.x - mu, d1 = v.y - mu, d2 = v.z - mu, d3 = v.w - mu;
  float q = d0 * d0 + d1 * d1 + d2 * d2 + d3 * d3;
#pragma unroll
  for (int m = 1; m < 64; m <<= 1) q += __shfl_xor(q, m);
  if (l == 0) red2[w] = q;
  __syncthreads();
  const float var = (red2[0] + red2[1] + red2[2] + red2[3]) * (1.f / 1024.f);
  const float rs = rsqrtf(var + 1e-5f);
  const float4 gg = *(const float4*)&g[t * 4];
  const float4 bb = *(const float4*)&bta[t * 4];
  bf16* o = out + (size_t)row * D_MODEL + t * 4;
  o[0] = __float2bfloat16(d0 * rs * gg.x + bb.x);
  o[1] = __float2bfloat16(d1 * rs * gg.y + bb.y);
  o[2] = __float2bfloat16(d2 * rs * gg.z + bb.z);
  o[3] = __float2bfloat16(d3 * rs * gg.w + bb.w);
}

// ---------------------------------------------------------------------------
// GEMM-BT: C[M,N] = A[M,K] * B[N,K]^T + bias.  A,B bf16 K-contiguous.
// 128x128 tile, BK=64, 4 waves (2x2), each wave 64x64 via 4x4 16x16x32 MFMA.
// MODE 0: bf16 out, permuted to [B,H,T,Hd]   (QKV)
// MODE 1: bf16 out row-major, ReLU            (FFN1)
// MODE 2: f32 out row-major, += res           (Wo, FFN2)
// ---------------------------------------------------------------------------
template <int MODE>
__global__ __launch_bounds__(256, 2) void gemm_bt(
    const bf16* __restrict__ A, const bf16* __restrict__ B,
    const float* __restrict__ bias, const float* __restrict__ res,
    void* __restrict__ out, int M, int N, int K) {
  __shared__ bf16 As[128 * 64];
  __shared__ bf16 Bs[128 * 64];
  const int t = threadIdx.x;
  const int w = t >> 6, l = t & 63;
  const int l15 = l & 15, l4 = l >> 4;
  const int m0 = blockIdx.y * 128, n0 = blockIdx.x * 128;
  const int wr = (w >> 1) * 64, wc = (w & 1) * 64;

  f32x4 acc[4][4] = {};

  for (int kb = 0; kb < K; kb += 64) {
#pragma unroll
    for (int i = 0; i < 4; ++i) {
      const int f = i * 256 + t;
      gload16(&A[(size_t)(m0 + (f >> 3)) * K + kb + (f & 7) * 8],
              (void*)(As + (i * 256 + w * 64) * 8));
      gload16(&B[(size_t)(n0 + (f >> 3)) * K + kb + (f & 7) * 8],
              (void*)(Bs + (i * 256 + w * 64) * 8));
    }
    __syncthreads();
#pragma unroll
    for (int kk = 0; kk < 2; ++kk) {
      bf16x8 af[4], bfr[4];
#pragma unroll
      for (int mi = 0; mi < 4; ++mi)
        af[mi] = *(const bf16x8*)&As[(wr + mi * 16 + l15) * 64 + kk * 32 + l4 * 8];
#pragma unroll
      for (int ni = 0; ni < 4; ++ni)
        bfr[ni] = *(const bf16x8*)&Bs[(wc + ni * 16 + l15) * 64 + kk * 32 + l4 * 8];
#pragma unroll
      for (int mi = 0; mi < 4; ++mi)
#pragma unroll
        for (int ni = 0; ni < 4; ++ni)
          acc[mi][ni] = __builtin_amdgcn_mfma_f32_16x16x32_bf16(af[mi], bfr[ni], acc[mi][ni], 0, 0, 0);
    }
    __syncthreads();
  }

#pragma unroll
  for (int mi = 0; mi < 4; ++mi) {
#pragma unroll
    for (int ni = 0; ni < 4; ++ni) {
      const int col = n0 + wc + ni * 16 + l15;
      const float bb = bias[col];
#pragma unroll
      for (int r = 0; r < 4; ++r) {
        const int row = m0 + wr + mi * 16 + l4 * 4 + r;
        float y = acc[mi][ni][r] + bb;
        if constexpr (MODE == 1) y = fmaxf(y, 0.f);
        if constexpr (MODE == 2) {
          y += res[(size_t)row * N + col];
          ((float*)out)[(size_t)row * N + col] = y;
        } else if constexpr (MODE == 0) {
          // [M=b*2048+t, N=h*64+hd] -> [B,H,T,Hd]
          const size_t dst = (size_t)((row >> 11) * NHEAD + (col >> 6)) * (SEQ * HEAD_DIM) +
                             (size_t)(row & (SEQ - 1)) * HEAD_DIM + (col & 63);
          ((bf16*)out)[dst] = __float2bfloat16(y);
        } else {
          ((bf16*)out)[(size_t)row * N + col] = __float2bfloat16(y);
        }
      }
    }
  }
}

// ---------------------------------------------------------------------------
// Flash attention. Q,K,V: [B,H,T,64] bf16. O: [B,T,1024] bf16 (t-major).
// Block = 4 waves, each wave owns 16 q-rows; K/V tiles of 64 staged in LDS.
// ---------------------------------------------------------------------------
__global__ __launch_bounds__(256, 2) void flash_attn(
    const bf16* __restrict__ Q, const bf16* __restrict__ K,
    const bf16* __restrict__ V, bf16* __restrict__ O) {
  __shared__ bf16 Klds[64 * 64];      // [k][d]
  __shared__ bf16 Vt[64 * 64];        // [d][k]  (transposed at staging)
  __shared__ bf16 Plds[4][16][80];    // per-wave, padded to 160B rows

  const int t = threadIdx.x;
  const int w = t >> 6, l = t & 63;
  const int l15 = l & 15, l4 = l >> 4;
  const int bh = blockIdx.y;
  const size_t base = (size_t)bh * (SEQ * HEAD_DIM);
  const int q0 = blockIdx.x * 64 + w * 16;

  bf16x8 qf[2];
#pragma unroll
  for (int kk = 0; kk < 2; ++kk)
    qf[kk] = *(const bf16x8*)&Q[base + (size_t)(q0 + l15) * 64 + kk * 32 + l4 * 8];

  f32x4 accO[4] = {};
  float m_run[4], l_run[4];
#pragma unroll
  for (int r = 0; r < 4; ++r) { m_run[r] = -1e30f; l_run[r] = 0.f; }

  for (int kt = 0; kt < SEQ; kt += 64) {
    // stage K (async direct-to-LDS)
#pragma unroll
    for (int i = 0; i < 2; ++i) {
      const int f = i * 256 + t;
      gload16(&K[base + (size_t)(kt + (f >> 3)) * 64 + (f & 7) * 8],
              (void*)(Klds + (i * 256 + w * 64) * 8));
    }
    // stage V transposed
#pragma unroll
    for (int i = 0; i < 2; ++i) {
      const int f = i * 256 + t;
      const int r = f >> 3, c0 = (f & 7) * 8;
      bf16x8 vv = *(const bf16x8*)&V[base + (size_t)(kt + r) * 64 + c0];
#pragma unroll
      for (int j = 0; j < 8; ++j) Vt[(c0 + j) * 64 + r] = ((const bf16*)&vv)[j];
    }
    __syncthreads();

    // S = Q K^T  (16x64 per wave)
    f32x4 s[4] = {};
#pragma unroll
    for (int kk = 0; kk < 2; ++kk) {
#pragma unroll
      for (int ni = 0; ni < 4; ++ni) {
        bf16x8 kf = *(const bf16x8*)&Klds[(ni * 16 + l15) * 64 + kk * 32 + l4 * 8];
        s[ni] = __builtin_amdgcn_mfma_f32_16x16x32_bf16(qf[kk], kf, s[ni], 0, 0, 0);
      }
    }
#pragma unroll
    for (int ni = 0; ni < 4; ++ni) s[ni] *= 0.125f;  // Hd^-0.5

    // online softmax (row stats live in the 16-lane group, rows l4*4+r)
    float mx[4];
#pragma unroll
    for (int r = 0; r < 4; ++r)
      mx[r] = fmaxf(fmaxf(s[0][r], s[1][r]), fmaxf(s[2][r], s[3][r]));
#pragma unroll
    for (int msk = 1; msk < 16; msk <<= 1)
#pragma unroll
      for (int r = 0; r < 4; ++r) mx[r] = fmaxf(mx[r], __shfl_xor(mx[r], msk));
    float corr[4];
#pragma unroll
    for (int r = 0; r < 4; ++r) {
      const float mn = fmaxf(m_run[r], mx[r]);
      corr[r] = __expf(m_run[r] - mn);
      m_run[r] = mn;
    }
    float ps[4] = {0.f, 0.f, 0.f, 0.f};
#pragma unroll
    for (int ni = 0; ni < 4; ++ni)
#pragma unroll
      for (int r = 0; r < 4; ++r) {
        const float p = __expf(s[ni][r] - m_run[r]);
        s[ni][r] = p;
        ps[r] += p;
      }
#pragma unroll
    for (int msk = 1; msk < 16; msk <<= 1)
#pragma unroll
      for (int r = 0; r < 4; ++r) ps[r] += __shfl_xor(ps[r], msk);
#pragma unroll
    for (int r = 0; r < 4; ++r) l_run[r] = l_run[r] * corr[r] + ps[r];
#pragma unroll
    for (int n = 0; n < 4; ++n)
#pragma unroll
      for (int r = 0; r < 4; ++r) accO[n][r] *= corr[r];

    // P: C-layout -> A-layout via per-wave LDS round-trip
#pragma unroll
    for (int ni = 0; ni < 4; ++ni)
#pragma unroll
      for (int r = 0; r < 4; ++r)
        Plds[w][l4 * 4 + r][ni * 16 + l15] = __float2bfloat16(s[ni][r]);
    asm volatile("s_waitcnt lgkmcnt(0)" ::: "memory");

    // O += P V
#pragma unroll
    for (int kk = 0; kk < 2; ++kk) {
      bf16x8 pf = *(const bf16x8*)&Plds[w][l15][kk * 32 + l4 * 8];
#pragma unroll
      for (int n = 0; n < 4; ++n) {
        bf16x8 vf = *(const bf16x8*)&Vt[(n * 16 + l15) * 64 + kk * 32 + l4 * 8];
        accO[n] = __builtin_amdgcn_mfma_f32_16x16x32_bf16(pf, vf, accO[n], 0, 0, 0);
      }
    }
    __syncthreads();
  }

  const int b = bh >> 4, h = bh & 15;
#pragma unroll
  for (int n = 0; n < 4; ++n)
#pragma unroll
    for (int r = 0; r < 4; ++r) {
      const size_t row = (size_t)b * SEQ + q0 + l4 * 4 + r;
      O[row * D_MODEL + h * HEAD_DIM + n * 16 + l15] =
          __float2bfloat16(accO[n][r] / l_run[r]);
    }
}

// ---------------------------------------------------------------------------
extern "C" void kernel_launch(void* const* d_in, const int* in_sizes, int n_in,
                              void* d_out, int out_size, void* d_ws, size_t ws_size,
                              hipStream_t stream) {
  const float* x     = (const float*)d_in[0];
  const float* Wq    = (const float*)d_in[1];
  const float* bq    = (const float*)d_in[2];
  const float* Wk    = (const float*)d_in[3];
  const float* bk    = (const float*)d_in[4];
  const float* Wv    = (const float*)d_in[5];
  const float* bv    = (const float*)d_in[6];
  const float* Wo    = (const float*)d_in[7];
  const float* bo    = (const float*)d_in[8];
  const float* W1    = (const float*)d_in[9];
  const float* b1    = (const float*)d_in[10];
  const float* W2    = (const float*)d_in[11];
  const float* b2    = (const float*)d_in[12];
  const float* ln1_g = (const float*)d_in[13];
  const float* ln1_b = (const float*)d_in[14];
  const float* ln2_g = (const float*)d_in[15];
  const float* ln2_b = (const float*)d_in[16];

  const size_t MB = 1ull << 20;
  char* ws = (char*)d_ws;
  bf16* wq_b = (bf16*)(ws + 0 * MB);
  bf16* wk_b = (bf16*)(ws + 2 * MB);
  bf16* wv_b = (bf16*)(ws + 4 * MB);
  bf16* wo_b = (bf16*)(ws + 6 * MB);
  bf16* w1_b = (bf16*)(ws + 8 * MB);    // 8 MB
  bf16* w2_b = (bf16*)(ws + 16 * MB);   // 8 MB
  bf16* xn   = (bf16*)(ws + 24 * MB);   // 16 MB: xn / attn_out / xn2
  bf16* qb   = (bf16*)(ws + 40 * MB);   // 16 MB
  bf16* kbuf = (bf16*)(ws + 56 * MB);   // 16 MB
  bf16* vb   = (bf16*)(ws + 72 * MB);   // 16 MB
  bf16* hb   = (bf16*)(ws + 40 * MB);   // 64 MB (reuses q/k/v after attention)
  float* x1  = (float*)(ws + 104 * MB); // 32 MB

  // weight conversions
  cvt_f32_bf16<<<1024, 256, 0, stream>>>(Wq, wq_b, 1048576);
  cvt_f32_bf16<<<1024, 256, 0, stream>>>(Wk, wk_b, 1048576);
  cvt_f32_bf16<<<1024, 256, 0, stream>>>(Wv, wv_b, 1048576);
  cvt_f32_bf16<<<1024, 256, 0, stream>>>(Wo, wo_b, 1048576);
  cvt_f32_bf16<<<4096, 256, 0, stream>>>(W1, w1_b, 4194304);
  cvt_f32_bf16<<<4096, 256, 0, stream>>>(W2, w2_b, 4194304);

  // LN1
  layernorm_kernel<<<NTOK, 256, 0, stream>>>(x, ln1_g, ln1_b, xn);

  // QKV (permuted to [B,H,T,Hd])
  dim3 g1024(1024 / 128, NTOK / 128);
  gemm_bt<0><<<g1024, 256, 0, stream>>>(xn, wq_b, bq, nullptr, qb,   NTOK, 1024, 1024);
  gemm_bt<0><<<g1024, 256, 0, stream>>>(xn, wk_b, bk, nullptr, kbuf, NTOK, 1024, 1024);
  gemm_bt<0><<<g1024, 256, 0, stream>>>(xn, wv_b, bv, nullptr, vb,   NTOK, 1024, 1024);

  // attention -> xn (as [B,T,D] bf16)
  flash_attn<<<dim3(SEQ / 64, 4 * NHEAD), 256, 0, stream>>>(qb, kbuf, vb, xn);

  // Wo + residual(x) -> x1 (fp32)
  gemm_bt<2><<<g1024, 256, 0, stream>>>(xn, wo_b, bo, x, x1, NTOK, 1024, 1024);

  // LN2 -> xn
  layernorm_kernel<<<NTOK, 256, 0, stream>>>(x1, ln2_g, ln2_b, xn);

  // FFN1 (ReLU) -> hb
  gemm_bt<1><<<dim3(D_FF / 128, NTOK / 128), 256, 0, stream>>>(xn, w1_b, b1, nullptr, hb, NTOK, D_FF, 1024);

  // FFN2 + residual(x1) -> d_out (fp32)
  gemm_bt<2><<<g1024, 256, 0, stream>>>(hb, w2_b, b2, x1, d_out, NTOK, 1024, D_FF);
}

// Round 2
// 565.460 us; speedup vs baseline: 1.2286x; 1.2286x over previous
//
#include <hip/hip_runtime.h>
#include <hip/hip_bf16.h>

using bf16 = __hip_bfloat16;
typedef __attribute__((ext_vector_type(8))) short bf16x8;
typedef __attribute__((ext_vector_type(4))) float f32x4;

#define D_MODEL 1024
#define NHEAD 16
#define HEAD_DIM 64
#define D_FF 4096
#define SEQ 2048
#define NTOK 8192  // 4 * 2048

__device__ __forceinline__ void gload16(const void* g, void* l) {
  __builtin_amdgcn_global_load_lds((const __attribute__((address_space(1))) void*)g,
                                   (__attribute__((address_space(3))) void*)l, 16, 0, 0);
}

// DPP max-reduce over the 16-lane group (quad xor1, xor2, then ror4, ror8)
template <int CTRL>
__device__ __forceinline__ float dppmaxf(float x) {
  int y = __builtin_amdgcn_update_dpp(0, __float_as_int(x), CTRL, 0xF, 0xF, true);
  return fmaxf(x, __int_as_float(y));
}
__device__ __forceinline__ float red_max16(float x) {
  x = dppmaxf<0xB1>(x);   // quad_perm [1,0,3,2]  (xor 1)
  x = dppmaxf<0x4E>(x);   // quad_perm [2,3,0,1]  (xor 2)
  x = dppmaxf<0x124>(x);  // row_ror:4
  x = dppmaxf<0x128>(x);  // row_ror:8
  return x;
}

// ---------------------------------------------------------------------------
// f32 -> bf16 conversion (weights)
// ---------------------------------------------------------------------------
__global__ void cvt_f32_bf16(const float* __restrict__ in, bf16* __restrict__ out, int n) {
  int i = (blockIdx.x * 256 + threadIdx.x) * 4;
  if (i >= n) return;
  const float4 v = *(const float4*)&in[i];
  out[i + 0] = __float2bfloat16(v.x);
  out[i + 1] = __float2bfloat16(v.y);
  out[i + 2] = __float2bfloat16(v.z);
  out[i + 3] = __float2bfloat16(v.w);
}

// ---------------------------------------------------------------------------
// LayerNorm over D=1024, fp32 in -> bf16 out. One block (256 thr) per row.
// ---------------------------------------------------------------------------
__global__ __launch_bounds__(256) void layernorm_kernel(
    const float* __restrict__ xin, const float* __restrict__ g,
    const float* __restrict__ bta, bf16* __restrict__ out) {
  const int row = blockIdx.x, t = threadIdx.x;
  const float4 v = *(const float4*)&xin[(size_t)row * D_MODEL + t * 4];
  float s = v.x + v.y + v.z + v.w;
#pragma unroll
  for (int m = 1; m < 64; m <<= 1) s += __shfl_xor(s, m);
  __shared__ float red[4], red2[4];
  const int w = t >> 6, l = t & 63;
  if (l == 0) red[w] = s;
  __syncthreads();
  const float mu = (red[0] + red[1] + red[2] + red[3]) * (1.f / 1024.f);
  const float d0 = v.x - mu, d1 = v.y - mu, d2 = v.z - mu, d3 = v.w - mu;
  float q = d0 * d0 + d1 * d1 + d2 * d2 + d3 * d3;
#pragma unroll
  for (int m = 1; m < 64; m <<= 1) q += __shfl_xor(q, m);
  if (l == 0) red2[w] = q;
  __syncthreads();
  const float var = (red2[0] + red2[1] + red2[2] + red2[3]) * (1.f / 1024.f);
  const float rs = rsqrtf(var + 1e-5f);
  const float4 gg = *(const float4*)&g[t * 4];
  const float4 bb = *(const float4*)&bta[t * 4];
  bf16* o = out + (size_t)row * D_MODEL + t * 4;
  o[0] = __float2bfloat16(d0 * rs * gg.x + bb.x);
  o[1] = __float2bfloat16(d1 * rs * gg.y + bb.y);
  o[2] = __float2bfloat16(d2 * rs * gg.z + bb.z);
  o[3] = __float2bfloat16(d3 * rs * gg.w + bb.w);
}

// ---------------------------------------------------------------------------
// GEMM-BT: C[M,N] = A[M,K] * B[N,K]^T + bias.  (unchanged from round 1)
// ---------------------------------------------------------------------------
template <int MODE>
__global__ __launch_bounds__(256, 2) void gemm_bt(
    const bf16* __restrict__ A, const bf16* __restrict__ B,
    const float* __restrict__ bias, const float* __restrict__ res,
    void* __restrict__ out, int M, int N, int K) {
  __shared__ bf16 As[128 * 64];
  __shared__ bf16 Bs[128 * 64];
  const int t = threadIdx.x;
  const int w = t >> 6, l = t & 63;
  const int l15 = l & 15, l4 = l >> 4;
  const int m0 = blockIdx.y * 128, n0 = blockIdx.x * 128;
  const int wr = (w >> 1) * 64, wc = (w & 1) * 64;

  f32x4 acc[4][4] = {};

  for (int kb = 0; kb < K; kb += 64) {
#pragma unroll
    for (int i = 0; i < 4; ++i) {
      const int f = i * 256 + t;
      gload16(&A[(size_t)(m0 + (f >> 3)) * K + kb + (f & 7) * 8],
              (void*)(As + (i * 256 + w * 64) * 8));
      gload16(&B[(size_t)(n0 + (f >> 3)) * K + kb + (f & 7) * 8],
              (void*)(Bs + (i * 256 + w * 64) * 8));
    }
    __syncthreads();
#pragma unroll
    for (int kk = 0; kk < 2; ++kk) {
      bf16x8 af[4], bfr[4];
#pragma unroll
      for (int mi = 0; mi < 4; ++mi)
        af[mi] = *(const bf16x8*)&As[(wr + mi * 16 + l15) * 64 + kk * 32 + l4 * 8];
#pragma unroll
      for (int ni = 0; ni < 4; ++ni)
        bfr[ni] = *(const bf16x8*)&Bs[(wc + ni * 16 + l15) * 64 + kk * 32 + l4 * 8];
#pragma unroll
      for (int mi = 0; mi < 4; ++mi)
#pragma unroll
        for (int ni = 0; ni < 4; ++ni)
          acc[mi][ni] = __builtin_amdgcn_mfma_f32_16x16x32_bf16(af[mi], bfr[ni], acc[mi][ni], 0, 0, 0);
    }
    __syncthreads();
  }

#pragma unroll
  for (int mi = 0; mi < 4; ++mi) {
#pragma unroll
    for (int ni = 0; ni < 4; ++ni) {
      const int col = n0 + wc + ni * 16 + l15;
      const float bb = bias[col];
#pragma unroll
      for (int r = 0; r < 4; ++r) {
        const int row = m0 + wr + mi * 16 + l4 * 4 + r;
        float y = acc[mi][ni][r] + bb;
        if constexpr (MODE == 1) y = fmaxf(y, 0.f);
        if constexpr (MODE == 2) {
          y += res[(size_t)row * N + col];
          ((float*)out)[(size_t)row * N + col] = y;
        } else if constexpr (MODE == 0) {
          const size_t dst = (size_t)((row >> 11) * NHEAD + (col >> 6)) * (SEQ * HEAD_DIM) +
                             (size_t)(row & (SEQ - 1)) * HEAD_DIM + (col & 63);
          ((bf16*)out)[dst] = __float2bfloat16(y);
        } else {
          ((bf16*)out)[(size_t)row * N + col] = __float2bfloat16(y);
        }
      }
    }
  }
}

// ---------------------------------------------------------------------------
// Flash attention v2. Q,K,V: [B,H,T,64] bf16. O: [B,T,1024] bf16.
// 4 waves x 64 q-rows (QBLK=256), KBLK=64, double-buffered swizzled K/Vt LDS,
// DPP row-max, row-sum via MFMA-with-ones, P round-trip through swizzled LDS.
// ---------------------------------------------------------------------------
#define SCL 0.18033688011112042f  // 0.125 * log2(e)
#define NT (SEQ / 64)

__global__ __launch_bounds__(256, 2) void flash_attn(
    const bf16* __restrict__ Q, const bf16* __restrict__ K,
    const bf16* __restrict__ V, bf16* __restrict__ O) {
  __shared__ bf16 Kl[2][64 * 64];   // [k][d], swizzled: byte = k*128 + (d*2 ^ ((k&7)<<4))
  __shared__ bf16 Vt2[2][64 * 64];  // [d][k], swizzled: byte = d*128 + (k*2 ^ ((d&7)<<4))
  __shared__ bf16 Pl[4][64 * 64];   // per-wave [q][k], swizzled

  const int t = threadIdx.x;
  const int w = t >> 6, l = t & 63;
  const int l15 = l & 15, l4 = l >> 4;
  const int bh = blockIdx.y;
  const size_t base = (size_t)bh * (SEQ * HEAD_DIM);
  const int q0 = blockIdx.x * 256 + w * 64;
  const short* Vg = (const short*)V;
  char* Pbase = (char*)(Pl[w]);
  const int dV = w * 16 + l15;  // this thread's Vt row (d)

  // Q fragments: 4 m-frags x 2 k-slices, held in registers
  bf16x8 qf[4][2];
#pragma unroll
  for (int mi = 0; mi < 4; ++mi)
#pragma unroll
    for (int kk = 0; kk < 2; ++kk)
      qf[mi][kk] = *(const bf16x8*)&Q[base + (size_t)(q0 + mi * 16 + l15) * 64 + kk * 32 + l4 * 8];

  bf16x8 ones;
#pragma unroll
  for (int j = 0; j < 8; ++j) ones[j] = (short)0x3F80;  // bf16 1.0

  f32x4 accO[4][4] = {};
  f32x4 lsum[4] = {};
  float m_run[4][4];
#pragma unroll
  for (int mi = 0; mi < 4; ++mi)
#pragma unroll
    for (int r = 0; r < 4; ++r) m_run[mi][r] = -1e30f;

  short vg[16];

#define STAGE_K(buf, kt)                                                          \
  {                                                                               \
    _Pragma("unroll") for (int i = 0; i < 2; ++i) {                               \
      const int F = i * 256 + t;                                                  \
      const int r_ = F >> 3;                                                      \
      const int c_ = 8 * ((F & 7) ^ (r_ & 7));                                    \
      gload16(&K[base + (size_t)((kt) + r_) * 64 + c_],                           \
              (void*)((char*)(buf) + (i * 256 + w * 64) * 16));                   \
    }                                                                             \
  }

#define V_GATHER(kt)                                                              \
  {                                                                               \
    _Pragma("unroll") for (int h_ = 0; h_ < 2; ++h_)                              \
        _Pragma("unroll") for (int j_ = 0; j_ < 8; ++j_)                          \
            vg[h_ * 8 + j_] =                                                     \
        Vg[base + (size_t)((kt) + h_ * 32 + l4 * 8 + j_) * 64 + dV];              \
  }

#define VT_WRITE(buf)                                                             \
  {                                                                               \
    _Pragma("unroll") for (int h_ = 0; h_ < 2; ++h_) {                            \
      bf16x8 vv;                                                                  \
      _Pragma("unroll") for (int j_ = 0; j_ < 8; ++j_) vv[j_] = vg[h_ * 8 + j_];  \
      const int kb_ = (h_ * 64 + l4 * 16) ^ ((dV & 7) << 4);                      \
      *(bf16x8*)((char*)(buf) + dV * 128 + kb_) = vv;                             \
    }                                                                             \
  }

  STAGE_K(Kl[0], 0);
  V_GATHER(0);
  VT_WRITE(Vt2[0]);
  __syncthreads();

  for (int it = 0; it < NT; ++it) {
    const int cur = it & 1;
    const char* Kb = (const char*)(Kl[cur]);
    const char* Vb = (const char*)(Vt2[cur]);
    const bool pre = (it + 1 < NT);
    if (pre) {
      STAGE_K(Kl[cur ^ 1], (it + 1) * 64);
      V_GATHER((it + 1) * 64);
    }

    // ---- compute on current buffers ----
    bf16x8 kf[2][4];
#pragma unroll
    for (int kk = 0; kk < 2; ++kk)
#pragma unroll
      for (int ni = 0; ni < 4; ++ni)
        kf[kk][ni] = *(const bf16x8*)(Kb + (ni * 16 + l15) * 128 +
                                      ((kk * 64 + l4 * 16) ^ ((l15 & 7) << 4)));

#pragma unroll
    for (int mi = 0; mi < 4; ++mi) {
      f32x4 s[4] = {};
      __builtin_amdgcn_s_setprio(1);
#pragma unroll
      for (int kk = 0; kk < 2; ++kk)
#pragma unroll
        for (int ni = 0; ni < 4; ++ni)
          s[ni] = __builtin_amdgcn_mfma_f32_16x16x32_bf16(qf[mi][kk], kf[kk][ni], s[ni], 0, 0, 0);
      __builtin_amdgcn_s_setprio(0);

      float mx[4], corr[4];
#pragma unroll
      for (int r = 0; r < 4; ++r)
        mx[r] = fmaxf(fmaxf(s[0][r], s[1][r]), fmaxf(s[2][r], s[3][r]));
#pragma unroll
      for (int r = 0; r < 4; ++r) mx[r] = red_max16(mx[r]);
#pragma unroll
      for (int r = 0; r < 4; ++r) {
        const float mn = fmaxf(m_run[mi][r], mx[r] * SCL);
        corr[r] = exp2f(m_run[mi][r] - mn);
        m_run[mi][r] = mn;
      }
#pragma unroll
      for (int ni = 0; ni < 4; ++ni)
#pragma unroll
        for (int r = 0; r < 4; ++r)
          s[ni][r] = exp2f(fmaf(s[ni][r], SCL, -m_run[mi][r]));
#pragma unroll
      for (int ni = 0; ni < 4; ++ni)
#pragma unroll
        for (int r = 0; r < 4; ++r) accO[mi][ni][r] *= corr[r];
#pragma unroll
      for (int r = 0; r < 4; ++r) lsum[mi][r] *= corr[r];
      // write P (swizzled)
#pragma unroll
      for (int r = 0; r < 4; ++r) {
        const int qrow = mi * 16 + l4 * 4 + r;
        char* prow = Pbase + qrow * 128;
        const int sw = (qrow & 7) << 4;
#pragma unroll
        for (int ni = 0; ni < 4; ++ni)
          *(bf16*)(prow + ((ni * 32 + l15 * 2) ^ sw)) = __float2bfloat16(s[ni][r]);
      }
    }

    asm volatile("s_waitcnt lgkmcnt(0)" ::: "memory");

    // ---- O += P V, rowsum += P * ones ----
#pragma unroll
    for (int kk = 0; kk < 2; ++kk) {
      bf16x8 vf[4];
#pragma unroll
      for (int ni = 0; ni < 4; ++ni)
        vf[ni] = *(const bf16x8*)(Vb + (ni * 16 + l15) * 128 +
                                  ((kk * 64 + l4 * 16) ^ ((l15 & 7) << 4)));
#pragma unroll
      for (int mi = 0; mi < 4; ++mi) {
        const bf16x8 pf = *(const bf16x8*)(Pbase + (mi * 16 + l15) * 128 +
                                           ((kk * 64 + l4 * 16) ^ ((l15 & 7) << 4)));
        __builtin_amdgcn_s_setprio(1);
#pragma unroll
        for (int ni = 0; ni < 4; ++ni)
          accO[mi][ni] = __builtin_amdgcn_mfma_f32_16x16x32_bf16(pf, vf[ni], accO[mi][ni], 0, 0, 0);
        lsum[mi] = __builtin_amdgcn_mfma_f32_16x16x32_bf16(pf, ones, lsum[mi], 0, 0, 0);
        __builtin_amdgcn_s_setprio(0);
      }
    }

    if (pre) VT_WRITE(Vt2[cur ^ 1]);
    __syncthreads();
  }

  // epilogue: O[b*T + q][h*64 + d] = accO / lsum
  const int b = bh >> 4, h = bh & 15;
#pragma unroll
  for (int mi = 0; mi < 4; ++mi) {
    float rl[4];
#pragma unroll
    for (int r = 0; r < 4; ++r) rl[r] = 1.f / lsum[mi][r];
#pragma unroll
    for (int ni = 0; ni < 4; ++ni)
#pragma unroll
      for (int r = 0; r < 4; ++r) {
        const size_t row = (size_t)b * SEQ + q0 + mi * 16 + l4 * 4 + r;
        O[row * D_MODEL + h * HEAD_DIM + ni * 16 + l15] =
            __float2bfloat16(accO[mi][ni][r] * rl[r]);
      }
  }
}

// ---------------------------------------------------------------------------
extern "C" void kernel_launch(void* const* d_in, const int* in_sizes, int n_in,
                              void* d_out, int out_size, void* d_ws, size_t ws_size,
                              hipStream_t stream) {
  const float* x     = (const float*)d_in[0];
  const float* Wq    = (const float*)d_in[1];
  const float* bq    = (const float*)d_in[2];
  const float* Wk    = (const float*)d_in[3];
  const float* bk    = (const float*)d_in[4];
  const float* Wv    = (const float*)d_in[5];
  const float* bv    = (const float*)d_in[6];
  const float* Wo    = (const float*)d_in[7];
  const float* bo    = (const float*)d_in[8];
  const float* W1    = (const float*)d_in[9];
  const float* b1    = (const float*)d_in[10];
  const float* W2    = (const float*)d_in[11];
  const float* b2    = (const float*)d_in[12];
  const float* ln1_g = (const float*)d_in[13];
  const float* ln1_b = (const float*)d_in[14];
  const float* ln2_g = (const float*)d_in[15];
  const float* ln2_b = (const float*)d_in[16];

  const size_t MB = 1ull << 20;
  char* ws = (char*)d_ws;
  bf16* wq_b = (bf16*)(ws + 0 * MB);
  bf16* wk_b = (bf16*)(ws + 2 * MB);
  bf16* wv_b = (bf16*)(ws + 4 * MB);
  bf16* wo_b = (bf16*)(ws + 6 * MB);
  bf16* w1_b = (bf16*)(ws + 8 * MB);    // 8 MB
  bf16* w2_b = (bf16*)(ws + 16 * MB);   // 8 MB
  bf16* xn   = (bf16*)(ws + 24 * MB);   // 16 MB: xn / attn_out / xn2
  bf16* qb   = (bf16*)(ws + 40 * MB);   // 16 MB
  bf16* kbuf = (bf16*)(ws + 56 * MB);   // 16 MB
  bf16* vb   = (bf16*)(ws + 72 * MB);   // 16 MB
  bf16* hb   = (bf16*)(ws + 40 * MB);   // 64 MB (reuses q/k/v after attention)
  float* x1  = (float*)(ws + 104 * MB); // 32 MB

  cvt_f32_bf16<<<1024, 256, 0, stream>>>(Wq, wq_b, 1048576);
  cvt_f32_bf16<<<1024, 256, 0, stream>>>(Wk, wk_b, 1048576);
  cvt_f32_bf16<<<1024, 256, 0, stream>>>(Wv, wv_b, 1048576);
  cvt_f32_bf16<<<1024, 256, 0, stream>>>(Wo, wo_b, 1048576);
  cvt_f32_bf16<<<4096, 256, 0, stream>>>(W1, w1_b, 4194304);
  cvt_f32_bf16<<<4096, 256, 0, stream>>>(W2, w2_b, 4194304);

  layernorm_kernel<<<NTOK, 256, 0, stream>>>(x, ln1_g, ln1_b, xn);

  dim3 g1024(1024 / 128, NTOK / 128);
  gemm_bt<0><<<g1024, 256, 0, stream>>>(xn, wq_b, bq, nullptr, qb,   NTOK, 1024, 1024);
  gemm_bt<0><<<g1024, 256, 0, stream>>>(xn, wk_b, bk, nullptr, kbuf, NTOK, 1024, 1024);
  gemm_bt<0><<<g1024, 256, 0, stream>>>(xn, wv_b, bv, nullptr, vb,   NTOK, 1024, 1024);

  flash_attn<<<dim3(SEQ / 256, 4 * NHEAD), 256, 0, stream>>>(qb, kbuf, vb, xn);

  gemm_bt<2><<<g1024, 256, 0, stream>>>(xn, wo_b, bo, x, x1, NTOK, 1024, 1024);

  layernorm_kernel<<<NTOK, 256, 0, stream>>>(x1, ln2_g, ln2_b, xn);

  gemm_bt<1><<<dim3(D_FF / 128, NTOK / 128), 256, 0, stream>>>(xn, w1_b, b1, nullptr, hb, NTOK, D_FF, 1024);

  gemm_bt<2><<<g1024, 256, 0, stream>>>(hb, w2_b, b2, x1, d_out, NTOK, 1024, D_FF);
}

// Round 3
// 465.250 us; speedup vs baseline: 1.4932x; 1.2154x over previous
//
#include <hip/hip_runtime.h>
#include <hip/hip_bf16.h>

using bf16 = __hip_bfloat16;
typedef __attribute__((ext_vector_type(8))) short bf16x8;
typedef __attribute__((ext_vector_type(4))) float f32x4;

#define D_MODEL 1024
#define NHEAD 16
#define HEAD_DIM 64
#define D_FF 4096
#define SEQ 2048
#define NTOK 8192  // 4 * 2048

__device__ __forceinline__ void gload16(const void* g, void* l) {
  __builtin_amdgcn_global_load_lds((const __attribute__((address_space(1))) void*)g,
                                   (__attribute__((address_space(3))) void*)l, 16, 0, 0);
}

__device__ __forceinline__ unsigned pkbf16(float lo, float hi) {
  unsigned r;
  asm("v_cvt_pk_bf16_f32 %0, %1, %2" : "=v"(r) : "v"(lo), "v"(hi));
  return r;
}

// ---------------------------------------------------------------------------
// f32 -> bf16 conversion (weights)
// ---------------------------------------------------------------------------
__global__ void cvt_f32_bf16(const float* __restrict__ in, bf16* __restrict__ out, int n) {
  int i = (blockIdx.x * 256 + threadIdx.x) * 4;
  if (i >= n) return;
  const float4 v = *(const float4*)&in[i];
  out[i + 0] = __float2bfloat16(v.x);
  out[i + 1] = __float2bfloat16(v.y);
  out[i + 2] = __float2bfloat16(v.z);
  out[i + 3] = __float2bfloat16(v.w);
}

// ---------------------------------------------------------------------------
// LayerNorm over D=1024, fp32 in -> bf16 out. One block (256 thr) per row.
// ---------------------------------------------------------------------------
__global__ __launch_bounds__(256) void layernorm_kernel(
    const float* __restrict__ xin, const float* __restrict__ g,
    const float* __restrict__ bta, bf16* __restrict__ out) {
  const int row = blockIdx.x, t = threadIdx.x;
  const float4 v = *(const float4*)&xin[(size_t)row * D_MODEL + t * 4];
  float s = v.x + v.y + v.z + v.w;
#pragma unroll
  for (int m = 1; m < 64; m <<= 1) s += __shfl_xor(s, m);
  __shared__ float red[4], red2[4];
  const int w = t >> 6, l = t & 63;
  if (l == 0) red[w] = s;
  __syncthreads();
  const float mu = (red[0] + red[1] + red[2] + red[3]) * (1.f / 1024.f);
  const float d0 = v.x - mu, d1 = v.y - mu, d2 = v.z - mu, d3 = v.w - mu;
  float q = d0 * d0 + d1 * d1 + d2 * d2 + d3 * d3;
#pragma unroll
  for (int m = 1; m < 64; m <<= 1) q += __shfl_xor(q, m);
  if (l == 0) red2[w] = q;
  __syncthreads();
  const float var = (red2[0] + red2[1] + red2[2] + red2[3]) * (1.f / 1024.f);
  const float rs = rsqrtf(var + 1e-5f);
  const float4 gg = *(const float4*)&g[t * 4];
  const float4 bb = *(const float4*)&bta[t * 4];
  bf16* o = out + (size_t)row * D_MODEL + t * 4;
  o[0] = __float2bfloat16(d0 * rs * gg.x + bb.x);
  o[1] = __float2bfloat16(d1 * rs * gg.y + bb.y);
  o[2] = __float2bfloat16(d2 * rs * gg.z + bb.z);
  o[3] = __float2bfloat16(d3 * rs * gg.w + bb.w);
}

// ---------------------------------------------------------------------------
// GEMM-BT: C[M,N] = A[M,K] * B[N,K]^T + bias.  (unchanged)
// ---------------------------------------------------------------------------
template <int MODE>
__global__ __launch_bounds__(256, 2) void gemm_bt(
    const bf16* __restrict__ A, const bf16* __restrict__ B,
    const float* __restrict__ bias, const float* __restrict__ res,
    void* __restrict__ out, int M, int N, int K) {
  __shared__ bf16 As[128 * 64];
  __shared__ bf16 Bs[128 * 64];
  const int t = threadIdx.x;
  const int w = t >> 6, l = t & 63;
  const int l15 = l & 15, l4 = l >> 4;
  const int m0 = blockIdx.y * 128, n0 = blockIdx.x * 128;
  const int wr = (w >> 1) * 64, wc = (w & 1) * 64;

  f32x4 acc[4][4] = {};

  for (int kb = 0; kb < K; kb += 64) {
#pragma unroll
    for (int i = 0; i < 4; ++i) {
      const int f = i * 256 + t;
      gload16(&A[(size_t)(m0 + (f >> 3)) * K + kb + (f & 7) * 8],
              (void*)(As + (i * 256 + w * 64) * 8));
      gload16(&B[(size_t)(n0 + (f >> 3)) * K + kb + (f & 7) * 8],
              (void*)(Bs + (i * 256 + w * 64) * 8));
    }
    __syncthreads();
#pragma unroll
    for (int kk = 0; kk < 2; ++kk) {
      bf16x8 af[4], bfr[4];
#pragma unroll
      for (int mi = 0; mi < 4; ++mi)
        af[mi] = *(const bf16x8*)&As[(wr + mi * 16 + l15) * 64 + kk * 32 + l4 * 8];
#pragma unroll
      for (int ni = 0; ni < 4; ++ni)
        bfr[ni] = *(const bf16x8*)&Bs[(wc + ni * 16 + l15) * 64 + kk * 32 + l4 * 8];
#pragma unroll
      for (int mi = 0; mi < 4; ++mi)
#pragma unroll
        for (int ni = 0; ni < 4; ++ni)
          acc[mi][ni] = __builtin_amdgcn_mfma_f32_16x16x32_bf16(af[mi], bfr[ni], acc[mi][ni], 0, 0, 0);
    }
    __syncthreads();
  }

#pragma unroll
  for (int mi = 0; mi < 4; ++mi) {
#pragma unroll
    for (int ni = 0; ni < 4; ++ni) {
      const int col = n0 + wc + ni * 16 + l15;
      const float bb = bias[col];
#pragma unroll
      for (int r = 0; r < 4; ++r) {
        const int row = m0 + wr + mi * 16 + l4 * 4 + r;
        float y = acc[mi][ni][r] + bb;
        if constexpr (MODE == 1) y = fmaxf(y, 0.f);
        if constexpr (MODE == 2) {
          y += res[(size_t)row * N + col];
          ((float*)out)[(size_t)row * N + col] = y;
        } else if constexpr (MODE == 0) {
          const size_t dst = (size_t)((row >> 11) * NHEAD + (col >> 6)) * (SEQ * HEAD_DIM) +
                             (size_t)(row & (SEQ - 1)) * HEAD_DIM + (col & 63);
          ((bf16*)out)[dst] = __float2bfloat16(y);
        } else {
          ((bf16*)out)[(size_t)row * N + col] = __float2bfloat16(y);
        }
      }
    }
  }
}

// ---------------------------------------------------------------------------
// Flash attention v3: swapped QK^T, in-register softmax + P, zero shuffles.
// Q,K,V: [B,H,T,64] bf16. O: [B,T,1024] bf16.
// 4 waves x 64 q-rows, KBLK=64, double-buffered swizzled K/Vt LDS.
// K-fragment rows permuted (kr = (ni>>1)*32+(ni&1)*4+(l15>>2)*8+(l15&3)) so
// each lane's 16 S-values land exactly at the PV B-frag layout k=kk*32+l4*8+j.
// ---------------------------------------------------------------------------
#define SCL 0.18033688011112042f  // 0.125 * log2(e)
#define NT (SEQ / 64)

__global__ __launch_bounds__(256, 2) void flash_attn(
    const bf16* __restrict__ Q, const bf16* __restrict__ K,
    const bf16* __restrict__ V, bf16* __restrict__ O) {
  __shared__ char smem[32768];
  // layout: K buf0 @0, K buf1 @8192, Vt buf0 @16384, Vt buf1 @24576
  const int t = threadIdx.x;
  const int w = t >> 6, l = t & 63;
  const int l15 = l & 15, l4 = l >> 4;
  const int bh = blockIdx.y;
  const size_t base = (size_t)bh * (SEQ * HEAD_DIM);
  const int q0 = blockIdx.x * 256 + w * 64;
  const short* Vg = (const short*)V;
  const int dV = w * 16 + l15;  // this thread's Vt row (d)

  // permuted K-fragment row per ni (byte offset + swizzle)
  int krow[4], kswz[4];
#pragma unroll
  for (int ni = 0; ni < 4; ++ni) {
    const int kr = (ni >> 1) * 32 + (ni & 1) * 4 + (l15 >> 2) * 8 + (l15 & 3);
    krow[ni] = kr * 128;
    kswz[ni] = ((kr & 3) | (((kr >> 3) & 1) << 2)) << 4;
  }

  // Q fragments: 4 m-frags x 2 k-slices (B-operand of swapped QK^T)
  bf16x8 qf[4][2];
#pragma unroll
  for (int mi = 0; mi < 4; ++mi)
#pragma unroll
    for (int kk = 0; kk < 2; ++kk)
      qf[mi][kk] = *(const bf16x8*)&Q[base + (size_t)(q0 + mi * 16 + l15) * 64 + kk * 32 + l4 * 8];

  f32x4 accO[4][4] = {};  // O^T: [mi][ni], lane: q=mi*16+l15, d=ni*16+l4*4+r
  float m_run[4], l_run[4];
#pragma unroll
  for (int mi = 0; mi < 4; ++mi) { m_run[mi] = -1e30f; l_run[mi] = 0.f; }

  short vg[16];

#define STAGE_K(bufofs, kt)                                                       \
  {                                                                               \
    _Pragma("unroll") for (int i = 0; i < 2; ++i) {                               \
      const int F = i * 256 + t;                                                  \
      const int r_ = F >> 3;                                                      \
      const int gk_ = (r_ & 3) | (((r_ >> 3) & 1) << 2);                          \
      const int c_ = 8 * ((F & 7) ^ gk_);                                         \
      gload16(&K[base + (size_t)((kt) + r_) * 64 + c_],                           \
              (void*)(smem + (bufofs) + (i * 256 + w * 64) * 16));                \
    }                                                                             \
  }

#define V_GATHER(kt)                                                              \
  {                                                                               \
    _Pragma("unroll") for (int h_ = 0; h_ < 2; ++h_)                              \
        _Pragma("unroll") for (int j_ = 0; j_ < 8; ++j_)                          \
            vg[h_ * 8 + j_] =                                                     \
        Vg[base + (size_t)((kt) + h_ * 32 + l4 * 8 + j_) * 64 + dV];              \
  }

#define VT_WRITE(bufofs)                                                          \
  {                                                                               \
    _Pragma("unroll") for (int h_ = 0; h_ < 2; ++h_) {                            \
      bf16x8 vv;                                                                  \
      _Pragma("unroll") for (int j_ = 0; j_ < 8; ++j_) vv[j_] = vg[h_ * 8 + j_];  \
      const int kb_ = (h_ * 64 + l4 * 16) ^ ((dV & 7) << 4);                      \
      *(bf16x8*)(smem + (bufofs) + dV * 128 + kb_) = vv;                          \
    }                                                                             \
  }

  STAGE_K(0, 0);
  V_GATHER(0);
  VT_WRITE(16384);
  __syncthreads();

  for (int it = 0; it < NT; ++it) {
    const int cur = it & 1;
    const char* Kb = (const char*)smem + cur * 8192;
    const char* Vb = (const char*)smem + 16384 + cur * 8192;
    const bool pre = (it + 1 < NT);
    if (pre) {
      STAGE_K((cur ^ 1) * 8192, (it + 1) * 64);
      V_GATHER((it + 1) * 64);
    }

    // ---- QK^T (swapped: A = permuted K rows, B = Q) ----
    bf16x8 kf[2][4];
#pragma unroll
    for (int kk = 0; kk < 2; ++kk)
#pragma unroll
      for (int ni = 0; ni < 4; ++ni)
        kf[kk][ni] = *(const bf16x8*)(Kb + krow[ni] + ((kk * 64 + l4 * 16) ^ kswz[ni]));

    unsigned pw[4][8];
    float corr[4];
#pragma unroll
    for (int mi = 0; mi < 4; ++mi) {
      f32x4 s[4] = {};
      __builtin_amdgcn_s_setprio(1);
#pragma unroll
      for (int kk = 0; kk < 2; ++kk)
#pragma unroll
        for (int ni = 0; ni < 4; ++ni)
          s[ni] = __builtin_amdgcn_mfma_f32_16x16x32_bf16(kf[kk][ni], qf[mi][kk], s[ni], 0, 0, 0);
      __builtin_amdgcn_s_setprio(0);

      // row max: 16 in-lane values + 2 shuffles (lane owns q = mi*16+l15)
      float mx = s[0][0];
#pragma unroll
      for (int ni = 0; ni < 4; ++ni)
#pragma unroll
        for (int r = 0; r < 4; ++r) mx = fmaxf(mx, s[ni][r]);
      mx = fmaxf(mx, __shfl_xor(mx, 16));
      mx = fmaxf(mx, __shfl_xor(mx, 32));
      const float mn = fmaxf(m_run[mi], mx * SCL);
      const float c = exp2f(m_run[mi] - mn);
      m_run[mi] = mn;
      corr[mi] = c;
      float rs = 0.f;
#pragma unroll
      for (int ni = 0; ni < 4; ++ni)
#pragma unroll
        for (int r = 0; r < 4; ++r) {
          const float p = exp2f(fmaf(s[ni][r], SCL, -mn));
          s[ni][r] = p;
          rs += p;
        }
      rs += __shfl_xor(rs, 16);
      rs += __shfl_xor(rs, 32);
      l_run[mi] = l_run[mi] * c + rs;
      // pack P to bf16 pairs, in-lane (k = kk*32 + l4*8 + j)
#pragma unroll
      for (int kk = 0; kk < 2; ++kk)
#pragma unroll
        for (int jj = 0; jj < 4; ++jj) {
          const int ni = 2 * kk + (jj >> 1);
          pw[mi][kk * 4 + jj] = pkbf16(s[ni][2 * (jj & 1)], s[ni][2 * (jj & 1) + 1]);
        }
    }

    // ---- PV: O^T += V^T P  (A = Vt rows d, B = packed P) ----
    bf16x8 vf[2][4];
#pragma unroll
    for (int kk = 0; kk < 2; ++kk)
#pragma unroll
      for (int ni = 0; ni < 4; ++ni)
        vf[kk][ni] = *(const bf16x8*)(Vb + (ni * 16 + l15) * 128 +
                                      ((kk * 64 + l4 * 16) ^ ((l15 & 7) << 4)));

#pragma unroll
    for (int mi = 0; mi < 4; ++mi) {
      const float c = corr[mi];
#pragma unroll
      for (int ni = 0; ni < 4; ++ni) accO[mi][ni] *= c;
#pragma unroll
      for (int kk = 0; kk < 2; ++kk) {
        union { unsigned u[4]; bf16x8 h; } pb;
#pragma unroll
        for (int jj = 0; jj < 4; ++jj) pb.u[jj] = pw[mi][kk * 4 + jj];
        __builtin_amdgcn_s_setprio(1);
#pragma unroll
        for (int ni = 0; ni < 4; ++ni)
          accO[mi][ni] = __builtin_amdgcn_mfma_f32_16x16x32_bf16(vf[kk][ni], pb.h, accO[mi][ni], 0, 0, 0);
        __builtin_amdgcn_s_setprio(0);
      }
    }

    if (pre) VT_WRITE(16384 + (cur ^ 1) * 8192);
    __syncthreads();
  }

  // ---- epilogue: bounce O^T through LDS to restore coalescing ----
  char* ob = smem + w * 8192;  // 8KB per wave (64 q-rows x 128B)
#pragma unroll
  for (int mi = 0; mi < 4; ++mi) {
    const float inv = 1.f / l_run[mi];
    const int qr = mi * 16 + l15;
    const int sw = (qr & 7) << 4;
#pragma unroll
    for (int ni = 0; ni < 4; ++ni)
#pragma unroll
      for (int rr = 0; rr < 2; ++rr) {
        const unsigned pk = pkbf16(accO[mi][ni][2 * rr] * inv, accO[mi][ni][2 * rr + 1] * inv);
        *(unsigned*)(ob + qr * 128 + ((ni * 32 + l4 * 8 + 4 * rr) ^ sw)) = pk;
      }
  }
  asm volatile("s_waitcnt lgkmcnt(0)" ::: "memory");
  __builtin_amdgcn_sched_barrier(0);

  const int b = bh >> 4, h = bh & 15;
  const size_t orow = ((size_t)b * SEQ + blockIdx.x * 256 + w * 64 + l) * D_MODEL + h * HEAD_DIM;
#pragma unroll
  for (int c = 0; c < 8; ++c) {
    bf16x8 vv = *(const bf16x8*)(ob + l * 128 + ((c * 16) ^ ((l & 7) << 4)));
    *(bf16x8*)&O[orow + c * 8] = vv;
  }
}

// ---------------------------------------------------------------------------
extern "C" void kernel_launch(void* const* d_in, const int* in_sizes, int n_in,
                              void* d_out, int out_size, void* d_ws, size_t ws_size,
                              hipStream_t stream) {
  const float* x     = (const float*)d_in[0];
  const float* Wq    = (const float*)d_in[1];
  const float* bq    = (const float*)d_in[2];
  const float* Wk    = (const float*)d_in[3];
  const float* bk    = (const float*)d_in[4];
  const float* Wv    = (const float*)d_in[5];
  const float* bv    = (const float*)d_in[6];
  const float* Wo    = (const float*)d_in[7];
  const float* bo    = (const float*)d_in[8];
  const float* W1    = (const float*)d_in[9];
  const float* b1    = (const float*)d_in[10];
  const float* W2    = (const float*)d_in[11];
  const float* b2    = (const float*)d_in[12];
  const float* ln1_g = (const float*)d_in[13];
  const float* ln1_b = (const float*)d_in[14];
  const float* ln2_g = (const float*)d_in[15];
  const float* ln2_b = (const float*)d_in[16];

  const size_t MB = 1ull << 20;
  char* ws = (char*)d_ws;
  bf16* wq_b = (bf16*)(ws + 0 * MB);
  bf16* wk_b = (bf16*)(ws + 2 * MB);
  bf16* wv_b = (bf16*)(ws + 4 * MB);
  bf16* wo_b = (bf16*)(ws + 6 * MB);
  bf16* w1_b = (bf16*)(ws + 8 * MB);    // 8 MB
  bf16* w2_b = (bf16*)(ws + 16 * MB);   // 8 MB
  bf16* xn   = (bf16*)(ws + 24 * MB);   // 16 MB: xn / attn_out / xn2
  bf16* qb   = (bf16*)(ws + 40 * MB);   // 16 MB
  bf16* kbuf = (bf16*)(ws + 56 * MB);   // 16 MB
  bf16* vb   = (bf16*)(ws + 72 * MB);   // 16 MB
  bf16* hb   = (bf16*)(ws + 40 * MB);   // 64 MB (reuses q/k/v after attention)
  float* x1  = (float*)(ws + 104 * MB); // 32 MB

  cvt_f32_bf16<<<1024, 256, 0, stream>>>(Wq, wq_b, 1048576);
  cvt_f32_bf16<<<1024, 256, 0, stream>>>(Wk, wk_b, 1048576);
  cvt_f32_bf16<<<1024, 256, 0, stream>>>(Wv, wv_b, 1048576);
  cvt_f32_bf16<<<1024, 256, 0, stream>>>(Wo, wo_b, 1048576);
  cvt_f32_bf16<<<4096, 256, 0, stream>>>(W1, w1_b, 4194304);
  cvt_f32_bf16<<<4096, 256, 0, stream>>>(W2, w2_b, 4194304);

  layernorm_kernel<<<NTOK, 256, 0, stream>>>(x, ln1_g, ln1_b, xn);

  dim3 g1024(1024 / 128, NTOK / 128);
  gemm_bt<0><<<g1024, 256, 0, stream>>>(xn, wq_b, bq, nullptr, qb,   NTOK, 1024, 1024);
  gemm_bt<0><<<g1024, 256, 0, stream>>>(xn, wk_b, bk, nullptr, kbuf, NTOK, 1024, 1024);
  gemm_bt<0><<<g1024, 256, 0, stream>>>(xn, wv_b, bv, nullptr, vb,   NTOK, 1024, 1024);

  flash_attn<<<dim3(SEQ / 256, 4 * NHEAD), 256, 0, stream>>>(qb, kbuf, vb, xn);

  gemm_bt<2><<<g1024, 256, 0, stream>>>(xn, wo_b, bo, x, x1, NTOK, 1024, 1024);

  layernorm_kernel<<<NTOK, 256, 0, stream>>>(x1, ln2_g, ln2_b, xn);

  gemm_bt<1><<<dim3(D_FF / 128, NTOK / 128), 256, 0, stream>>>(xn, w1_b, b1, nullptr, hb, NTOK, D_FF, 1024);

  gemm_bt<2><<<g1024, 256, 0, stream>>>(hb, w2_b, b2, x1, d_out, NTOK, 1024, D_FF);
}

// Round 4
// 450.667 us; speedup vs baseline: 1.5415x; 1.0324x over previous
//
#include <hip/hip_runtime.h>
#include <hip/hip_bf16.h>

using bf16 = __hip_bfloat16;
typedef __attribute__((ext_vector_type(8))) short bf16x8;
typedef __attribute__((ext_vector_type(4))) float f32x4;

#define D_MODEL 1024
#define NHEAD 16
#define HEAD_DIM 64
#define D_FF 4096
#define SEQ 2048
#define NTOK 8192  // 4 * 2048

__device__ __forceinline__ void gload16(const void* g, void* l) {
  __builtin_amdgcn_global_load_lds((const __attribute__((address_space(1))) void*)g,
                                   (__attribute__((address_space(3))) void*)l, 16, 0, 0);
}

__device__ __forceinline__ unsigned pkbf16(float lo, float hi) {
  unsigned r;
  asm("v_cvt_pk_bf16_f32 %0, %1, %2" : "=v"(r) : "v"(lo), "v"(hi));
  return r;
}

// ---------------------------------------------------------------------------
// f32 -> bf16 conversion (weights)
// ---------------------------------------------------------------------------
__global__ void cvt_f32_bf16(const float* __restrict__ in, bf16* __restrict__ out, int n) {
  int i = (blockIdx.x * 256 + threadIdx.x) * 4;
  if (i >= n) return;
  const float4 v = *(const float4*)&in[i];
  out[i + 0] = __float2bfloat16(v.x);
  out[i + 1] = __float2bfloat16(v.y);
  out[i + 2] = __float2bfloat16(v.z);
  out[i + 3] = __float2bfloat16(v.w);
}

// ---------------------------------------------------------------------------
// LayerNorm over D=1024, fp32 in -> bf16 out. One block (256 thr) per row.
// ---------------------------------------------------------------------------
__global__ __launch_bounds__(256) void layernorm_kernel(
    const float* __restrict__ xin, const float* __restrict__ g,
    const float* __restrict__ bta, bf16* __restrict__ out) {
  const int row = blockIdx.x, t = threadIdx.x;
  const float4 v = *(const float4*)&xin[(size_t)row * D_MODEL + t * 4];
  float s = v.x + v.y + v.z + v.w;
#pragma unroll
  for (int m = 1; m < 64; m <<= 1) s += __shfl_xor(s, m);
  __shared__ float red[4], red2[4];
  const int w = t >> 6, l = t & 63;
  if (l == 0) red[w] = s;
  __syncthreads();
  const float mu = (red[0] + red[1] + red[2] + red[3]) * (1.f / 1024.f);
  const float d0 = v.x - mu, d1 = v.y - mu, d2 = v.z - mu, d3 = v.w - mu;
  float q = d0 * d0 + d1 * d1 + d2 * d2 + d3 * d3;
#pragma unroll
  for (int m = 1; m < 64; m <<= 1) q += __shfl_xor(q, m);
  if (l == 0) red2[w] = q;
  __syncthreads();
  const float var = (red2[0] + red2[1] + red2[2] + red2[3]) * (1.f / 1024.f);
  const float rs = rsqrtf(var + 1e-5f);
  const float4 gg = *(const float4*)&g[t * 4];
  const float4 bb = *(const float4*)&bta[t * 4];
  bf16* o = out + (size_t)row * D_MODEL + t * 4;
  o[0] = __float2bfloat16(d0 * rs * gg.x + bb.x);
  o[1] = __float2bfloat16(d1 * rs * gg.y + bb.y);
  o[2] = __float2bfloat16(d2 * rs * gg.z + bb.z);
  o[3] = __float2bfloat16(d3 * rs * gg.w + bb.w);
}

// ---------------------------------------------------------------------------
// gemm8: deep-pipelined GEMM-BT. C[M,N] = A[M,K] * B[N,K]^T + bias.
// BM=256, BK=64, 512 threads, 8 waves (1M x 8N). 8 phases per K-tile,
// counted vmcnt (never 0 in loop), raw s_barrier, setprio around MFMA,
// XOR-row LDS swizzle staged via inverse-swizzled global source.
// Phase p computes output rows m0+32p..m0+32p+31 (acc[2p],acc[2p+1]).
// Stage FIFO per tile: [B0..B(NBL-1), A0..A3]; phase p issues load #p.
// Waits: vmcnt(4)@p1, vmcnt(5)@p3, vmcnt(6)@p5, vmcnt(3)@p7 (derived
// from FIFO positions; each load gets >=3 phases of latency cover).
// MODE 0: bf16 out, QKV permute+split to [B,H,T,Hd] x 3 buffers
// MODE 1: bf16 out row-major, ReLU
// MODE 2: f32 out row-major, += res
// ---------------------------------------------------------------------------
template <int BN_, int MODE>
__global__ __launch_bounds__(512, 2) void gemm8(
    const bf16* __restrict__ A, const bf16* __restrict__ Bw,
    const float* __restrict__ bias0, const float* __restrict__ bias1,
    const float* __restrict__ bias2, const float* __restrict__ res,
    void* __restrict__ out, int M, int N, int K) {
  constexpr int NI = BN_ / 128;   // N-frags per wave (2 or 1)
  constexpr int ASZ = 256 * 128;  // A tile bytes
  constexpr int BSZ = BN_ * 128;
  constexpr int TILE = ASZ + BSZ;
  constexpr int NBL = BN_ / 64;  // B stage loads per tile per thread

  __shared__ __align__(16) char smem[2 * TILE];

  const int t = threadIdx.x;
  const int l = t & 63, l15 = l & 15, l4 = l >> 4;
  const int w = t >> 6;
  const int m0 = blockIdx.y * 256, n0 = blockIdx.x * BN_;
  const int wc = w * (16 * NI);

  // staging: thread covers row sr of each 64-row pass, 16B chunk sc8,
  // source column pre-XORed so linear LDS dest yields swizzled layout
  const int sr = t >> 3;
  const int scol = 8 * ((t & 7) ^ (sr & 7));

  // fragment read column offsets (row&7 == l15&7 for all frag rows)
  const int swz = (l15 & 7) << 4;
  int coff[2];
#pragma unroll
  for (int kk = 0; kk < 2; ++kk) coff[kk] = (kk * 64 + l4 * 16) ^ swz;

#define ST_A(j, kb, buf)                                              \
  gload16(&A[(size_t)(m0 + (j) * 64 + sr) * K + (kb) + scol],         \
          (void*)(smem + (buf) * TILE + (j) * 8192 + t * 16))
#define ST_B(j, kb, buf)                                              \
  gload16(&Bw[(size_t)(n0 + (j) * 64 + sr) * K + (kb) + scol],        \
          (void*)(smem + (buf) * TILE + ASZ + (j) * 8192 + t * 16))

  f32x4 acc[16][NI] = {};
  bf16x8 bfrag[NI][2];
  const int NTm = K >> 6;

  // prologue: stage tile 0 in steady-state FIFO order
#pragma unroll
  for (int j = 0; j < NBL; ++j) ST_B(j, 0, 0);
#pragma unroll
  for (int j = 0; j < 4; ++j) ST_A(j, 0, 0);
  asm volatile("s_waitcnt vmcnt(3)" ::: "memory");
  __builtin_amdgcn_s_barrier();

#define PHASE(p)                                                                       \
  {                                                                                    \
    if ((p) == 0) {                                                                    \
      _Pragma("unroll") for (int ni = 0; ni < NI; ++ni)                                \
          _Pragma("unroll") for (int kk = 0; kk < 2; ++kk)                             \
              bfrag[ni][kk] = *(const bf16x8*)(cb + ASZ +                              \
                                               (wc + ni * 16 + l15) * 128 + coff[kk]); \
    }                                                                                  \
    bf16x8 af[2][2];                                                                   \
    _Pragma("unroll") for (int mi2 = 0; mi2 < 2; ++mi2)                                \
        _Pragma("unroll") for (int kk = 0; kk < 2; ++kk)                               \
            af[mi2][kk] = *(const bf16x8*)(cb + ((p) * 32 + mi2 * 16 + l15) * 128 +    \
                                           coff[kk]);                                  \
    if (hasNext) {                                                                     \
      if (BN_ == 256) {                                                                \
        if ((p) < 4) { ST_B((p) & 3, kbn, nb); } else { ST_A((p) - 4, kbn, nb); }      \
      } else {                                                                         \
        if ((p) < 2) { ST_B((p) & 1, kbn, nb); }                                       \
        else if ((p) < 6) { ST_A((p) - 2, kbn, nb); }                                  \
      }                                                                                \
    }                                                                                  \
    __builtin_amdgcn_s_barrier();                                                      \
    asm volatile("s_waitcnt lgkmcnt(0)" ::: "memory");                                 \
    __builtin_amdgcn_sched_barrier(0);                                                 \
    __builtin_amdgcn_s_setprio(1);                                                     \
    _Pragma("unroll") for (int ni = 0; ni < NI; ++ni)                                  \
        _Pragma("unroll") for (int mi2 = 0; mi2 < 2; ++mi2)                            \
            _Pragma("unroll") for (int kk = 0; kk < 2; ++kk)                           \
                acc[2 * (p) + mi2][ni] = __builtin_amdgcn_mfma_f32_16x16x32_bf16(      \
                    af[mi2][kk], bfrag[ni][kk], acc[2 * (p) + mi2][ni], 0, 0, 0);      \
    __builtin_amdgcn_s_setprio(0);                                                     \
    if ((p) == 1) asm volatile("s_waitcnt vmcnt(4)" ::: "memory");                     \
    if ((p) == 3) asm volatile("s_waitcnt vmcnt(5)" ::: "memory");                     \
    if ((p) == 5) asm volatile("s_waitcnt vmcnt(6)" ::: "memory");                     \
    if ((p) == 7) asm volatile("s_waitcnt vmcnt(3)" ::: "memory");                     \
    __builtin_amdgcn_s_barrier();                                                      \
  }

  for (int kt = 0; kt < NTm; ++kt) {
    const char* cb = smem + (kt & 1) * TILE;
    const int nb = (kt & 1) ^ 1;
    const int kbn = (kt + 1) << 6;
    const bool hasNext = (kt + 1 < NTm);
    PHASE(0) PHASE(1) PHASE(2) PHASE(3) PHASE(4) PHASE(5) PHASE(6) PHASE(7)
  }
#undef PHASE
#undef ST_A
#undef ST_B

  // epilogue
#pragma unroll
  for (int mi = 0; mi < 16; ++mi) {
#pragma unroll
    for (int ni = 0; ni < NI; ++ni) {
      const int col = n0 + wc + ni * 16 + l15;
      float bb;
      if constexpr (MODE == 0) {
        const int sel = col >> 10;
        const float* bp = (sel == 0) ? bias0 : ((sel == 1) ? bias1 : bias2);
        bb = bp[col & 1023];
      } else {
        bb = bias0[col];
      }
#pragma unroll
      for (int r = 0; r < 4; ++r) {
        const int row = m0 + mi * 16 + l4 * 4 + r;
        float y = acc[mi][ni][r] + bb;
        if constexpr (MODE == 1) y = fmaxf(y, 0.f);
        if constexpr (MODE == 2) {
          y += res[(size_t)row * N + col];
          ((float*)out)[(size_t)row * N + col] = y;
        } else if constexpr (MODE == 0) {
          const int sel = col >> 10;
          const int c10 = col & 1023;
          const size_t dst = (size_t)sel * (NTOK * 1024) +
                             (size_t)((row >> 11) * NHEAD + (c10 >> 6)) * (SEQ * HEAD_DIM) +
                             (size_t)(row & (SEQ - 1)) * HEAD_DIM + (c10 & 63);
          ((bf16*)out)[dst] = __float2bfloat16(y);
        } else {
          ((bf16*)out)[(size_t)row * N + col] = __float2bfloat16(y);
        }
      }
    }
  }
}

// ---------------------------------------------------------------------------
// Flash attention v3 (unchanged from round 3): swapped QK^T, in-register
// softmax + P, zero shuffles. Q,K,V: [B,H,T,64] bf16. O: [B,T,1024] bf16.
// ---------------------------------------------------------------------------
#define SCL 0.18033688011112042f  // 0.125 * log2(e)
#define NT (SEQ / 64)

__global__ __launch_bounds__(256, 2) void flash_attn(
    const bf16* __restrict__ Q, const bf16* __restrict__ K,
    const bf16* __restrict__ V, bf16* __restrict__ O) {
  __shared__ char smem[32768];
  const int t = threadIdx.x;
  const int w = t >> 6, l = t & 63;
  const int l15 = l & 15, l4 = l >> 4;
  const int bh = blockIdx.y;
  const size_t base = (size_t)bh * (SEQ * HEAD_DIM);
  const int q0 = blockIdx.x * 256 + w * 64;
  const short* Vg = (const short*)V;
  const int dV = w * 16 + l15;

  int krow[4], kswz[4];
#pragma unroll
  for (int ni = 0; ni < 4; ++ni) {
    const int kr = (ni >> 1) * 32 + (ni & 1) * 4 + (l15 >> 2) * 8 + (l15 & 3);
    krow[ni] = kr * 128;
    kswz[ni] = ((kr & 3) | (((kr >> 3) & 1) << 2)) << 4;
  }

  bf16x8 qf[4][2];
#pragma unroll
  for (int mi = 0; mi < 4; ++mi)
#pragma unroll
    for (int kk = 0; kk < 2; ++kk)
      qf[mi][kk] = *(const bf16x8*)&Q[base + (size_t)(q0 + mi * 16 + l15) * 64 + kk * 32 + l4 * 8];

  f32x4 accO[4][4] = {};
  float m_run[4], l_run[4];
#pragma unroll
  for (int mi = 0; mi < 4; ++mi) { m_run[mi] = -1e30f; l_run[mi] = 0.f; }

  short vg[16];

#define STAGE_K(bufofs, kt)                                                       \
  {                                                                               \
    _Pragma("unroll") for (int i = 0; i < 2; ++i) {                               \
      const int F = i * 256 + t;                                                  \
      const int r_ = F >> 3;                                                      \
      const int gk_ = (r_ & 3) | (((r_ >> 3) & 1) << 2);                          \
      const int c_ = 8 * ((F & 7) ^ gk_);                                         \
      gload16(&K[base + (size_t)((kt) + r_) * 64 + c_],                           \
              (void*)(smem + (bufofs) + (i * 256 + w * 64) * 16));                \
    }                                                                             \
  }

#define V_GATHER(kt)                                                              \
  {                                                                               \
    _Pragma("unroll") for (int h_ = 0; h_ < 2; ++h_)                              \
        _Pragma("unroll") for (int j_ = 0; j_ < 8; ++j_)                          \
            vg[h_ * 8 + j_] =                                                     \
        Vg[base + (size_t)((kt) + h_ * 32 + l4 * 8 + j_) * 64 + dV];              \
  }

#define VT_WRITE(bufofs)                                                          \
  {                                                                               \
    _Pragma("unroll") for (int h_ = 0; h_ < 2; ++h_) {                            \
      bf16x8 vv;                                                                  \
      _Pragma("unroll") for (int j_ = 0; j_ < 8; ++j_) vv[j_] = vg[h_ * 8 + j_];  \
      const int kb_ = (h_ * 64 + l4 * 16) ^ ((dV & 7) << 4);                      \
      *(bf16x8*)(smem + (bufofs) + dV * 128 + kb_) = vv;                          \
    }                                                                             \
  }

  STAGE_K(0, 0);
  V_GATHER(0);
  VT_WRITE(16384);
  __syncthreads();

  for (int it = 0; it < NT; ++it) {
    const int cur = it & 1;
    const char* Kb = (const char*)smem + cur * 8192;
    const char* Vb = (const char*)smem + 16384 + cur * 8192;
    const bool pre = (it + 1 < NT);
    if (pre) {
      STAGE_K((cur ^ 1) * 8192, (it + 1) * 64);
      V_GATHER((it + 1) * 64);
    }

    bf16x8 kf[2][4];
#pragma unroll
    for (int kk = 0; kk < 2; ++kk)
#pragma unroll
      for (int ni = 0; ni < 4; ++ni)
        kf[kk][ni] = *(const bf16x8*)(Kb + krow[ni] + ((kk * 64 + l4 * 16) ^ kswz[ni]));

    unsigned pw[4][8];
    float corr[4];
#pragma unroll
    for (int mi = 0; mi < 4; ++mi) {
      f32x4 s[4] = {};
      __builtin_amdgcn_s_setprio(1);
#pragma unroll
      for (int kk = 0; kk < 2; ++kk)
#pragma unroll
        for (int ni = 0; ni < 4; ++ni)
          s[ni] = __builtin_amdgcn_mfma_f32_16x16x32_bf16(kf[kk][ni], qf[mi][kk], s[ni], 0, 0, 0);
      __builtin_amdgcn_s_setprio(0);

      float mx = s[0][0];
#pragma unroll
      for (int ni = 0; ni < 4; ++ni)
#pragma unroll
        for (int r = 0; r < 4; ++r) mx = fmaxf(mx, s[ni][r]);
      mx = fmaxf(mx, __shfl_xor(mx, 16));
      mx = fmaxf(mx, __shfl_xor(mx, 32));
      const float mn = fmaxf(m_run[mi], mx * SCL);
      const float c = exp2f(m_run[mi] - mn);
      m_run[mi] = mn;
      corr[mi] = c;
      float rs = 0.f;
#pragma unroll
      for (int ni = 0; ni < 4; ++ni)
#pragma unroll
        for (int r = 0; r < 4; ++r) {
          const float p = exp2f(fmaf(s[ni][r], SCL, -mn));
          s[ni][r] = p;
          rs += p;
        }
      rs += __shfl_xor(rs, 16);
      rs += __shfl_xor(rs, 32);
      l_run[mi] = l_run[mi] * c + rs;
#pragma unroll
      for (int kk = 0; kk < 2; ++kk)
#pragma unroll
        for (int jj = 0; jj < 4; ++jj) {
          const int ni = 2 * kk + (jj >> 1);
          pw[mi][kk * 4 + jj] = pkbf16(s[ni][2 * (jj & 1)], s[ni][2 * (jj & 1) + 1]);
        }
    }

    bf16x8 vf[2][4];
#pragma unroll
    for (int kk = 0; kk < 2; ++kk)
#pragma unroll
      for (int ni = 0; ni < 4; ++ni)
        vf[kk][ni] = *(const bf16x8*)(Vb + (ni * 16 + l15) * 128 +
                                      ((kk * 64 + l4 * 16) ^ ((l15 & 7) << 4)));

#pragma unroll
    for (int mi = 0; mi < 4; ++mi) {
      const float c = corr[mi];
#pragma unroll
      for (int ni = 0; ni < 4; ++ni) accO[mi][ni] *= c;
#pragma unroll
      for (int kk = 0; kk < 2; ++kk) {
        union { unsigned u[4]; bf16x8 h; } pb;
#pragma unroll
        for (int jj = 0; jj < 4; ++jj) pb.u[jj] = pw[mi][kk * 4 + jj];
        __builtin_amdgcn_s_setprio(1);
#pragma unroll
        for (int ni = 0; ni < 4; ++ni)
          accO[mi][ni] = __builtin_amdgcn_mfma_f32_16x16x32_bf16(vf[kk][ni], pb.h, accO[mi][ni], 0, 0, 0);
        __builtin_amdgcn_s_setprio(0);
      }
    }

    if (pre) VT_WRITE(16384 + (cur ^ 1) * 8192);
    __syncthreads();
  }

  char* ob = smem + w * 8192;
#pragma unroll
  for (int mi = 0; mi < 4; ++mi) {
    const float inv = 1.f / l_run[mi];
    const int qr = mi * 16 + l15;
    const int sw = (qr & 7) << 4;
#pragma unroll
    for (int ni = 0; ni < 4; ++ni)
#pragma unroll
      for (int rr = 0; rr < 2; ++rr) {
        const unsigned pk = pkbf16(accO[mi][ni][2 * rr] * inv, accO[mi][ni][2 * rr + 1] * inv);
        *(unsigned*)(ob + qr * 128 + ((ni * 32 + l4 * 8 + 4 * rr) ^ sw)) = pk;
      }
  }
  asm volatile("s_waitcnt lgkmcnt(0)" ::: "memory");
  __builtin_amdgcn_sched_barrier(0);

  const int b = bh >> 4, h = bh & 15;
  const size_t orow = ((size_t)b * SEQ + blockIdx.x * 256 + w * 64 + l) * D_MODEL + h * HEAD_DIM;
#pragma unroll
  for (int c = 0; c < 8; ++c) {
    bf16x8 vv = *(const bf16x8*)(ob + l * 128 + ((c * 16) ^ ((l & 7) << 4)));
    *(bf16x8*)&O[orow + c * 8] = vv;
  }
}

// ---------------------------------------------------------------------------
extern "C" void kernel_launch(void* const* d_in, const int* in_sizes, int n_in,
                              void* d_out, int out_size, void* d_ws, size_t ws_size,
                              hipStream_t stream) {
  const float* x     = (const float*)d_in[0];
  const float* Wq    = (const float*)d_in[1];
  const float* bq    = (const float*)d_in[2];
  const float* Wk    = (const float*)d_in[3];
  const float* bk    = (const float*)d_in[4];
  const float* Wv    = (const float*)d_in[5];
  const float* bv    = (const float*)d_in[6];
  const float* Wo    = (const float*)d_in[7];
  const float* bo    = (const float*)d_in[8];
  const float* W1    = (const float*)d_in[9];
  const float* b1    = (const float*)d_in[10];
  const float* W2    = (const float*)d_in[11];
  const float* b2    = (const float*)d_in[12];
  const float* ln1_g = (const float*)d_in[13];
  const float* ln1_b = (const float*)d_in[14];
  const float* ln2_g = (const float*)d_in[15];
  const float* ln2_b = (const float*)d_in[16];

  const size_t MB = 1ull << 20;
  char* ws = (char*)d_ws;
  bf16* wqkv = (bf16*)(ws + 0 * MB);    // 6 MB: [Wq;Wk;Wv] rows, K-contig
  bf16* wo_b = (bf16*)(ws + 6 * MB);
  bf16* w1_b = (bf16*)(ws + 8 * MB);    // 8 MB
  bf16* w2_b = (bf16*)(ws + 16 * MB);   // 8 MB
  bf16* xn   = (bf16*)(ws + 24 * MB);   // 16 MB: xn / attn_out / xn2
  bf16* qb   = (bf16*)(ws + 40 * MB);   // 16 MB  (q, k, v contiguous)
  bf16* kbuf = (bf16*)(ws + 56 * MB);   // 16 MB
  bf16* vb   = (bf16*)(ws + 72 * MB);   // 16 MB
  bf16* hb   = (bf16*)(ws + 40 * MB);   // 64 MB (reuses q/k/v after attention)
  float* x1  = (float*)(ws + 104 * MB); // 32 MB

  cvt_f32_bf16<<<1024, 256, 0, stream>>>(Wq, wqkv, 1048576);
  cvt_f32_bf16<<<1024, 256, 0, stream>>>(Wk, wqkv + 1048576, 1048576);
  cvt_f32_bf16<<<1024, 256, 0, stream>>>(Wv, wqkv + 2097152, 1048576);
  cvt_f32_bf16<<<1024, 256, 0, stream>>>(Wo, wo_b, 1048576);
  cvt_f32_bf16<<<4096, 256, 0, stream>>>(W1, w1_b, 4194304);
  cvt_f32_bf16<<<4096, 256, 0, stream>>>(W2, w2_b, 4194304);

  layernorm_kernel<<<NTOK, 256, 0, stream>>>(x, ln1_g, ln1_b, xn);

  // QKV fused: [8192,3072] = xn @ wqkv^T, permuted+split to q/k/v buffers
  gemm8<256, 0><<<dim3(3072 / 256, NTOK / 256), 512, 0, stream>>>(
      xn, wqkv, bq, bk, bv, nullptr, qb, NTOK, 3072, 1024);

  flash_attn<<<dim3(SEQ / 256, 4 * NHEAD), 256, 0, stream>>>(qb, kbuf, vb, xn);

  // Wo + residual(x) -> x1 (fp32)
  gemm8<128, 2><<<dim3(1024 / 128, NTOK / 256), 512, 0, stream>>>(
      xn, wo_b, bo, bo, bo, x, x1, NTOK, 1024, 1024);

  layernorm_kernel<<<NTOK, 256, 0, stream>>>(x1, ln2_g, ln2_b, xn);

  // FFN1 (ReLU) -> hb
  gemm8<256, 1><<<dim3(D_FF / 256, NTOK / 256), 512, 0, stream>>>(
      xn, w1_b, b1, b1, b1, nullptr, hb, NTOK, D_FF, 1024);

  // FFN2 + residual(x1) -> d_out (fp32)
  gemm8<128, 2><<<dim3(1024 / 128, NTOK / 256), 512, 0, stream>>>(
      hb, w2_b, b2, b2, b2, x1, d_out, NTOK, 1024, D_FF);
}

// Round 5
// 431.593 us; speedup vs baseline: 1.6097x; 1.0442x over previous
//
#include <hip/hip_runtime.h>
#include <hip/hip_bf16.h>

using bf16 = __hip_bfloat16;
typedef __attribute__((ext_vector_type(8))) short bf16x8;
typedef __attribute__((ext_vector_type(4))) float f32x4;

#define D_MODEL 1024
#define NHEAD 16
#define HEAD_DIM 64
#define D_FF 4096
#define SEQ 2048
#define NTOK 8192  // 4 * 2048

__device__ __forceinline__ void gload16(const void* g, void* l) {
  __builtin_amdgcn_global_load_lds((const __attribute__((address_space(1))) void*)g,
                                   (__attribute__((address_space(3))) void*)l, 16, 0, 0);
}

__device__ __forceinline__ unsigned pkbf16(float lo, float hi) {
  unsigned r;
  asm("v_cvt_pk_bf16_f32 %0, %1, %2" : "=v"(r) : "v"(lo), "v"(hi));
  return r;
}

// ---------------------------------------------------------------------------
// f32 -> bf16 conversion (weights)
// ---------------------------------------------------------------------------
__global__ void cvt_f32_bf16(const float* __restrict__ in, bf16* __restrict__ out, int n) {
  int i = (blockIdx.x * 256 + threadIdx.x) * 4;
  if (i >= n) return;
  const float4 v = *(const float4*)&in[i];
  out[i + 0] = __float2bfloat16(v.x);
  out[i + 1] = __float2bfloat16(v.y);
  out[i + 2] = __float2bfloat16(v.z);
  out[i + 3] = __float2bfloat16(v.w);
}

// ---------------------------------------------------------------------------
// LayerNorm over D=1024, fp32 in -> bf16 out. One block (256 thr) per row.
// ---------------------------------------------------------------------------
__global__ __launch_bounds__(256) void layernorm_kernel(
    const float* __restrict__ xin, const float* __restrict__ g,
    const float* __restrict__ bta, bf16* __restrict__ out) {
  const int row = blockIdx.x, t = threadIdx.x;
  const float4 v = *(const float4*)&xin[(size_t)row * D_MODEL + t * 4];
  float s = v.x + v.y + v.z + v.w;
#pragma unroll
  for (int m = 1; m < 64; m <<= 1) s += __shfl_xor(s, m);
  __shared__ float red[4], red2[4];
  const int w = t >> 6, l = t & 63;
  if (l == 0) red[w] = s;
  __syncthreads();
  const float mu = (red[0] + red[1] + red[2] + red[3]) * (1.f / 1024.f);
  const float d0 = v.x - mu, d1 = v.y - mu, d2 = v.z - mu, d3 = v.w - mu;
  float q = d0 * d0 + d1 * d1 + d2 * d2 + d3 * d3;
#pragma unroll
  for (int m = 1; m < 64; m <<= 1) q += __shfl_xor(q, m);
  if (l == 0) red2[w] = q;
  __syncthreads();
  const float var = (red2[0] + red2[1] + red2[2] + red2[3]) * (1.f / 1024.f);
  const float rs = rsqrtf(var + 1e-5f);
  const float4 gg = *(const float4*)&g[t * 4];
  const float4 bb = *(const float4*)&bta[t * 4];
  bf16* o = out + (size_t)row * D_MODEL + t * 4;
  o[0] = __float2bfloat16(d0 * rs * gg.x + bb.x);
  o[1] = __float2bfloat16(d1 * rs * gg.y + bb.y);
  o[2] = __float2bfloat16(d2 * rs * gg.z + bb.z);
  o[3] = __float2bfloat16(d3 * rs * gg.w + bb.w);
}

// ---------------------------------------------------------------------------
// gemmA: BM=256,BN=256,BK=64, 512 thr, 8 waves (2M x 4N), wave tile 128x64.
// 4 phases/K-tile x 16 MFMA (split by m-half and kk). 8 ds_read_b128/phase.
// Load FIFO per tile: p0:[A0,A2] p1:[B0,B1] p2:[B2,B3] p3:[A1,A3].
// Waits: end-p1 vmcnt(4) (protects A1/A3 for p2), end-p3 vmcnt(2)
// (protects next-tile p0: A0,A2,B0..B3). vmcnt(0) only on the last tile.
// MODE 0: QKV permute+split bf16; MODE 1: ReLU bf16 row-major.
// ---------------------------------------------------------------------------
template <int MODE>
__global__ __launch_bounds__(512, 2) void gemmA(
    const bf16* __restrict__ A, const bf16* __restrict__ Bw,
    const float* __restrict__ bias0, const float* __restrict__ bias1,
    const float* __restrict__ bias2,
    void* __restrict__ out, int M, int N, int K) {
  constexpr int ASZ = 256 * 128;
  constexpr int TILE = ASZ + 256 * 128;  // 64 KB
  __shared__ __align__(16) char smem[2 * TILE];

  const int t = threadIdx.x;
  const int l = t & 63, l15 = l & 15, l4 = (l >> 4) & 3;
  const int w = t >> 6, wm = w >> 2, wn = w & 3;
  // XCD-aware block swizzle (nwg % 8 == 0 for all our grids)
  const int gx = gridDim.x;
  const int nwg = gx * gridDim.y;
  const int bid0 = blockIdx.y * gx + blockIdx.x;
  const int bid = (bid0 & 7) * (nwg >> 3) + (bid0 >> 3);
  const int m0 = (bid / gx) * 256, n0 = (bid % gx) * 256;

  const int sr = t >> 3;
  const int scol = 8 * ((t & 7) ^ (sr & 7));
  const int swz = (l15 & 7) << 4;
  int coff[2];
  coff[0] = (l4 * 16) ^ swz;
  coff[1] = (64 + l4 * 16) ^ swz;

#define ST_A(j, kb, buf)                                          \
  gload16(&A[(size_t)(m0 + (j) * 64 + sr) * K + (kb) + scol],     \
          (void*)(smem + (buf) * TILE + (j) * 8192 + t * 16))
#define ST_B(j, kb, buf)                                          \
  gload16(&Bw[(size_t)(n0 + (j) * 64 + sr) * K + (kb) + scol],    \
          (void*)(smem + (buf) * TILE + ASZ + (j) * 8192 + t * 16))

  f32x4 acc[8][4] = {};
  const int NTm = K >> 6;

  // prologue: tile 0 in FIFO order
  ST_A(0, 0, 0); ST_A(2, 0, 0);
  ST_B(0, 0, 0); ST_B(1, 0, 0); ST_B(2, 0, 0); ST_B(3, 0, 0);
  ST_A(1, 0, 0); ST_A(3, 0, 0);
  asm volatile("s_waitcnt vmcnt(2)" ::: "memory");
  __builtin_amdgcn_s_barrier();

#define PHASE_A(p)                                                                 \
  {                                                                                \
    constexpr int kk = (p) & 1;                                                    \
    constexpr int mh = ((p) >> 1) * 4;                                             \
    bf16x8 af[4], bf[4];                                                           \
    _Pragma("unroll") for (int m = 0; m < 4; ++m)                                  \
      af[m] = *(const bf16x8*)(cb + (wm * 128 + (mh + m) * 16 + l15) * 128 +       \
                               coff[kk]);                                          \
    _Pragma("unroll") for (int n = 0; n < 4; ++n)                                  \
      bf[n] = *(const bf16x8*)(cb + ASZ + (wn * 64 + n * 16 + l15) * 128 +         \
                               coff[kk]);                                          \
    if (hasNext) {                                                                 \
      if ((p) == 0) { ST_A(0, kbn, nb); ST_A(2, kbn, nb); }                        \
      else if ((p) == 1) { ST_B(0, kbn, nb); ST_B(1, kbn, nb); }                   \
      else if ((p) == 2) { ST_B(2, kbn, nb); ST_B(3, kbn, nb); }                   \
      else { ST_A(1, kbn, nb); ST_A(3, kbn, nb); }                                 \
    }                                                                              \
    __builtin_amdgcn_s_barrier();                                                  \
    asm volatile("s_waitcnt lgkmcnt(0)" ::: "memory");                             \
    __builtin_amdgcn_sched_barrier(0);                                             \
    __builtin_amdgcn_s_setprio(1);                                                 \
    _Pragma("unroll") for (int m = 0; m < 4; ++m)                                  \
      _Pragma("unroll") for (int n = 0; n < 4; ++n)                                \
        acc[mh + m][n] = __builtin_amdgcn_mfma_f32_16x16x32_bf16(                  \
            af[m], bf[n], acc[mh + m][n], 0, 0, 0);                                \
    __builtin_amdgcn_s_setprio(0);                                                 \
    if ((p) == 1) {                                                                \
      if (hasNext) asm volatile("s_waitcnt vmcnt(4)" ::: "memory");                \
      else asm volatile("s_waitcnt vmcnt(0)" ::: "memory");                        \
    }                                                                              \
    if ((p) == 3 && hasNext)                                                       \
      asm volatile("s_waitcnt vmcnt(2)" ::: "memory");                             \
    __builtin_amdgcn_s_barrier();                                                  \
  }

  for (int kt = 0; kt < NTm; ++kt) {
    const char* cb = smem + (kt & 1) * TILE;
    const int nb = (kt & 1) ^ 1;
    const int kbn = (kt + 1) << 6;
    const bool hasNext = (kt + 1 < NTm);
    PHASE_A(0) PHASE_A(1) PHASE_A(2) PHASE_A(3)
  }
#undef PHASE_A
#undef ST_A
#undef ST_B

#pragma unroll
  for (int mf = 0; mf < 8; ++mf) {
#pragma unroll
    for (int nf = 0; nf < 4; ++nf) {
      const int col = n0 + wn * 64 + nf * 16 + l15;
      float bb;
      if constexpr (MODE == 0) {
        const int sel = col >> 10;
        const float* bp = (sel == 0) ? bias0 : ((sel == 1) ? bias1 : bias2);
        bb = bp[col & 1023];
      } else {
        bb = bias0[col];
      }
#pragma unroll
      for (int r = 0; r < 4; ++r) {
        const int row = m0 + wm * 128 + mf * 16 + l4 * 4 + r;
        float y = acc[mf][nf][r] + bb;
        if constexpr (MODE == 1) y = fmaxf(y, 0.f);
        if constexpr (MODE == 0) {
          const int sel = col >> 10;
          const int c10 = col & 1023;
          const size_t dst = (size_t)sel * (NTOK * 1024) +
                             (size_t)((row >> 11) * NHEAD + (c10 >> 6)) * (SEQ * HEAD_DIM) +
                             (size_t)(row & (SEQ - 1)) * HEAD_DIM + (c10 & 63);
          ((bf16*)out)[dst] = __float2bfloat16(y);
        } else {
          ((bf16*)out)[(size_t)row * N + col] = __float2bfloat16(y);
        }
      }
    }
  }
}

// ---------------------------------------------------------------------------
// gemmB: BM=128,BN=256,BK=64, 512 thr, 8 waves (2M x 4N), wave tile 64x64.
// 2 phases/K-tile x 16 MFMA (kk-split). 3 LDS buffers, 2-tiles-ahead
// prefetch: loads for tile t+2 issued during t (3/phase); single wait
// vmcnt(6) per tile -> ~2 K-tiles of latency cover. f32 out += res.
// ---------------------------------------------------------------------------
__global__ __launch_bounds__(512, 2) void gemmB(
    const bf16* __restrict__ A, const bf16* __restrict__ Bw,
    const float* __restrict__ bias, const float* __restrict__ res,
    float* __restrict__ out, int M, int N, int K) {
  constexpr int ASZ = 128 * 128;
  constexpr int TILE = ASZ + 256 * 128;  // 48 KB
  __shared__ __align__(16) char smem[3 * TILE];  // 144 KB

  const int t = threadIdx.x;
  const int l = t & 63, l15 = l & 15, l4 = (l >> 4) & 3;
  const int w = t >> 6, wm = w >> 2, wn = w & 3;
  const int gx = gridDim.x;
  const int nwg = gx * gridDim.y;
  const int bid0 = blockIdx.y * gx + blockIdx.x;
  const int bid = (bid0 & 7) * (nwg >> 3) + (bid0 >> 3);
  const int m0 = (bid / gx) * 128, n0 = (bid % gx) * 256;

  const int sr = t >> 3;
  const int scol = 8 * ((t & 7) ^ (sr & 7));
  const int swz = (l15 & 7) << 4;
  int coff[2];
  coff[0] = (l4 * 16) ^ swz;
  coff[1] = (64 + l4 * 16) ^ swz;

#define ST_A(j, kb, buf)                                          \
  gload16(&A[(size_t)(m0 + (j) * 64 + sr) * K + (kb) + scol],     \
          (void*)(smem + (buf) * TILE + (j) * 8192 + t * 16))
#define ST_B(j, kb, buf)                                          \
  gload16(&Bw[(size_t)(n0 + (j) * 64 + sr) * K + (kb) + scol],    \
          (void*)(smem + (buf) * TILE + ASZ + (j) * 8192 + t * 16))

  f32x4 acc[4][4] = {};
  const int NTm = K >> 6;

  // prologue: stage tiles 0 and 1
  ST_B(0, 0, 0); ST_B(1, 0, 0); ST_B(2, 0, 0);
  ST_B(3, 0, 0); ST_A(0, 0, 0); ST_A(1, 0, 0);
  ST_B(0, 64, 1); ST_B(1, 64, 1); ST_B(2, 64, 1);
  ST_B(3, 64, 1); ST_A(0, 64, 1); ST_A(1, 64, 1);
  asm volatile("s_waitcnt vmcnt(6)" ::: "memory");
  __builtin_amdgcn_s_barrier();

#define PHASE_B(p)                                                                 \
  {                                                                                \
    constexpr int kk = (p);                                                        \
    bf16x8 af[4], bf[4];                                                           \
    _Pragma("unroll") for (int m = 0; m < 4; ++m)                                  \
      af[m] = *(const bf16x8*)(cb + (wm * 64 + m * 16 + l15) * 128 + coff[kk]);    \
    _Pragma("unroll") for (int n = 0; n < 4; ++n)                                  \
      bf[n] = *(const bf16x8*)(cb + ASZ + (wn * 64 + n * 16 + l15) * 128 +         \
                               coff[kk]);                                          \
    if (iss) {                                                                     \
      if ((p) == 0) { ST_B(0, kbn, nb); ST_B(1, kbn, nb); ST_B(2, kbn, nb); }      \
      else { ST_B(3, kbn, nb); ST_A(0, kbn, nb); ST_A(1, kbn, nb); }               \
    }                                                                              \
    __builtin_amdgcn_s_barrier();                                                  \
    asm volatile("s_waitcnt lgkmcnt(0)" ::: "memory");                             \
    __builtin_amdgcn_sched_barrier(0);                                             \
    __builtin_amdgcn_s_setprio(1);                                                 \
    _Pragma("unroll") for (int m = 0; m < 4; ++m)                                  \
      _Pragma("unroll") for (int n = 0; n < 4; ++n)                                \
        acc[m][n] = __builtin_amdgcn_mfma_f32_16x16x32_bf16(                       \
            af[m], bf[n], acc[m][n], 0, 0, 0);                                     \
    __builtin_amdgcn_s_setprio(0);                                                 \
    if ((p) == 1) {                                                                \
      if (iss) asm volatile("s_waitcnt vmcnt(6)" ::: "memory");                    \
      else asm volatile("s_waitcnt vmcnt(0)" ::: "memory");                        \
    }                                                                              \
    __builtin_amdgcn_s_barrier();                                                  \
  }

  for (int kt = 0; kt < NTm; ++kt) {
    const char* cb = smem + (kt % 3) * TILE;
    const int nb = (kt + 2) % 3;
    const int kbn = (kt + 2) << 6;
    const bool iss = (kt + 2 < NTm);
    PHASE_B(0) PHASE_B(1)
  }
#undef PHASE_B
#undef ST_A
#undef ST_B

#pragma unroll
  for (int mf = 0; mf < 4; ++mf) {
#pragma unroll
    for (int nf = 0; nf < 4; ++nf) {
      const int col = n0 + wn * 64 + nf * 16 + l15;
      const float bb = bias[col];
#pragma unroll
      for (int r = 0; r < 4; ++r) {
        const int row = m0 + wm * 64 + mf * 16 + l4 * 4 + r;
        out[(size_t)row * N + col] = acc[mf][nf][r] + bb + res[(size_t)row * N + col];
      }
    }
  }
}

// ---------------------------------------------------------------------------
// Flash attention v4: swapped QK^T, in-register softmax/P, defer-rescale,
// rowsum via MFMA-with-ones. QBLK=128 (4 waves x 32 q-rows) -> 1024 blocks.
// Q,K,V: [B,H,T,64] bf16. O: [B,T,1024] bf16.
// ---------------------------------------------------------------------------
#define SCL 0.18033688011112042f  // 0.125 * log2(e)
#define NT (SEQ / 64)

__global__ __launch_bounds__(256, 4) void flash_attn(
    const bf16* __restrict__ Q, const bf16* __restrict__ K,
    const bf16* __restrict__ V, bf16* __restrict__ O) {
  __shared__ char smem[32768];  // K dbuf @0..16K, Vt dbuf @16K..32K
  const int t = threadIdx.x;
  const int w = t >> 6, l = t & 63;
  const int l15 = l & 15, l4 = l >> 4;
  // XCD swizzle: 1024 blocks -> 128 consecutive per XCD (bh-groups stay local)
  const int bid0 = blockIdx.y * 16 + blockIdx.x;
  const int bid = (bid0 & 7) * 128 + (bid0 >> 3);
  const int bx = bid & 15, bh = bid >> 4;
  const size_t base = (size_t)bh * (SEQ * HEAD_DIM);
  const int q0 = bx * 128 + w * 32;
  const short* Vg = (const short*)V;
  const int dV = w * 16 + l15;

  int krow[4], kswz[4];
#pragma unroll
  for (int ni = 0; ni < 4; ++ni) {
    const int kr = (ni >> 1) * 32 + (ni & 1) * 4 + (l15 >> 2) * 8 + (l15 & 3);
    krow[ni] = kr * 128;
    kswz[ni] = ((kr & 3) | (((kr >> 3) & 1) << 2)) << 4;
  }

  bf16x8 qf[2][2];
#pragma unroll
  for (int mi = 0; mi < 2; ++mi)
#pragma unroll
    for (int kk = 0; kk < 2; ++kk)
      qf[mi][kk] = *(const bf16x8*)&Q[base + (size_t)(q0 + mi * 16 + l15) * 64 + kk * 32 + l4 * 8];

  bf16x8 ones;
#pragma unroll
  for (int j = 0; j < 8; ++j) ones[j] = (short)0x3F80;  // bf16 1.0

  f32x4 accO[2][4] = {};
  float m_run[2], l_run[2];
#pragma unroll
  for (int mi = 0; mi < 2; ++mi) { m_run[mi] = -1e30f; l_run[mi] = 0.f; }

  short vg[16];

#define STAGE_K(bufofs, kt)                                                       \
  {                                                                               \
    _Pragma("unroll") for (int i = 0; i < 2; ++i) {                               \
      const int F = i * 256 + t;                                                  \
      const int r_ = F >> 3;                                                      \
      const int gk_ = (r_ & 3) | (((r_ >> 3) & 1) << 2);                          \
      const int c_ = 8 * ((F & 7) ^ gk_);                                         \
      gload16(&K[base + (size_t)((kt) + r_) * 64 + c_],                           \
              (void*)(smem + (bufofs) + (i * 256 + w * 64) * 16));                \
    }                                                                             \
  }

#define V_GATHER(kt)                                                              \
  {                                                                               \
    _Pragma("unroll") for (int h_ = 0; h_ < 2; ++h_)                              \
        _Pragma("unroll") for (int j_ = 0; j_ < 8; ++j_)                          \
            vg[h_ * 8 + j_] =                                                     \
        Vg[base + (size_t)((kt) + h_ * 32 + l4 * 8 + j_) * 64 + dV];              \
  }

#define VT_WRITE(bufofs)                                                          \
  {                                                                               \
    _Pragma("unroll") for (int h_ = 0; h_ < 2; ++h_) {                            \
      bf16x8 vv;                                                                  \
      _Pragma("unroll") for (int j_ = 0; j_ < 8; ++j_) vv[j_] = vg[h_ * 8 + j_];  \
      const int kb_ = (h_ * 64 + l4 * 16) ^ ((dV & 7) << 4);                      \
      *(bf16x8*)(smem + (bufofs) + dV * 128 + kb_) = vv;                          \
    }                                                                             \
  }

  STAGE_K(0, 0);
  V_GATHER(0);
  VT_WRITE(16384);
  __syncthreads();

  for (int it = 0; it < NT; ++it) {
    const int cur = it & 1;
    const char* Kb = (const char*)smem + cur * 8192;
    const char* Vb = (const char*)smem + 16384 + cur * 8192;
    const bool pre = (it + 1 < NT);
    if (pre) {
      STAGE_K((cur ^ 1) * 8192, (it + 1) * 64);
      V_GATHER((it + 1) * 64);
    }

    // ---- QK^T (swapped) + softmax ----
    bf16x8 kf[2][4];
#pragma unroll
    for (int kk = 0; kk < 2; ++kk)
#pragma unroll
      for (int ni = 0; ni < 4; ++ni)
        kf[kk][ni] = *(const bf16x8*)(Kb + krow[ni] + ((kk * 64 + l4 * 16) ^ kswz[ni]));

    unsigned pw[2][8];
#pragma unroll
    for (int mi = 0; mi < 2; ++mi) {
      f32x4 s[4] = {};
      __builtin_amdgcn_s_setprio(1);
#pragma unroll
      for (int kk = 0; kk < 2; ++kk)
#pragma unroll
        for (int ni = 0; ni < 4; ++ni)
          s[ni] = __builtin_amdgcn_mfma_f32_16x16x32_bf16(kf[kk][ni], qf[mi][kk], s[ni], 0, 0, 0);
      __builtin_amdgcn_s_setprio(0);

      float mx = s[0][0];
#pragma unroll
      for (int ni = 0; ni < 4; ++ni)
#pragma unroll
        for (int r = 0; r < 4; ++r) mx = fmaxf(mx, s[ni][r]);
      mx = fmaxf(mx, __shfl_xor(mx, 16));
      mx = fmaxf(mx, __shfl_xor(mx, 32));
      const float mxs = mx * SCL;
      // defer-rescale (T13): only rescale when the running max grows by >8
      if (__any(mxs > m_run[mi] + 8.f)) {
        const float mn = fmaxf(m_run[mi], mxs);
        const float c = exp2f(m_run[mi] - mn);
        m_run[mi] = mn;
        l_run[mi] *= c;
#pragma unroll
        for (int ni = 0; ni < 4; ++ni)
#pragma unroll
          for (int r = 0; r < 4; ++r) accO[mi][ni][r] *= c;
      }
#pragma unroll
      for (int ni = 0; ni < 4; ++ni)
#pragma unroll
        for (int r = 0; r < 4; ++r)
          s[ni][r] = exp2f(fmaf(s[ni][r], SCL, -m_run[mi]));
#pragma unroll
      for (int kk = 0; kk < 2; ++kk)
#pragma unroll
        for (int jj = 0; jj < 4; ++jj) {
          const int ni = 2 * kk + (jj >> 1);
          pw[mi][kk * 4 + jj] = pkbf16(s[ni][2 * (jj & 1)], s[ni][2 * (jj & 1) + 1]);
        }
    }

    // ---- PV: O^T += V^T P, rowsum via MFMA-with-ones ----
    f32x4 zz[2] = {};
#pragma unroll
    for (int kk = 0; kk < 2; ++kk) {
      bf16x8 vf[4];
#pragma unroll
      for (int ni = 0; ni < 4; ++ni)
        vf[ni] = *(const bf16x8*)(Vb + (ni * 16 + l15) * 128 +
                                  ((kk * 64 + l4 * 16) ^ ((l15 & 7) << 4)));
#pragma unroll
      for (int mi = 0; mi < 2; ++mi) {
        union { unsigned u[4]; bf16x8 h; } pb;
#pragma unroll
        for (int jj = 0; jj < 4; ++jj) pb.u[jj] = pw[mi][kk * 4 + jj];
        __builtin_amdgcn_s_setprio(1);
#pragma unroll
        for (int ni = 0; ni < 4; ++ni)
          accO[mi][ni] = __builtin_amdgcn_mfma_f32_16x16x32_bf16(vf[ni], pb.h, accO[mi][ni], 0, 0, 0);
        zz[mi] = __builtin_amdgcn_mfma_f32_16x16x32_bf16(ones, pb.h, zz[mi], 0, 0, 0);
        __builtin_amdgcn_s_setprio(0);
      }
    }
#pragma unroll
    for (int mi = 0; mi < 2; ++mi) l_run[mi] += zz[mi][0];

    if (pre) VT_WRITE(16384 + (cur ^ 1) * 8192);
    __syncthreads();
  }

  // ---- epilogue: bounce O^T through LDS (4 KB/wave) for coalesced stores ----
  char* ob = smem + w * 4096;
#pragma unroll
  for (int mi = 0; mi < 2; ++mi) {
    const float inv = 1.f / l_run[mi];
    const int qr = mi * 16 + l15;
    const int sw = (qr & 7) << 4;
#pragma unroll
    for (int ni = 0; ni < 4; ++ni)
#pragma unroll
      for (int rr = 0; rr < 2; ++rr) {
        const unsigned pk = pkbf16(accO[mi][ni][2 * rr] * inv, accO[mi][ni][2 * rr + 1] * inv);
        *(unsigned*)(ob + qr * 128 + ((ni * 32 + l4 * 8 + 4 * rr) ^ sw)) = pk;
      }
  }
  asm volatile("s_waitcnt lgkmcnt(0)" ::: "memory");
  __builtin_amdgcn_sched_barrier(0);

  const int b = bh >> 4, h = bh & 15;
  const int hr = l >> 1, hf = l & 1;
  const size_t orow = ((size_t)b * SEQ + bx * 128 + w * 32 + hr) * D_MODEL + h * HEAD_DIM + hf * 32;
#pragma unroll
  for (int c = 0; c < 4; ++c) {
    bf16x8 vv = *(const bf16x8*)(ob + hr * 128 + (((hf * 64) + c * 16) ^ ((hr & 7) << 4)));
    *(bf16x8*)&O[orow + c * 8] = vv;
  }
}

// ---------------------------------------------------------------------------
extern "C" void kernel_launch(void* const* d_in, const int* in_sizes, int n_in,
                              void* d_out, int out_size, void* d_ws, size_t ws_size,
                              hipStream_t stream) {
  const float* x     = (const float*)d_in[0];
  const float* Wq    = (const float*)d_in[1];
  const float* bq    = (const float*)d_in[2];
  const float* Wk    = (const float*)d_in[3];
  const float* bk    = (const float*)d_in[4];
  const float* Wv    = (const float*)d_in[5];
  const float* bv    = (const float*)d_in[6];
  const float* Wo    = (const float*)d_in[7];
  const float* bo    = (const float*)d_in[8];
  const float* W1    = (const float*)d_in[9];
  const float* b1    = (const float*)d_in[10];
  const float* W2    = (const float*)d_in[11];
  const float* b2    = (const float*)d_in[12];
  const float* ln1_g = (const float*)d_in[13];
  const float* ln1_b = (const float*)d_in[14];
  const float* ln2_g = (const float*)d_in[15];
  const float* ln2_b = (const float*)d_in[16];

  const size_t MB = 1ull << 20;
  char* ws = (char*)d_ws;
  bf16* wqkv = (bf16*)(ws + 0 * MB);    // 6 MB: [Wq;Wk;Wv] rows, K-contig
  bf16* wo_b = (bf16*)(ws + 6 * MB);
  bf16* w1_b = (bf16*)(ws + 8 * MB);    // 8 MB
  bf16* w2_b = (bf16*)(ws + 16 * MB);   // 8 MB
  bf16* xn   = (bf16*)(ws + 24 * MB);   // 16 MB: xn / attn_out / xn2
  bf16* qb   = (bf16*)(ws + 40 * MB);   // 16 MB (q,k,v contiguous: sel stride)
  bf16* kbuf = (bf16*)(ws + 56 * MB);   // 16 MB
  bf16* vb   = (bf16*)(ws + 72 * MB);   // 16 MB
  bf16* hb   = (bf16*)(ws + 40 * MB);   // 64 MB (reuses q/k/v after attention)
  float* x1  = (float*)(ws + 104 * MB); // 32 MB

  cvt_f32_bf16<<<1024, 256, 0, stream>>>(Wq, wqkv, 1048576);
  cvt_f32_bf16<<<1024, 256, 0, stream>>>(Wk, wqkv + 1048576, 1048576);
  cvt_f32_bf16<<<1024, 256, 0, stream>>>(Wv, wqkv + 2097152, 1048576);
  cvt_f32_bf16<<<1024, 256, 0, stream>>>(Wo, wo_b, 1048576);
  cvt_f32_bf16<<<4096, 256, 0, stream>>>(W1, w1_b, 4194304);
  cvt_f32_bf16<<<4096, 256, 0, stream>>>(W2, w2_b, 4194304);

  layernorm_kernel<<<NTOK, 256, 0, stream>>>(x, ln1_g, ln1_b, xn);

  // QKV fused: [8192,3072] = xn @ wqkv^T -> permuted/split q/k/v
  gemmA<0><<<dim3(3072 / 256, NTOK / 256), 512, 0, stream>>>(
      xn, wqkv, bq, bk, bv, qb, NTOK, 3072, 1024);

  flash_attn<<<dim3(SEQ / 128, 4 * NHEAD), 256, 0, stream>>>(qb, kbuf, vb, xn);

  // Wo + residual(x) -> x1 (fp32)
  gemmB<<<dim3(1024 / 256, NTOK / 128), 512, 0, stream>>>(
      xn, wo_b, bo, x, x1, NTOK, 1024, 1024);

  layernorm_kernel<<<NTOK, 256, 0, stream>>>(x1, ln2_g, ln2_b, xn);

  // FFN1 (ReLU) -> hb
  gemmA<1><<<dim3(D_FF / 256, NTOK / 256), 512, 0, stream>>>(
      xn, w1_b, b1, b1, b1, hb, NTOK, D_FF, 1024);

  // FFN2 + residual(x1) -> d_out (fp32)
  gemmB<<<dim3(1024 / 256, NTOK / 128), 512, 0, stream>>>(
      hb, w2_b, b2, x1, (float*)d_out, NTOK, 1024, D_FF);
}

// Round 6
// 426.566 us; speedup vs baseline: 1.6286x; 1.0118x over previous
//
#include <hip/hip_runtime.h>
#include <hip/hip_bf16.h>

using bf16 = __hip_bfloat16;
typedef __attribute__((ext_vector_type(8))) short bf16x8;
typedef __attribute__((ext_vector_type(4))) float f32x4;

#define D_MODEL 1024
#define NHEAD 16
#define HEAD_DIM 64
#define D_FF 4096
#define SEQ 2048
#define NTOK 8192  // 4 * 2048

__device__ __forceinline__ void gload16(const void* g, void* l) {
  __builtin_amdgcn_global_load_lds((const __attribute__((address_space(1))) void*)g,
                                   (__attribute__((address_space(3))) void*)l, 16, 0, 0);
}

__device__ __forceinline__ unsigned pkbf16(float lo, float hi) {
  unsigned r;
  asm("v_cvt_pk_bf16_f32 %0, %1, %2" : "=v"(r) : "v"(lo), "v"(hi));
  return r;
}

// ---------------------------------------------------------------------------
// f32 -> bf16 conversion, all 6 weight matrices in ONE launch.
// blocks 0..4095: W1 (4M elems); 4096..8191: W2; then 4x1024 blocks for
// Wq, Wk, Wv (into wqkv contiguous) and Wo.
// ---------------------------------------------------------------------------
__global__ __launch_bounds__(256) void cvt_all(
    const float* __restrict__ W1, const float* __restrict__ W2,
    const float* __restrict__ Wq, const float* __restrict__ Wk,
    const float* __restrict__ Wv, const float* __restrict__ Wo,
    bf16* __restrict__ w1_b, bf16* __restrict__ w2_b,
    bf16* __restrict__ wqkv, bf16* __restrict__ wo_b) {
  const int bid = blockIdx.x;
  const float* src;
  bf16* dst;
  int lb;
  if (bid < 4096) { src = W1; dst = w1_b; lb = bid; }
  else if (bid < 8192) { src = W2; dst = w2_b; lb = bid - 4096; }
  else {
    const int j = (bid - 8192) >> 10;
    lb = (bid - 8192) & 1023;
    if (j == 0) { src = Wq; dst = wqkv; }
    else if (j == 1) { src = Wk; dst = wqkv + 1048576; }
    else if (j == 2) { src = Wv; dst = wqkv + 2097152; }
    else { src = Wo; dst = wo_b; }
  }
  const int i = (lb * 256 + threadIdx.x) * 4;
  const float4 v = *(const float4*)&src[i];
  dst[i + 0] = __float2bfloat16(v.x);
  dst[i + 1] = __float2bfloat16(v.y);
  dst[i + 2] = __float2bfloat16(v.z);
  dst[i + 3] = __float2bfloat16(v.w);
}

// ---------------------------------------------------------------------------
// LayerNorm over D=1024, fp32 in -> bf16 out. One block (256 thr) per row.
// ---------------------------------------------------------------------------
__global__ __launch_bounds__(256) void layernorm_kernel(
    const float* __restrict__ xin, const float* __restrict__ g,
    const float* __restrict__ bta, bf16* __restrict__ out) {
  const int row = blockIdx.x, t = threadIdx.x;
  const float4 v = *(const float4*)&xin[(size_t)row * D_MODEL + t * 4];
  float s = v.x + v.y + v.z + v.w;
#pragma unroll
  for (int m = 1; m < 64; m <<= 1) s += __shfl_xor(s, m);
  __shared__ float red[4], red2[4];
  const int w = t >> 6, l = t & 63;
  if (l == 0) red[w] = s;
  __syncthreads();
  const float mu = (red[0] + red[1] + red[2] + red[3]) * (1.f / 1024.f);
  const float d0 = v.x - mu, d1 = v.y - mu, d2 = v.z - mu, d3 = v.w - mu;
  float q = d0 * d0 + d1 * d1 + d2 * d2 + d3 * d3;
#pragma unroll
  for (int m = 1; m < 64; m <<= 1) q += __shfl_xor(q, m);
  if (l == 0) red2[w] = q;
  __syncthreads();
  const float var = (red2[0] + red2[1] + red2[2] + red2[3]) * (1.f / 1024.f);
  const float rs = rsqrtf(var + 1e-5f);
  const float4 gg = *(const float4*)&g[t * 4];
  const float4 bb = *(const float4*)&bta[t * 4];
  bf16* o = out + (size_t)row * D_MODEL + t * 4;
  o[0] = __float2bfloat16(d0 * rs * gg.x + bb.x);
  o[1] = __float2bfloat16(d1 * rs * gg.y + bb.y);
  o[2] = __float2bfloat16(d2 * rs * gg.z + bb.z);
  o[3] = __float2bfloat16(d3 * rs * gg.w + bb.w);
}

// ---------------------------------------------------------------------------
// gemmA: BM=256,BN=256,BK=64, 512 thr, 8 waves (2M x 4N), wave tile 128x64.
// 4 phases/K-tile x 16 MFMA. (unchanged from round 5)
// ---------------------------------------------------------------------------
template <int MODE>
__global__ __launch_bounds__(512, 2) void gemmA(
    const bf16* __restrict__ A, const bf16* __restrict__ Bw,
    const float* __restrict__ bias0, const float* __restrict__ bias1,
    const float* __restrict__ bias2,
    void* __restrict__ out, int M, int N, int K) {
  constexpr int ASZ = 256 * 128;
  constexpr int TILE = ASZ + 256 * 128;  // 64 KB
  __shared__ __align__(16) char smem[2 * TILE];

  const int t = threadIdx.x;
  const int l = t & 63, l15 = l & 15, l4 = (l >> 4) & 3;
  const int w = t >> 6, wm = w >> 2, wn = w & 3;
  const int gx = gridDim.x;
  const int nwg = gx * gridDim.y;
  const int bid0 = blockIdx.y * gx + blockIdx.x;
  const int bid = (bid0 & 7) * (nwg >> 3) + (bid0 >> 3);
  const int m0 = (bid / gx) * 256, n0 = (bid % gx) * 256;

  const int sr = t >> 3;
  const int scol = 8 * ((t & 7) ^ (sr & 7));
  const int swz = (l15 & 7) << 4;
  int coff[2];
  coff[0] = (l4 * 16) ^ swz;
  coff[1] = (64 + l4 * 16) ^ swz;

#define ST_A(j, kb, buf)                                          \
  gload16(&A[(size_t)(m0 + (j) * 64 + sr) * K + (kb) + scol],     \
          (void*)(smem + (buf) * TILE + (j) * 8192 + t * 16))
#define ST_B(j, kb, buf)                                          \
  gload16(&Bw[(size_t)(n0 + (j) * 64 + sr) * K + (kb) + scol],    \
          (void*)(smem + (buf) * TILE + ASZ + (j) * 8192 + t * 16))

  f32x4 acc[8][4] = {};
  const int NTm = K >> 6;

  ST_A(0, 0, 0); ST_A(2, 0, 0);
  ST_B(0, 0, 0); ST_B(1, 0, 0); ST_B(2, 0, 0); ST_B(3, 0, 0);
  ST_A(1, 0, 0); ST_A(3, 0, 0);
  asm volatile("s_waitcnt vmcnt(2)" ::: "memory");
  __builtin_amdgcn_s_barrier();

#define PHASE_A(p)                                                                 \
  {                                                                                \
    constexpr int kk = (p) & 1;                                                    \
    constexpr int mh = ((p) >> 1) * 4;                                             \
    bf16x8 af[4], bf[4];                                                           \
    _Pragma("unroll") for (int m = 0; m < 4; ++m)                                  \
      af[m] = *(const bf16x8*)(cb + (wm * 128 + (mh + m) * 16 + l15) * 128 +       \
                               coff[kk]);                                          \
    _Pragma("unroll") for (int n = 0; n < 4; ++n)                                  \
      bf[n] = *(const bf16x8*)(cb + ASZ + (wn * 64 + n * 16 + l15) * 128 +         \
                               coff[kk]);                                          \
    if (hasNext) {                                                                 \
      if ((p) == 0) { ST_A(0, kbn, nb); ST_A(2, kbn, nb); }                        \
      else if ((p) == 1) { ST_B(0, kbn, nb); ST_B(1, kbn, nb); }                   \
      else if ((p) == 2) { ST_B(2, kbn, nb); ST_B(3, kbn, nb); }                   \
      else { ST_A(1, kbn, nb); ST_A(3, kbn, nb); }                                 \
    }                                                                              \
    __builtin_amdgcn_s_barrier();                                                  \
    asm volatile("s_waitcnt lgkmcnt(0)" ::: "memory");                             \
    __builtin_amdgcn_sched_barrier(0);                                             \
    __builtin_amdgcn_s_setprio(1);                                                 \
    _Pragma("unroll") for (int m = 0; m < 4; ++m)                                  \
      _Pragma("unroll") for (int n = 0; n < 4; ++n)                                \
        acc[mh + m][n] = __builtin_amdgcn_mfma_f32_16x16x32_bf16(                  \
            af[m], bf[n], acc[mh + m][n], 0, 0, 0);                                \
    __builtin_amdgcn_s_setprio(0);                                                 \
    if ((p) == 1) {                                                                \
      if (hasNext) asm volatile("s_waitcnt vmcnt(4)" ::: "memory");                \
      else asm volatile("s_waitcnt vmcnt(0)" ::: "memory");                        \
    }                                                                              \
    if ((p) == 3 && hasNext)                                                       \
      asm volatile("s_waitcnt vmcnt(2)" ::: "memory");                             \
    __builtin_amdgcn_s_barrier();                                                  \
  }

  for (int kt = 0; kt < NTm; ++kt) {
    const char* cb = smem + (kt & 1) * TILE;
    const int nb = (kt & 1) ^ 1;
    const int kbn = (kt + 1) << 6;
    const bool hasNext = (kt + 1 < NTm);
    PHASE_A(0) PHASE_A(1) PHASE_A(2) PHASE_A(3)
  }
#undef PHASE_A
#undef ST_A
#undef ST_B

#pragma unroll
  for (int mf = 0; mf < 8; ++mf) {
#pragma unroll
    for (int nf = 0; nf < 4; ++nf) {
      const int col = n0 + wn * 64 + nf * 16 + l15;
      float bb;
      if constexpr (MODE == 0) {
        const int sel = col >> 10;
        const float* bp = (sel == 0) ? bias0 : ((sel == 1) ? bias1 : bias2);
        bb = bp[col & 1023];
      } else {
        bb = bias0[col];
      }
#pragma unroll
      for (int r = 0; r < 4; ++r) {
        const int row = m0 + wm * 128 + mf * 16 + l4 * 4 + r;
        float y = acc[mf][nf][r] + bb;
        if constexpr (MODE == 1) y = fmaxf(y, 0.f);
        if constexpr (MODE == 0) {
          const int sel = col >> 10;
          const int c10 = col & 1023;
          const size_t dst = (size_t)sel * (NTOK * 1024) +
                             (size_t)((row >> 11) * NHEAD + (c10 >> 6)) * (SEQ * HEAD_DIM) +
                             (size_t)(row & (SEQ - 1)) * HEAD_DIM + (c10 & 63);
          ((bf16*)out)[dst] = __float2bfloat16(y);
        } else {
          ((bf16*)out)[(size_t)row * N + col] = __float2bfloat16(y);
        }
      }
    }
  }
}

// ---------------------------------------------------------------------------
// gemmB: BM=128,BN=256,BK=64, 512 thr, 8 waves (2M x 4N), wave tile 64x64.
// 2 phases/K-tile x 16 MFMA, 3 LDS buffers, 2-tiles-ahead prefetch.
// (unchanged from round 5)
// ---------------------------------------------------------------------------
__global__ __launch_bounds__(512, 2) void gemmB(
    const bf16* __restrict__ A, const bf16* __restrict__ Bw,
    const float* __restrict__ bias, const float* __restrict__ res,
    float* __restrict__ out, int M, int N, int K) {
  constexpr int ASZ = 128 * 128;
  constexpr int TILE = ASZ + 256 * 128;  // 48 KB
  __shared__ __align__(16) char smem[3 * TILE];  // 144 KB

  const int t = threadIdx.x;
  const int l = t & 63, l15 = l & 15, l4 = (l >> 4) & 3;
  const int w = t >> 6, wm = w >> 2, wn = w & 3;
  const int gx = gridDim.x;
  const int nwg = gx * gridDim.y;
  const int bid0 = blockIdx.y * gx + blockIdx.x;
  const int bid = (bid0 & 7) * (nwg >> 3) + (bid0 >> 3);
  const int m0 = (bid / gx) * 128, n0 = (bid % gx) * 256;

  const int sr = t >> 3;
  const int scol = 8 * ((t & 7) ^ (sr & 7));
  const int swz = (l15 & 7) << 4;
  int coff[2];
  coff[0] = (l4 * 16) ^ swz;
  coff[1] = (64 + l4 * 16) ^ swz;

#define ST_A(j, kb, buf)                                          \
  gload16(&A[(size_t)(m0 + (j) * 64 + sr) * K + (kb) + scol],     \
          (void*)(smem + (buf) * TILE + (j) * 8192 + t * 16))
#define ST_B(j, kb, buf)                                          \
  gload16(&Bw[(size_t)(n0 + (j) * 64 + sr) * K + (kb) + scol],    \
          (void*)(smem + (buf) * TILE + ASZ + (j) * 8192 + t * 16))

  f32x4 acc[4][4] = {};
  const int NTm = K >> 6;

  ST_B(0, 0, 0); ST_B(1, 0, 0); ST_B(2, 0, 0);
  ST_B(3, 0, 0); ST_A(0, 0, 0); ST_A(1, 0, 0);
  ST_B(0, 64, 1); ST_B(1, 64, 1); ST_B(2, 64, 1);
  ST_B(3, 64, 1); ST_A(0, 64, 1); ST_A(1, 64, 1);
  asm volatile("s_waitcnt vmcnt(6)" ::: "memory");
  __builtin_amdgcn_s_barrier();

#define PHASE_B(p)                                                                 \
  {                                                                                \
    constexpr int kk = (p);                                                        \
    bf16x8 af[4], bf[4];                                                           \
    _Pragma("unroll") for (int m = 0; m < 4; ++m)                                  \
      af[m] = *(const bf16x8*)(cb + (wm * 64 + m * 16 + l15) * 128 + coff[kk]);    \
    _Pragma("unroll") for (int n = 0; n < 4; ++n)                                  \
      bf[n] = *(const bf16x8*)(cb + ASZ + (wn * 64 + n * 16 + l15) * 128 +         \
                               coff[kk]);                                          \
    if (iss) {                                                                     \
      if ((p) == 0) { ST_B(0, kbn, nb); ST_B(1, kbn, nb); ST_B(2, kbn, nb); }      \
      else { ST_B(3, kbn, nb); ST_A(0, kbn, nb); ST_A(1, kbn, nb); }               \
    }                                                                              \
    __builtin_amdgcn_s_barrier();                                                  \
    asm volatile("s_waitcnt lgkmcnt(0)" ::: "memory");                             \
    __builtin_amdgcn_sched_barrier(0);                                             \
    __builtin_amdgcn_s_setprio(1);                                                 \
    _Pragma("unroll") for (int m = 0; m < 4; ++m)                                  \
      _Pragma("unroll") for (int n = 0; n < 4; ++n)                                \
        acc[m][n] = __builtin_amdgcn_mfma_f32_16x16x32_bf16(                       \
            af[m], bf[n], acc[m][n], 0, 0, 0);                                     \
    __builtin_amdgcn_s_setprio(0);                                                 \
    if ((p) == 1) {                                                                \
      if (iss) asm volatile("s_waitcnt vmcnt(6)" ::: "memory");                    \
      else asm volatile("s_waitcnt vmcnt(0)" ::: "memory");                        \
    }                                                                              \
    __builtin_amdgcn_s_barrier();                                                  \
  }

  for (int kt = 0; kt < NTm; ++kt) {
    const char* cb = smem + (kt % 3) * TILE;
    const int nb = (kt + 2) % 3;
    const int kbn = (kt + 2) << 6;
    const bool iss = (kt + 2 < NTm);
    PHASE_B(0) PHASE_B(1)
  }
#undef PHASE_B
#undef ST_A
#undef ST_B

#pragma unroll
  for (int mf = 0; mf < 4; ++mf) {
#pragma unroll
    for (int nf = 0; nf < 4; ++nf) {
      const int col = n0 + wn * 64 + nf * 16 + l15;
      const float bb = bias[col];
#pragma unroll
      for (int r = 0; r < 4; ++r) {
        const int row = m0 + wm * 64 + mf * 16 + l4 * 4 + r;
        out[(size_t)row * N + col] = acc[mf][nf][r] + bb + res[(size_t)row * N + col];
      }
    }
  }
}

// ---------------------------------------------------------------------------
// Flash attention v5: same as v4 but WITHOUT the VGPR clamp (r5's
// __launch_bounds__(256,4) forced 64 VGPR -> 20MB/dispatch scratch spills,
// WRITE_SIZE 36.9MB vs 16.4MB output). Natural VGPR ~90-110 still permits
// 4 blocks/CU (16 waves/CU needs VGPR<=128).
// ---------------------------------------------------------------------------
#define SCL 0.18033688011112042f  // 0.125 * log2(e)
#define NT (SEQ / 64)

__global__ __launch_bounds__(256) void flash_attn(
    const bf16* __restrict__ Q, const bf16* __restrict__ K,
    const bf16* __restrict__ V, bf16* __restrict__ O) {
  __shared__ char smem[32768];  // K dbuf @0..16K, Vt dbuf @16K..32K
  const int t = threadIdx.x;
  const int w = t >> 6, l = t & 63;
  const int l15 = l & 15, l4 = l >> 4;
  const int bid0 = blockIdx.y * 16 + blockIdx.x;
  const int bid = (bid0 & 7) * 128 + (bid0 >> 3);
  const int bx = bid & 15, bh = bid >> 4;
  const size_t base = (size_t)bh * (SEQ * HEAD_DIM);
  const int q0 = bx * 128 + w * 32;
  const short* Vg = (const short*)V;
  const int dV = w * 16 + l15;

  int krow[4], kswz[4];
#pragma unroll
  for (int ni = 0; ni < 4; ++ni) {
    const int kr = (ni >> 1) * 32 + (ni & 1) * 4 + (l15 >> 2) * 8 + (l15 & 3);
    krow[ni] = kr * 128;
    kswz[ni] = ((kr & 3) | (((kr >> 3) & 1) << 2)) << 4;
  }

  bf16x8 qf[2][2];
#pragma unroll
  for (int mi = 0; mi < 2; ++mi)
#pragma unroll
    for (int kk = 0; kk < 2; ++kk)
      qf[mi][kk] = *(const bf16x8*)&Q[base + (size_t)(q0 + mi * 16 + l15) * 64 + kk * 32 + l4 * 8];

  bf16x8 ones;
#pragma unroll
  for (int j = 0; j < 8; ++j) ones[j] = (short)0x3F80;  // bf16 1.0

  f32x4 accO[2][4] = {};
  float m_run[2], l_run[2];
#pragma unroll
  for (int mi = 0; mi < 2; ++mi) { m_run[mi] = -1e30f; l_run[mi] = 0.f; }

  short vg[16];

#define STAGE_K(bufofs, kt)                                                       \
  {                                                                               \
    _Pragma("unroll") for (int i = 0; i < 2; ++i) {                               \
      const int F = i * 256 + t;                                                  \
      const int r_ = F >> 3;                                                      \
      const int gk_ = (r_ & 3) | (((r_ >> 3) & 1) << 2);                          \
      const int c_ = 8 * ((F & 7) ^ gk_);                                         \
      gload16(&K[base + (size_t)((kt) + r_) * 64 + c_],                           \
              (void*)(smem + (bufofs) + (i * 256 + w * 64) * 16));                \
    }                                                                             \
  }

#define V_GATHER(kt)                                                              \
  {                                                                               \
    _Pragma("unroll") for (int h_ = 0; h_ < 2; ++h_)                              \
        _Pragma("unroll") for (int j_ = 0; j_ < 8; ++j_)                          \
            vg[h_ * 8 + j_] =                                                     \
        Vg[base + (size_t)((kt) + h_ * 32 + l4 * 8 + j_) * 64 + dV];              \
  }

#define VT_WRITE(bufofs)                                                          \
  {                                                                               \
    _Pragma("unroll") for (int h_ = 0; h_ < 2; ++h_) {                            \
      bf16x8 vv;                                                                  \
      _Pragma("unroll") for (int j_ = 0; j_ < 8; ++j_) vv[j_] = vg[h_ * 8 + j_];  \
      const int kb_ = (h_ * 64 + l4 * 16) ^ ((dV & 7) << 4);                      \
      *(bf16x8*)(smem + (bufofs) + dV * 128 + kb_) = vv;                          \
    }                                                                             \
  }

  STAGE_K(0, 0);
  V_GATHER(0);
  VT_WRITE(16384);
  __syncthreads();

  for (int it = 0; it < NT; ++it) {
    const int cur = it & 1;
    const char* Kb = (const char*)smem + cur * 8192;
    const char* Vb = (const char*)smem + 16384 + cur * 8192;
    const bool pre = (it + 1 < NT);
    if (pre) {
      STAGE_K((cur ^ 1) * 8192, (it + 1) * 64);
      V_GATHER((it + 1) * 64);
    }

    // ---- QK^T (swapped) + softmax ----
    bf16x8 kf[2][4];
#pragma unroll
    for (int kk = 0; kk < 2; ++kk)
#pragma unroll
      for (int ni = 0; ni < 4; ++ni)
        kf[kk][ni] = *(const bf16x8*)(Kb + krow[ni] + ((kk * 64 + l4 * 16) ^ kswz[ni]));

    unsigned pw[2][8];
#pragma unroll
    for (int mi = 0; mi < 2; ++mi) {
      f32x4 s[4] = {};
      __builtin_amdgcn_s_setprio(1);
#pragma unroll
      for (int kk = 0; kk < 2; ++kk)
#pragma unroll
        for (int ni = 0; ni < 4; ++ni)
          s[ni] = __builtin_amdgcn_mfma_f32_16x16x32_bf16(kf[kk][ni], qf[mi][kk], s[ni], 0, 0, 0);
      __builtin_amdgcn_s_setprio(0);

      float mx = s[0][0];
#pragma unroll
      for (int ni = 0; ni < 4; ++ni)
#pragma unroll
        for (int r = 0; r < 4; ++r) mx = fmaxf(mx, s[ni][r]);
      mx = fmaxf(mx, __shfl_xor(mx, 16));
      mx = fmaxf(mx, __shfl_xor(mx, 32));
      const float mxs = mx * SCL;
      // defer-rescale (T13)
      if (__any(mxs > m_run[mi] + 8.f)) {
        const float mn = fmaxf(m_run[mi], mxs);
        const float c = exp2f(m_run[mi] - mn);
        m_run[mi] = mn;
        l_run[mi] *= c;
#pragma unroll
        for (int ni = 0; ni < 4; ++ni)
#pragma unroll
          for (int r = 0; r < 4; ++r) accO[mi][ni][r] *= c;
      }
#pragma unroll
      for (int ni = 0; ni < 4; ++ni)
#pragma unroll
        for (int r = 0; r < 4; ++r)
          s[ni][r] = exp2f(fmaf(s[ni][r], SCL, -m_run[mi]));
#pragma unroll
      for (int kk = 0; kk < 2; ++kk)
#pragma unroll
        for (int jj = 0; jj < 4; ++jj) {
          const int ni = 2 * kk + (jj >> 1);
          pw[mi][kk * 4 + jj] = pkbf16(s[ni][2 * (jj & 1)], s[ni][2 * (jj & 1) + 1]);
        }
    }

    // ---- PV: O^T += V^T P, rowsum via MFMA-with-ones ----
    f32x4 zz[2] = {};
#pragma unroll
    for (int kk = 0; kk < 2; ++kk) {
      bf16x8 vf[4];
#pragma unroll
      for (int ni = 0; ni < 4; ++ni)
        vf[ni] = *(const bf16x8*)(Vb + (ni * 16 + l15) * 128 +
                                  ((kk * 64 + l4 * 16) ^ ((l15 & 7) << 4)));
#pragma unroll
      for (int mi = 0; mi < 2; ++mi) {
        union { unsigned u[4]; bf16x8 h; } pb;
#pragma unroll
        for (int jj = 0; jj < 4; ++jj) pb.u[jj] = pw[mi][kk * 4 + jj];
        __builtin_amdgcn_s_setprio(1);
#pragma unroll
        for (int ni = 0; ni < 4; ++ni)
          accO[mi][ni] = __builtin_amdgcn_mfma_f32_16x16x32_bf16(vf[ni], pb.h, accO[mi][ni], 0, 0, 0);
        zz[mi] = __builtin_amdgcn_mfma_f32_16x16x32_bf16(ones, pb.h, zz[mi], 0, 0, 0);
        __builtin_amdgcn_s_setprio(0);
      }
    }
#pragma unroll
    for (int mi = 0; mi < 2; ++mi) l_run[mi] += zz[mi][0];

    if (pre) VT_WRITE(16384 + (cur ^ 1) * 8192);
    __syncthreads();
  }

  // ---- epilogue: bounce O^T through LDS (4 KB/wave) for coalesced stores ----
  char* ob = smem + w * 4096;
#pragma unroll
  for (int mi = 0; mi < 2; ++mi) {
    const float inv = 1.f / l_run[mi];
    const int qr = mi * 16 + l15;
    const int sw = (qr & 7) << 4;
#pragma unroll
    for (int ni = 0; ni < 4; ++ni)
#pragma unroll
      for (int rr = 0; rr < 2; ++rr) {
        const unsigned pk = pkbf16(accO[mi][ni][2 * rr] * inv, accO[mi][ni][2 * rr + 1] * inv);
        *(unsigned*)(ob + qr * 128 + ((ni * 32 + l4 * 8 + 4 * rr) ^ sw)) = pk;
      }
  }
  asm volatile("s_waitcnt lgkmcnt(0)" ::: "memory");
  __builtin_amdgcn_sched_barrier(0);

  const int b = bh >> 4, h = bh & 15;
  const int hr = l >> 1, hf = l & 1;
  const size_t orow = ((size_t)b * SEQ + bx * 128 + w * 32 + hr) * D_MODEL + h * HEAD_DIM + hf * 32;
#pragma unroll
  for (int c = 0; c < 4; ++c) {
    bf16x8 vv = *(const bf16x8*)(ob + hr * 128 + (((hf * 64) + c * 16) ^ ((hr & 7) << 4)));
    *(bf16x8*)&O[orow + c * 8] = vv;
  }
}

// ---------------------------------------------------------------------------
extern "C" void kernel_launch(void* const* d_in, const int* in_sizes, int n_in,
                              void* d_out, int out_size, void* d_ws, size_t ws_size,
                              hipStream_t stream) {
  const float* x     = (const float*)d_in[0];
  const float* Wq    = (const float*)d_in[1];
  const float* bq    = (const float*)d_in[2];
  const float* Wk    = (const float*)d_in[3];
  const float* bk    = (const float*)d_in[4];
  const float* Wv    = (const float*)d_in[5];
  const float* bv    = (const float*)d_in[6];
  const float* Wo    = (const float*)d_in[7];
  const float* bo    = (const float*)d_in[8];
  const float* W1    = (const float*)d_in[9];
  const float* b1    = (const float*)d_in[10];
  const float* W2    = (const float*)d_in[11];
  const float* b2    = (const float*)d_in[12];
  const float* ln1_g = (const float*)d_in[13];
  const float* ln1_b = (const float*)d_in[14];
  const float* ln2_g = (const float*)d_in[15];
  const float* ln2_b = (const float*)d_in[16];

  const size_t MB = 1ull << 20;
  char* ws = (char*)d_ws;
  bf16* wqkv = (bf16*)(ws + 0 * MB);    // 6 MB: [Wq;Wk;Wv] rows, K-contig
  bf16* wo_b = (bf16*)(ws + 6 * MB);
  bf16* w1_b = (bf16*)(ws + 8 * MB);    // 8 MB
  bf16* w2_b = (bf16*)(ws + 16 * MB);   // 8 MB
  bf16* xn   = (bf16*)(ws + 24 * MB);   // 16 MB: xn / attn_out / xn2
  bf16* qb   = (bf16*)(ws + 40 * MB);   // 16 MB (q,k,v contiguous)
  bf16* kbuf = (bf16*)(ws + 56 * MB);   // 16 MB
  bf16* vb   = (bf16*)(ws + 72 * MB);   // 16 MB
  bf16* hb   = (bf16*)(ws + 40 * MB);   // 64 MB (reuses q/k/v after attention)
  float* x1  = (float*)(ws + 104 * MB); // 32 MB

  // all weight conversions in one launch (saves ~5 dispatch overheads)
  cvt_all<<<12288, 256, 0, stream>>>(W1, W2, Wq, Wk, Wv, Wo, w1_b, w2_b, wqkv, wo_b);

  layernorm_kernel<<<NTOK, 256, 0, stream>>>(x, ln1_g, ln1_b, xn);

  // QKV fused: [8192,3072] = xn @ wqkv^T -> permuted/split q/k/v
  gemmA<0><<<dim3(3072 / 256, NTOK / 256), 512, 0, stream>>>(
      xn, wqkv, bq, bk, bv, qb, NTOK, 3072, 1024);

  flash_attn<<<dim3(SEQ / 128, 4 * NHEAD), 256, 0, stream>>>(qb, kbuf, vb, xn);

  // Wo + residual(x) -> x1 (fp32)
  gemmB<<<dim3(1024 / 256, NTOK / 128), 512, 0, stream>>>(
      xn, wo_b, bo, x, x1, NTOK, 1024, 1024);

  layernorm_kernel<<<NTOK, 256, 0, stream>>>(x1, ln2_g, ln2_b, xn);

  // FFN1 (ReLU) -> hb
  gemmA<1><<<dim3(D_FF / 256, NTOK / 256), 512, 0, stream>>>(
      xn, w1_b, b1, b1, b1, hb, NTOK, D_FF, 1024);

  // FFN2 + residual(x1) -> d_out (fp32)
  gemmB<<<dim3(1024 / 256, NTOK / 128), 512, 0, stream>>>(
      hb, w2_b, b2, x1, (float*)d_out, NTOK, 1024, D_FF);
}

// Round 7
// 397.912 us; speedup vs baseline: 1.7459x; 1.0720x over previous
//
#include <hip/hip_runtime.h>
#include <hip/hip_bf16.h>

using bf16 = __hip_bfloat16;
typedef __attribute__((ext_vector_type(8))) short bf16x8;
typedef __attribute__((ext_vector_type(4))) float f32x4;

#define D_MODEL 1024
#define NHEAD 16
#define HEAD_DIM 64
#define D_FF 4096
#define SEQ 2048
#define NTOK 8192  // 4 * 2048

__device__ __forceinline__ void gload16(const void* g, void* l) {
  __builtin_amdgcn_global_load_lds((const __attribute__((address_space(1))) void*)g,
                                   (__attribute__((address_space(3))) void*)l, 16, 0, 0);
}

__device__ __forceinline__ unsigned pkbf16(float lo, float hi) {
  unsigned r;
  asm("v_cvt_pk_bf16_f32 %0, %1, %2" : "=v"(r) : "v"(lo), "v"(hi));
  return r;
}

// raw v_exp_f32 (2^x): exp2f() lowers to OCML multi-instr; this is 1 VALU op.
__device__ __forceinline__ float fexp2(float x) {
  float r;
  asm("v_exp_f32 %0, %1" : "=v"(r) : "v"(x));
  return r;
}

__device__ __forceinline__ float max3f(float a, float b, float c) {
  return fmaxf(fmaxf(a, b), c);  // fuses to v_max3_f32
}

// ---------------------------------------------------------------------------
// f32 -> bf16 conversion, all 6 weight matrices in ONE launch.
// ---------------------------------------------------------------------------
__global__ __launch_bounds__(256) void cvt_all(
    const float* __restrict__ W1, const float* __restrict__ W2,
    const float* __restrict__ Wq, const float* __restrict__ Wk,
    const float* __restrict__ Wv, const float* __restrict__ Wo,
    bf16* __restrict__ w1_b, bf16* __restrict__ w2_b,
    bf16* __restrict__ wqkv, bf16* __restrict__ wo_b) {
  const int bid = blockIdx.x;
  const float* src;
  bf16* dst;
  int lb;
  if (bid < 4096) { src = W1; dst = w1_b; lb = bid; }
  else if (bid < 8192) { src = W2; dst = w2_b; lb = bid - 4096; }
  else {
    const int j = (bid - 8192) >> 10;
    lb = (bid - 8192) & 1023;
    if (j == 0) { src = Wq; dst = wqkv; }
    else if (j == 1) { src = Wk; dst = wqkv + 1048576; }
    else if (j == 2) { src = Wv; dst = wqkv + 2097152; }
    else { src = Wo; dst = wo_b; }
  }
  const int i = (lb * 256 + threadIdx.x) * 4;
  const float4 v = *(const float4*)&src[i];
  dst[i + 0] = __float2bfloat16(v.x);
  dst[i + 1] = __float2bfloat16(v.y);
  dst[i + 2] = __float2bfloat16(v.z);
  dst[i + 3] = __float2bfloat16(v.w);
}

// ---------------------------------------------------------------------------
// LayerNorm over D=1024, fp32 in -> bf16 out. One block (256 thr) per row.
// ---------------------------------------------------------------------------
__global__ __launch_bounds__(256) void layernorm_kernel(
    const float* __restrict__ xin, const float* __restrict__ g,
    const float* __restrict__ bta, bf16* __restrict__ out) {
  const int row = blockIdx.x, t = threadIdx.x;
  const float4 v = *(const float4*)&xin[(size_t)row * D_MODEL + t * 4];
  float s = v.x + v.y + v.z + v.w;
#pragma unroll
  for (int m = 1; m < 64; m <<= 1) s += __shfl_xor(s, m);
  __shared__ float red[4], red2[4];
  const int w = t >> 6, l = t & 63;
  if (l == 0) red[w] = s;
  __syncthreads();
  const float mu = (red[0] + red[1] + red[2] + red[3]) * (1.f / 1024.f);
  const float d0 = v.x - mu, d1 = v.y - mu, d2 = v.z - mu, d3 = v.w - mu;
  float q = d0 * d0 + d1 * d1 + d2 * d2 + d3 * d3;
#pragma unroll
  for (int m = 1; m < 64; m <<= 1) q += __shfl_xor(q, m);
  if (l == 0) red2[w] = q;
  __syncthreads();
  const float var = (red2[0] + red2[1] + red2[2] + red2[3]) * (1.f / 1024.f);
  const float rs = rsqrtf(var + 1e-5f);
  const float4 gg = *(const float4*)&g[t * 4];
  const float4 bb = *(const float4*)&bta[t * 4];
  bf16* o = out + (size_t)row * D_MODEL + t * 4;
  o[0] = __float2bfloat16(d0 * rs * gg.x + bb.x);
  o[1] = __float2bfloat16(d1 * rs * gg.y + bb.y);
  o[2] = __float2bfloat16(d2 * rs * gg.z + bb.z);
  o[3] = __float2bfloat16(d3 * rs * gg.w + bb.w);
}

// ---------------------------------------------------------------------------
// gemmA: BM=256,BN=256,BK=64, 512 thr, 8 waves (2M x 4N), wave tile 128x64.
// 4 phases/K-tile x 16 MFMA. (unchanged)
// ---------------------------------------------------------------------------
template <int MODE>
__global__ __launch_bounds__(512, 2) void gemmA(
    const bf16* __restrict__ A, const bf16* __restrict__ Bw,
    const float* __restrict__ bias0, const float* __restrict__ bias1,
    const float* __restrict__ bias2,
    void* __restrict__ out, int M, int N, int K) {
  constexpr int ASZ = 256 * 128;
  constexpr int TILE = ASZ + 256 * 128;  // 64 KB
  __shared__ __align__(16) char smem[2 * TILE];

  const int t = threadIdx.x;
  const int l = t & 63, l15 = l & 15, l4 = (l >> 4) & 3;
  const int w = t >> 6, wm = w >> 2, wn = w & 3;
  const int gx = gridDim.x;
  const int nwg = gx * gridDim.y;
  const int bid0 = blockIdx.y * gx + blockIdx.x;
  const int bid = (bid0 & 7) * (nwg >> 3) + (bid0 >> 3);
  const int m0 = (bid / gx) * 256, n0 = (bid % gx) * 256;

  const int sr = t >> 3;
  const int scol = 8 * ((t & 7) ^ (sr & 7));
  const int swz = (l15 & 7) << 4;
  int coff[2];
  coff[0] = (l4 * 16) ^ swz;
  coff[1] = (64 + l4 * 16) ^ swz;

#define ST_A(j, kb, buf)                                          \
  gload16(&A[(size_t)(m0 + (j) * 64 + sr) * K + (kb) + scol],     \
          (void*)(smem + (buf) * TILE + (j) * 8192 + t * 16))
#define ST_B(j, kb, buf)                                          \
  gload16(&Bw[(size_t)(n0 + (j) * 64 + sr) * K + (kb) + scol],    \
          (void*)(smem + (buf) * TILE + ASZ + (j) * 8192 + t * 16))

  f32x4 acc[8][4] = {};
  const int NTm = K >> 6;

  ST_A(0, 0, 0); ST_A(2, 0, 0);
  ST_B(0, 0, 0); ST_B(1, 0, 0); ST_B(2, 0, 0); ST_B(3, 0, 0);
  ST_A(1, 0, 0); ST_A(3, 0, 0);
  asm volatile("s_waitcnt vmcnt(2)" ::: "memory");
  __builtin_amdgcn_s_barrier();

#define PHASE_A(p)                                                                 \
  {                                                                                \
    constexpr int kk = (p) & 1;                                                    \
    constexpr int mh = ((p) >> 1) * 4;                                             \
    bf16x8 af[4], bf[4];                                                           \
    _Pragma("unroll") for (int m = 0; m < 4; ++m)                                  \
      af[m] = *(const bf16x8*)(cb + (wm * 128 + (mh + m) * 16 + l15) * 128 +       \
                               coff[kk]);                                          \
    _Pragma("unroll") for (int n = 0; n < 4; ++n)                                  \
      bf[n] = *(const bf16x8*)(cb + ASZ + (wn * 64 + n * 16 + l15) * 128 +         \
                               coff[kk]);                                          \
    if (hasNext) {                                                                 \
      if ((p) == 0) { ST_A(0, kbn, nb); ST_A(2, kbn, nb); }                        \
      else if ((p) == 1) { ST_B(0, kbn, nb); ST_B(1, kbn, nb); }                   \
      else if ((p) == 2) { ST_B(2, kbn, nb); ST_B(3, kbn, nb); }                   \
      else { ST_A(1, kbn, nb); ST_A(3, kbn, nb); }                                 \
    }                                                                              \
    __builtin_amdgcn_s_barrier();                                                  \
    asm volatile("s_waitcnt lgkmcnt(0)" ::: "memory");                             \
    __builtin_amdgcn_sched_barrier(0);                                             \
    __builtin_amdgcn_s_setprio(1);                                                 \
    _Pragma("unroll") for (int m = 0; m < 4; ++m)                                  \
      _Pragma("unroll") for (int n = 0; n < 4; ++n)                                \
        acc[mh + m][n] = __builtin_amdgcn_mfma_f32_16x16x32_bf16(                  \
            af[m], bf[n], acc[mh + m][n], 0, 0, 0);                                \
    __builtin_amdgcn_s_setprio(0);                                                 \
    if ((p) == 1) {                                                                \
      if (hasNext) asm volatile("s_waitcnt vmcnt(4)" ::: "memory");                \
      else asm volatile("s_waitcnt vmcnt(0)" ::: "memory");                        \
    }                                                                              \
    if ((p) == 3 && hasNext)                                                       \
      asm volatile("s_waitcnt vmcnt(2)" ::: "memory");                             \
    __builtin_amdgcn_s_barrier();                                                  \
  }

  for (int kt = 0; kt < NTm; ++kt) {
    const char* cb = smem + (kt & 1) * TILE;
    const int nb = (kt & 1) ^ 1;
    const int kbn = (kt + 1) << 6;
    const bool hasNext = (kt + 1 < NTm);
    PHASE_A(0) PHASE_A(1) PHASE_A(2) PHASE_A(3)
  }
#undef PHASE_A
#undef ST_A
#undef ST_B

#pragma unroll
  for (int mf = 0; mf < 8; ++mf) {
#pragma unroll
    for (int nf = 0; nf < 4; ++nf) {
      const int col = n0 + wn * 64 + nf * 16 + l15;
      float bb;
      if constexpr (MODE == 0) {
        const int sel = col >> 10;
        const float* bp = (sel == 0) ? bias0 : ((sel == 1) ? bias1 : bias2);
        bb = bp[col & 1023];
      } else {
        bb = bias0[col];
      }
#pragma unroll
      for (int r = 0; r < 4; ++r) {
        const int row = m0 + wm * 128 + mf * 16 + l4 * 4 + r;
        float y = acc[mf][nf][r] + bb;
        if constexpr (MODE == 1) y = fmaxf(y, 0.f);
        if constexpr (MODE == 0) {
          const int sel = col >> 10;
          const int c10 = col & 1023;
          const size_t dst = (size_t)sel * (NTOK * 1024) +
                             (size_t)((row >> 11) * NHEAD + (c10 >> 6)) * (SEQ * HEAD_DIM) +
                             (size_t)(row & (SEQ - 1)) * HEAD_DIM + (c10 & 63);
          ((bf16*)out)[dst] = __float2bfloat16(y);
        } else {
          ((bf16*)out)[(size_t)row * N + col] = __float2bfloat16(y);
        }
      }
    }
  }
}

// ---------------------------------------------------------------------------
// gemmB: BM=128,BN=256,BK=64, 512 thr, 8 waves (2M x 4N), wave tile 64x64.
// 2 phases/K-tile x 16 MFMA, 3 LDS buffers, 2-tiles-ahead prefetch.
// (unchanged)
// ---------------------------------------------------------------------------
__global__ __launch_bounds__(512, 2) void gemmB(
    const bf16* __restrict__ A, const bf16* __restrict__ Bw,
    const float* __restrict__ bias, const float* __restrict__ res,
    float* __restrict__ out, int M, int N, int K) {
  constexpr int ASZ = 128 * 128;
  constexpr int TILE = ASZ + 256 * 128;  // 48 KB
  __shared__ __align__(16) char smem[3 * TILE];  // 144 KB

  const int t = threadIdx.x;
  const int l = t & 63, l15 = l & 15, l4 = (l >> 4) & 3;
  const int w = t >> 6, wm = w >> 2, wn = w & 3;
  const int gx = gridDim.x;
  const int nwg = gx * gridDim.y;
  const int bid0 = blockIdx.y * gx + blockIdx.x;
  const int bid = (bid0 & 7) * (nwg >> 3) + (bid0 >> 3);
  const int m0 = (bid / gx) * 128, n0 = (bid % gx) * 256;

  const int sr = t >> 3;
  const int scol = 8 * ((t & 7) ^ (sr & 7));
  const int swz = (l15 & 7) << 4;
  int coff[2];
  coff[0] = (l4 * 16) ^ swz;
  coff[1] = (64 + l4 * 16) ^ swz;

#define ST_A(j, kb, buf)                                          \
  gload16(&A[(size_t)(m0 + (j) * 64 + sr) * K + (kb) + scol],     \
          (void*)(smem + (buf) * TILE + (j) * 8192 + t * 16))
#define ST_B(j, kb, buf)                                          \
  gload16(&Bw[(size_t)(n0 + (j) * 64 + sr) * K + (kb) + scol],    \
          (void*)(smem + (buf) * TILE + ASZ + (j) * 8192 + t * 16))

  f32x4 acc[4][4] = {};
  const int NTm = K >> 6;

  ST_B(0, 0, 0); ST_B(1, 0, 0); ST_B(2, 0, 0);
  ST_B(3, 0, 0); ST_A(0, 0, 0); ST_A(1, 0, 0);
  ST_B(0, 64, 1); ST_B(1, 64, 1); ST_B(2, 64, 1);
  ST_B(3, 64, 1); ST_A(0, 64, 1); ST_A(1, 64, 1);
  asm volatile("s_waitcnt vmcnt(6)" ::: "memory");
  __builtin_amdgcn_s_barrier();

#define PHASE_B(p)                                                                 \
  {                                                                                \
    constexpr int kk = (p);                                                        \
    bf16x8 af[4], bf[4];                                                           \
    _Pragma("unroll") for (int m = 0; m < 4; ++m)                                  \
      af[m] = *(const bf16x8*)(cb + (wm * 64 + m * 16 + l15) * 128 + coff[kk]);    \
    _Pragma("unroll") for (int n = 0; n < 4; ++n)                                  \
      bf[n] = *(const bf16x8*)(cb + ASZ + (wn * 64 + n * 16 + l15) * 128 +         \
                               coff[kk]);                                          \
    if (iss) {                                                                     \
      if ((p) == 0) { ST_B(0, kbn, nb); ST_B(1, kbn, nb); ST_B(2, kbn, nb); }      \
      else { ST_B(3, kbn, nb); ST_A(0, kbn, nb); ST_A(1, kbn, nb); }               \
    }                                                                              \
    __builtin_amdgcn_s_barrier();                                                  \
    asm volatile("s_waitcnt lgkmcnt(0)" ::: "memory");                             \
    __builtin_amdgcn_sched_barrier(0);                                             \
    __builtin_amdgcn_s_setprio(1);                                                 \
    _Pragma("unroll") for (int m = 0; m < 4; ++m)                                  \
      _Pragma("unroll") for (int n = 0; n < 4; ++n)                                \
        acc[m][n] = __builtin_amdgcn_mfma_f32_16x16x32_bf16(                       \
            af[m], bf[n], acc[m][n], 0, 0, 0);                                     \
    __builtin_amdgcn_s_setprio(0);                                                 \
    if ((p) == 1) {                                                                \
      if (iss) asm volatile("s_waitcnt vmcnt(6)" ::: "memory");                    \
      else asm volatile("s_waitcnt vmcnt(0)" ::: "memory");                        \
    }                                                                              \
    __builtin_amdgcn_s_barrier();                                                  \
  }

  for (int kt = 0; kt < NTm; ++kt) {
    const char* cb = smem + (kt % 3) * TILE;
    const int nb = (kt + 2) % 3;
    const int kbn = (kt + 2) << 6;
    const bool iss = (kt + 2 < NTm);
    PHASE_B(0) PHASE_B(1)
  }
#undef PHASE_B
#undef ST_A
#undef ST_B

#pragma unroll
  for (int mf = 0; mf < 4; ++mf) {
#pragma unroll
    for (int nf = 0; nf < 4; ++nf) {
      const int col = n0 + wn * 64 + nf * 16 + l15;
      const float bb = bias[col];
#pragma unroll
      for (int r = 0; r < 4; ++r) {
        const int row = m0 + wm * 64 + mf * 16 + l4 * 4 + r;
        out[(size_t)row * N + col] = acc[mf][nf][r] + bb + res[(size_t)row * N + col];
      }
    }
  }
}

// ---------------------------------------------------------------------------
// Flash attention v6: v5 + (a) raw v_exp_f32 instead of OCML exp2f,
// (b) loop-carried global pointers (K-stage, V-gather) with imm offsets,
// (c) max3-tree row max. Structure otherwise unchanged.
// ---------------------------------------------------------------------------
#define SCL 0.18033688011112042f  // 0.125 * log2(e)
#define NT (SEQ / 64)

__global__ __launch_bounds__(256) void flash_attn(
    const bf16* __restrict__ Q, const bf16* __restrict__ K,
    const bf16* __restrict__ V, bf16* __restrict__ O) {
  __shared__ char smem[32768];  // K dbuf @0..16K, Vt dbuf @16K..32K
  const int t = threadIdx.x;
  const int w = t >> 6, l = t & 63;
  const int l15 = l & 15, l4 = l >> 4;
  const int bid0 = blockIdx.y * 16 + blockIdx.x;
  const int bid = (bid0 & 7) * 128 + (bid0 >> 3);
  const int bx = bid & 15, bh = bid >> 4;
  const size_t base = (size_t)bh * (SEQ * HEAD_DIM);
  const int q0 = bx * 128 + w * 32;
  const int dV = w * 16 + l15;

  int krow[4], kswz[4];
#pragma unroll
  for (int ni = 0; ni < 4; ++ni) {
    const int kr = (ni >> 1) * 32 + (ni & 1) * 4 + (l15 >> 2) * 8 + (l15 & 3);
    krow[ni] = kr * 128;
    kswz[ni] = ((kr & 3) | (((kr >> 3) & 1) << 2)) << 4;
  }

  bf16x8 qf[2][2];
#pragma unroll
  for (int mi = 0; mi < 2; ++mi)
#pragma unroll
    for (int kk = 0; kk < 2; ++kk)
      qf[mi][kk] = *(const bf16x8*)&Q[base + (size_t)(q0 + mi * 16 + l15) * 64 + kk * 32 + l4 * 8];

  bf16x8 ones;
#pragma unroll
  for (int j = 0; j < 8; ++j) ones[j] = (short)0x3F80;  // bf16 1.0

  f32x4 accO[2][4] = {};
  float m_run[2], l_run[2];
#pragma unroll
  for (int mi = 0; mi < 2; ++mi) { m_run[mi] = -1e30f; l_run[mi] = 0.f; }

  short vg[16];

  // loop-carried global pointers (advance 4096 shorts per K-tile)
  const int r0 = t >> 3;
  const int c0 = 8 * ((t & 7) ^ ((r0 & 3) | (((r0 >> 3) & 1) << 2)));
  const int r1 = r0 + 32;
  const int c1 = 8 * ((t & 7) ^ ((r1 & 3) | (((r1 >> 3) & 1) << 2)));
  const short* kg0 = (const short*)K + base + r0 * 64 + c0;
  const short* kg1 = (const short*)K + base + r1 * 64 + c1;
  const short* vp0 = (const short*)V + base + (l4 * 8) * 64 + dV;
  const short* vp1 = vp0 + 2048;

#define STAGE_K(bufofs)                                          \
  {                                                              \
    gload16(kg0, (void*)(smem + (bufofs) + w * 1024));           \
    gload16(kg1, (void*)(smem + (bufofs) + 4096 + w * 1024));    \
    kg0 += 4096; kg1 += 4096;                                    \
  }

#define V_GATHER()                                               \
  {                                                              \
    _Pragma("unroll") for (int j_ = 0; j_ < 8; ++j_) {           \
      vg[j_] = vp0[j_ * 64];                                     \
      vg[8 + j_] = vp1[j_ * 64];                                 \
    }                                                            \
    vp0 += 4096; vp1 += 4096;                                    \
  }

#define VT_WRITE(bufofs)                                                          \
  {                                                                               \
    _Pragma("unroll") for (int h_ = 0; h_ < 2; ++h_) {                            \
      bf16x8 vv;                                                                  \
      _Pragma("unroll") for (int j_ = 0; j_ < 8; ++j_) vv[j_] = vg[h_ * 8 + j_];  \
      const int kb_ = (h_ * 64 + l4 * 16) ^ ((dV & 7) << 4);                      \
      *(bf16x8*)(smem + (bufofs) + dV * 128 + kb_) = vv;                          \
    }                                                                             \
  }

  STAGE_K(0);
  V_GATHER();
  VT_WRITE(16384);
  __syncthreads();

  for (int it = 0; it < NT; ++it) {
    const int cur = it & 1;
    const char* Kb = (const char*)smem + cur * 8192;
    const char* Vb = (const char*)smem + 16384 + cur * 8192;
    const bool pre = (it + 1 < NT);
    if (pre) {
      STAGE_K((cur ^ 1) * 8192);
      V_GATHER();
    }

    // ---- QK^T (swapped) + softmax ----
    bf16x8 kf[2][4];
#pragma unroll
    for (int kk = 0; kk < 2; ++kk)
#pragma unroll
      for (int ni = 0; ni < 4; ++ni)
        kf[kk][ni] = *(const bf16x8*)(Kb + krow[ni] + ((kk * 64 + l4 * 16) ^ kswz[ni]));

    unsigned pw[2][8];
#pragma unroll
    for (int mi = 0; mi < 2; ++mi) {
      f32x4 s[4] = {};
      __builtin_amdgcn_s_setprio(1);
#pragma unroll
      for (int kk = 0; kk < 2; ++kk)
#pragma unroll
        for (int ni = 0; ni < 4; ++ni)
          s[ni] = __builtin_amdgcn_mfma_f32_16x16x32_bf16(kf[kk][ni], qf[mi][kk], s[ni], 0, 0, 0);
      __builtin_amdgcn_s_setprio(0);

      // row max: max3 tree over 16 in-lane values + 2 shuffles
      const float t0 = max3f(s[0][0], s[0][1], s[0][2]);
      const float t1 = max3f(s[0][3], s[1][0], s[1][1]);
      const float t2 = max3f(s[1][2], s[1][3], s[2][0]);
      const float t3 = max3f(s[2][1], s[2][2], s[2][3]);
      const float t4 = max3f(s[3][0], s[3][1], s[3][2]);
      float mx = fmaxf(max3f(t1, t2, t3), fmaxf(t4, fmaxf(t0, s[3][3])));
      mx = fmaxf(mx, __shfl_xor(mx, 16));
      mx = fmaxf(mx, __shfl_xor(mx, 32));
      const float mxs = mx * SCL;
      // defer-rescale (T13)
      if (__any(mxs > m_run[mi] + 8.f)) {
        const float mn = fmaxf(m_run[mi], mxs);
        const float c = fexp2(m_run[mi] - mn);
        m_run[mi] = mn;
        l_run[mi] *= c;
#pragma unroll
        for (int ni = 0; ni < 4; ++ni)
#pragma unroll
          for (int r = 0; r < 4; ++r) accO[mi][ni][r] *= c;
      }
#pragma unroll
      for (int ni = 0; ni < 4; ++ni)
#pragma unroll
        for (int r = 0; r < 4; ++r)
          s[ni][r] = fexp2(fmaf(s[ni][r], SCL, -m_run[mi]));
#pragma unroll
      for (int kk = 0; kk < 2; ++kk)
#pragma unroll
        for (int jj = 0; jj < 4; ++jj) {
          const int ni = 2 * kk + (jj >> 1);
          pw[mi][kk * 4 + jj] = pkbf16(s[ni][2 * (jj & 1)], s[ni][2 * (jj & 1) + 1]);
        }
    }

    // ---- PV: O^T += V^T P, rowsum via MFMA-with-ones ----
    f32x4 zz[2] = {};
#pragma unroll
    for (int kk = 0; kk < 2; ++kk) {
      bf16x8 vf[4];
#pragma unroll
      for (int ni = 0; ni < 4; ++ni)
        vf[ni] = *(const bf16x8*)(Vb + (ni * 16 + l15) * 128 +
                                  ((kk * 64 + l4 * 16) ^ ((l15 & 7) << 4)));
#pragma unroll
      for (int mi = 0; mi < 2; ++mi) {
        union { unsigned u[4]; bf16x8 h; } pb;
#pragma unroll
        for (int jj = 0; jj < 4; ++jj) pb.u[jj] = pw[mi][kk * 4 + jj];
        __builtin_amdgcn_s_setprio(1);
#pragma unroll
        for (int ni = 0; ni < 4; ++ni)
          accO[mi][ni] = __builtin_amdgcn_mfma_f32_16x16x32_bf16(vf[ni], pb.h, accO[mi][ni], 0, 0, 0);
        zz[mi] = __builtin_amdgcn_mfma_f32_16x16x32_bf16(ones, pb.h, zz[mi], 0, 0, 0);
        __builtin_amdgcn_s_setprio(0);
      }
    }
#pragma unroll
    for (int mi = 0; mi < 2; ++mi) l_run[mi] += zz[mi][0];

    if (pre) VT_WRITE(16384 + (cur ^ 1) * 8192);
    __syncthreads();
  }

  // ---- epilogue: bounce O^T through LDS (4 KB/wave) for coalesced stores ----
  char* ob = smem + w * 4096;
#pragma unroll
  for (int mi = 0; mi < 2; ++mi) {
    const float inv = 1.f / l_run[mi];
    const int qr = mi * 16 + l15;
    const int sw = (qr & 7) << 4;
#pragma unroll
    for (int ni = 0; ni < 4; ++ni)
#pragma unroll
      for (int rr = 0; rr < 2; ++rr) {
        const unsigned pk = pkbf16(accO[mi][ni][2 * rr] * inv, accO[mi][ni][2 * rr + 1] * inv);
        *(unsigned*)(ob + qr * 128 + ((ni * 32 + l4 * 8 + 4 * rr) ^ sw)) = pk;
      }
  }
  asm volatile("s_waitcnt lgkmcnt(0)" ::: "memory");
  __builtin_amdgcn_sched_barrier(0);

  const int b = bh >> 4, h = bh & 15;
  const int hr = l >> 1, hf = l & 1;
  const size_t orow = ((size_t)b * SEQ + bx * 128 + w * 32 + hr) * D_MODEL + h * HEAD_DIM + hf * 32;
#pragma unroll
  for (int c = 0; c < 4; ++c) {
    bf16x8 vv = *(const bf16x8*)(ob + hr * 128 + (((hf * 64) + c * 16) ^ ((hr & 7) << 4)));
    *(bf16x8*)&O[orow + c * 8] = vv;
  }
}

// ---------------------------------------------------------------------------
extern "C" void kernel_launch(void* const* d_in, const int* in_sizes, int n_in,
                              void* d_out, int out_size, void* d_ws, size_t ws_size,
                              hipStream_t stream) {
  const float* x     = (const float*)d_in[0];
  const float* Wq    = (const float*)d_in[1];
  const float* bq    = (const float*)d_in[2];
  const float* Wk    = (const float*)d_in[3];
  const float* bk    = (const float*)d_in[4];
  const float* Wv    = (const float*)d_in[5];
  const float* bv    = (const float*)d_in[6];
  const float* Wo    = (const float*)d_in[7];
  const float* bo    = (const float*)d_in[8];
  const float* W1    = (const float*)d_in[9];
  const float* b1    = (const float*)d_in[10];
  const float* W2    = (const float*)d_in[11];
  const float* b2    = (const float*)d_in[12];
  const float* ln1_g = (const float*)d_in[13];
  const float* ln1_b = (const float*)d_in[14];
  const float* ln2_g = (const float*)d_in[15];
  const float* ln2_b = (const float*)d_in[16];

  const size_t MB = 1ull << 20;
  char* ws = (char*)d_ws;
  bf16* wqkv = (bf16*)(ws + 0 * MB);    // 6 MB: [Wq;Wk;Wv] rows, K-contig
  bf16* wo_b = (bf16*)(ws + 6 * MB);
  bf16* w1_b = (bf16*)(ws + 8 * MB);    // 8 MB
  bf16* w2_b = (bf16*)(ws + 16 * MB);   // 8 MB
  bf16* xn   = (bf16*)(ws + 24 * MB);   // 16 MB: xn / attn_out / xn2
  bf16* qb   = (bf16*)(ws + 40 * MB);   // 16 MB (q,k,v contiguous)
  bf16* kbuf = (bf16*)(ws + 56 * MB);   // 16 MB
  bf16* vb   = (bf16*)(ws + 72 * MB);   // 16 MB
  bf16* hb   = (bf16*)(ws + 40 * MB);   // 64 MB (reuses q/k/v after attention)
  float* x1  = (float*)(ws + 104 * MB); // 32 MB

  cvt_all<<<12288, 256, 0, stream>>>(W1, W2, Wq, Wk, Wv, Wo, w1_b, w2_b, wqkv, wo_b);

  layernorm_kernel<<<NTOK, 256, 0, stream>>>(x, ln1_g, ln1_b, xn);

  // QKV fused: [8192,3072] = xn @ wqkv^T -> permuted/split q/k/v
  gemmA<0><<<dim3(3072 / 256, NTOK / 256), 512, 0, stream>>>(
      xn, wqkv, bq, bk, bv, qb, NTOK, 3072, 1024);

  flash_attn<<<dim3(SEQ / 128, 4 * NHEAD), 256, 0, stream>>>(qb, kbuf, vb, xn);

  // Wo + residual(x) -> x1 (fp32)
  gemmB<<<dim3(1024 / 256, NTOK / 128), 512, 0, stream>>>(
      xn, wo_b, bo, x, x1, NTOK, 1024, 1024);

  layernorm_kernel<<<NTOK, 256, 0, stream>>>(x1, ln2_g, ln2_b, xn);

  // FFN1 (ReLU) -> hb
  gemmA<1><<<dim3(D_FF / 256, NTOK / 256), 512, 0, stream>>>(
      xn, w1_b, b1, b1, b1, hb, NTOK, D_FF, 1024);

  // FFN2 + residual(x1) -> d_out (fp32)
  gemmB<<<dim3(1024 / 256, NTOK / 128), 512, 0, stream>>>(
      hb, w2_b, b2, x1, (float*)d_out, NTOK, 1024, D_FF);
}

// Round 8
// 385.948 us; speedup vs baseline: 1.8000x; 1.0310x over previous
//
#include <hip/hip_runtime.h>
#include <hip/hip_bf16.h>

using bf16 = __hip_bfloat16;
typedef __attribute__((ext_vector_type(8))) short bf16x8;
typedef __attribute__((ext_vector_type(4))) float f32x4;

#define D_MODEL 1024
#define NHEAD 16
#define HEAD_DIM 64
#define D_FF 4096
#define SEQ 2048
#define NTOK 8192  // 4 * 2048

__device__ __forceinline__ void gload16(const void* g, void* l) {
  __builtin_amdgcn_global_load_lds((const __attribute__((address_space(1))) void*)g,
                                   (__attribute__((address_space(3))) void*)l, 16, 0, 0);
}

__device__ __forceinline__ unsigned pkbf16(float lo, float hi) {
  unsigned r;
  asm("v_cvt_pk_bf16_f32 %0, %1, %2" : "=v"(r) : "v"(lo), "v"(hi));
  return r;
}

// raw v_exp_f32 (2^x): exp2f() lowers to OCML multi-instr; this is 1 VALU op.
__device__ __forceinline__ float fexp2(float x) {
  float r;
  asm("v_exp_f32 %0, %1" : "=v"(r) : "v"(x));
  return r;
}

__device__ __forceinline__ float max3f(float a, float b, float c) {
  return fmaxf(fmaxf(a, b), c);  // fuses to v_max3_f32
}

// ---------------------------------------------------------------------------
// f32 -> bf16 conversion, all 6 weight matrices in ONE launch.
// ---------------------------------------------------------------------------
__global__ __launch_bounds__(256) void cvt_all(
    const float* __restrict__ W1, const float* __restrict__ W2,
    const float* __restrict__ Wq, const float* __restrict__ Wk,
    const float* __restrict__ Wv, const float* __restrict__ Wo,
    bf16* __restrict__ w1_b, bf16* __restrict__ w2_b,
    bf16* __restrict__ wqkv, bf16* __restrict__ wo_b) {
  const int bid = blockIdx.x;
  const float* src;
  bf16* dst;
  int lb;
  if (bid < 4096) { src = W1; dst = w1_b; lb = bid; }
  else if (bid < 8192) { src = W2; dst = w2_b; lb = bid - 4096; }
  else {
    const int j = (bid - 8192) >> 10;
    lb = (bid - 8192) & 1023;
    if (j == 0) { src = Wq; dst = wqkv; }
    else if (j == 1) { src = Wk; dst = wqkv + 1048576; }
    else if (j == 2) { src = Wv; dst = wqkv + 2097152; }
    else { src = Wo; dst = wo_b; }
  }
  const int i = (lb * 256 + threadIdx.x) * 4;
  const float4 v = *(const float4*)&src[i];
  dst[i + 0] = __float2bfloat16(v.x);
  dst[i + 1] = __float2bfloat16(v.y);
  dst[i + 2] = __float2bfloat16(v.z);
  dst[i + 3] = __float2bfloat16(v.w);
}

// ---------------------------------------------------------------------------
// LayerNorm over D=1024, fp32 in -> bf16 out. One block (256 thr) per row.
// ---------------------------------------------------------------------------
__global__ __launch_bounds__(256) void layernorm_kernel(
    const float* __restrict__ xin, const float* __restrict__ g,
    const float* __restrict__ bta, bf16* __restrict__ out) {
  const int row = blockIdx.x, t = threadIdx.x;
  const float4 v = *(const float4*)&xin[(size_t)row * D_MODEL + t * 4];
  float s = v.x + v.y + v.z + v.w;
#pragma unroll
  for (int m = 1; m < 64; m <<= 1) s += __shfl_xor(s, m);
  __shared__ float red[4], red2[4];
  const int w = t >> 6, l = t & 63;
  if (l == 0) red[w] = s;
  __syncthreads();
  const float mu = (red[0] + red[1] + red[2] + red[3]) * (1.f / 1024.f);
  const float d0 = v.x - mu, d1 = v.y - mu, d2 = v.z - mu, d3 = v.w - mu;
  float q = d0 * d0 + d1 * d1 + d2 * d2 + d3 * d3;
#pragma unroll
  for (int m = 1; m < 64; m <<= 1) q += __shfl_xor(q, m);
  if (l == 0) red2[w] = q;
  __syncthreads();
  const float var = (red2[0] + red2[1] + red2[2] + red2[3]) * (1.f / 1024.f);
  const float rs = rsqrtf(var + 1e-5f);
  const float4 gg = *(const float4*)&g[t * 4];
  const float4 bb = *(const float4*)&bta[t * 4];
  bf16* o = out + (size_t)row * D_MODEL + t * 4;
  o[0] = __float2bfloat16(d0 * rs * gg.x + bb.x);
  o[1] = __float2bfloat16(d1 * rs * gg.y + bb.y);
  o[2] = __float2bfloat16(d2 * rs * gg.z + bb.z);
  o[3] = __float2bfloat16(d3 * rs * gg.w + bb.w);
}

// ---------------------------------------------------------------------------
// gemmA: BM=256,BN=256,BK=64, 512 thr, 8 waves (2M x 4N), wave tile 128x64.
// 4 phases/K-tile x 16 MFMA. (unchanged)
// ---------------------------------------------------------------------------
template <int MODE>
__global__ __launch_bounds__(512, 2) void gemmA(
    const bf16* __restrict__ A, const bf16* __restrict__ Bw,
    const float* __restrict__ bias0, const float* __restrict__ bias1,
    const float* __restrict__ bias2,
    void* __restrict__ out, int M, int N, int K) {
  constexpr int ASZ = 256 * 128;
  constexpr int TILE = ASZ + 256 * 128;  // 64 KB
  __shared__ __align__(16) char smem[2 * TILE];

  const int t = threadIdx.x;
  const int l = t & 63, l15 = l & 15, l4 = (l >> 4) & 3;
  const int w = t >> 6, wm = w >> 2, wn = w & 3;
  const int gx = gridDim.x;
  const int nwg = gx * gridDim.y;
  const int bid0 = blockIdx.y * gx + blockIdx.x;
  const int bid = (bid0 & 7) * (nwg >> 3) + (bid0 >> 3);
  const int m0 = (bid / gx) * 256, n0 = (bid % gx) * 256;

  const int sr = t >> 3;
  const int scol = 8 * ((t & 7) ^ (sr & 7));
  const int swz = (l15 & 7) << 4;
  int coff[2];
  coff[0] = (l4 * 16) ^ swz;
  coff[1] = (64 + l4 * 16) ^ swz;

#define ST_A(j, kb, buf)                                          \
  gload16(&A[(size_t)(m0 + (j) * 64 + sr) * K + (kb) + scol],     \
          (void*)(smem + (buf) * TILE + (j) * 8192 + t * 16))
#define ST_B(j, kb, buf)                                          \
  gload16(&Bw[(size_t)(n0 + (j) * 64 + sr) * K + (kb) + scol],    \
          (void*)(smem + (buf) * TILE + ASZ + (j) * 8192 + t * 16))

  f32x4 acc[8][4] = {};
  const int NTm = K >> 6;

  ST_A(0, 0, 0); ST_A(2, 0, 0);
  ST_B(0, 0, 0); ST_B(1, 0, 0); ST_B(2, 0, 0); ST_B(3, 0, 0);
  ST_A(1, 0, 0); ST_A(3, 0, 0);
  asm volatile("s_waitcnt vmcnt(2)" ::: "memory");
  __builtin_amdgcn_s_barrier();

#define PHASE_A(p)                                                                 \
  {                                                                                \
    constexpr int kk = (p) & 1;                                                    \
    constexpr int mh = ((p) >> 1) * 4;                                             \
    bf16x8 af[4], bf[4];                                                           \
    _Pragma("unroll") for (int m = 0; m < 4; ++m)                                  \
      af[m] = *(const bf16x8*)(cb + (wm * 128 + (mh + m) * 16 + l15) * 128 +       \
                               coff[kk]);                                          \
    _Pragma("unroll") for (int n = 0; n < 4; ++n)                                  \
      bf[n] = *(const bf16x8*)(cb + ASZ + (wn * 64 + n * 16 + l15) * 128 +         \
                               coff[kk]);                                          \
    if (hasNext) {                                                                 \
      if ((p) == 0) { ST_A(0, kbn, nb); ST_A(2, kbn, nb); }                        \
      else if ((p) == 1) { ST_B(0, kbn, nb); ST_B(1, kbn, nb); }                   \
      else if ((p) == 2) { ST_B(2, kbn, nb); ST_B(3, kbn, nb); }                   \
      else { ST_A(1, kbn, nb); ST_A(3, kbn, nb); }                                 \
    }                                                                              \
    __builtin_amdgcn_s_barrier();                                                  \
    asm volatile("s_waitcnt lgkmcnt(0)" ::: "memory");                             \
    __builtin_amdgcn_sched_barrier(0);                                             \
    __builtin_amdgcn_s_setprio(1);                                                 \
    _Pragma("unroll") for (int m = 0; m < 4; ++m)                                  \
      _Pragma("unroll") for (int n = 0; n < 4; ++n)                                \
        acc[mh + m][n] = __builtin_amdgcn_mfma_f32_16x16x32_bf16(                  \
            af[m], bf[n], acc[mh + m][n], 0, 0, 0);                                \
    __builtin_amdgcn_s_setprio(0);                                                 \
    if ((p) == 1) {                                                                \
      if (hasNext) asm volatile("s_waitcnt vmcnt(4)" ::: "memory");                \
      else asm volatile("s_waitcnt vmcnt(0)" ::: "memory");                        \
    }                                                                              \
    if ((p) == 3 && hasNext)                                                       \
      asm volatile("s_waitcnt vmcnt(2)" ::: "memory");                             \
    __builtin_amdgcn_s_barrier();                                                  \
  }

  for (int kt = 0; kt < NTm; ++kt) {
    const char* cb = smem + (kt & 1) * TILE;
    const int nb = (kt & 1) ^ 1;
    const int kbn = (kt + 1) << 6;
    const bool hasNext = (kt + 1 < NTm);
    PHASE_A(0) PHASE_A(1) PHASE_A(2) PHASE_A(3)
  }
#undef PHASE_A
#undef ST_A
#undef ST_B

#pragma unroll
  for (int mf = 0; mf < 8; ++mf) {
#pragma unroll
    for (int nf = 0; nf < 4; ++nf) {
      const int col = n0 + wn * 64 + nf * 16 + l15;
      float bb;
      if constexpr (MODE == 0) {
        const int sel = col >> 10;
        const float* bp = (sel == 0) ? bias0 : ((sel == 1) ? bias1 : bias2);
        bb = bp[col & 1023];
      } else {
        bb = bias0[col];
      }
#pragma unroll
      for (int r = 0; r < 4; ++r) {
        const int row = m0 + wm * 128 + mf * 16 + l4 * 4 + r;
        float y = acc[mf][nf][r] + bb;
        if constexpr (MODE == 1) y = fmaxf(y, 0.f);
        if constexpr (MODE == 0) {
          const int sel = col >> 10;
          const int c10 = col & 1023;
          const size_t dst = (size_t)sel * (NTOK * 1024) +
                             (size_t)((row >> 11) * NHEAD + (c10 >> 6)) * (SEQ * HEAD_DIM) +
                             (size_t)(row & (SEQ - 1)) * HEAD_DIM + (c10 & 63);
          ((bf16*)out)[dst] = __float2bfloat16(y);
        } else {
          ((bf16*)out)[(size_t)row * N + col] = __float2bfloat16(y);
        }
      }
    }
  }
}

// ---------------------------------------------------------------------------
// gemmB: BM=128,BN=256,BK=64, 512 thr, 8 waves (2M x 4N), wave tile 64x64.
// 2 phases/K-tile x 16 MFMA, 3 LDS buffers, 2-tiles-ahead prefetch.
// (unchanged)
// ---------------------------------------------------------------------------
__global__ __launch_bounds__(512, 2) void gemmB(
    const bf16* __restrict__ A, const bf16* __restrict__ Bw,
    const float* __restrict__ bias, const float* __restrict__ res,
    float* __restrict__ out, int M, int N, int K) {
  constexpr int ASZ = 128 * 128;
  constexpr int TILE = ASZ + 256 * 128;  // 48 KB
  __shared__ __align__(16) char smem[3 * TILE];  // 144 KB

  const int t = threadIdx.x;
  const int l = t & 63, l15 = l & 15, l4 = (l >> 4) & 3;
  const int w = t >> 6, wm = w >> 2, wn = w & 3;
  const int gx = gridDim.x;
  const int nwg = gx * gridDim.y;
  const int bid0 = blockIdx.y * gx + blockIdx.x;
  const int bid = (bid0 & 7) * (nwg >> 3) + (bid0 >> 3);
  const int m0 = (bid / gx) * 128, n0 = (bid % gx) * 256;

  const int sr = t >> 3;
  const int scol = 8 * ((t & 7) ^ (sr & 7));
  const int swz = (l15 & 7) << 4;
  int coff[2];
  coff[0] = (l4 * 16) ^ swz;
  coff[1] = (64 + l4 * 16) ^ swz;

#define ST_A(j, kb, buf)                                          \
  gload16(&A[(size_t)(m0 + (j) * 64 + sr) * K + (kb) + scol],     \
          (void*)(smem + (buf) * TILE + (j) * 8192 + t * 16))
#define ST_B(j, kb, buf)                                          \
  gload16(&Bw[(size_t)(n0 + (j) * 64 + sr) * K + (kb) + scol],    \
          (void*)(smem + (buf) * TILE + ASZ + (j) * 8192 + t * 16))

  f32x4 acc[4][4] = {};
  const int NTm = K >> 6;

  ST_B(0, 0, 0); ST_B(1, 0, 0); ST_B(2, 0, 0);
  ST_B(3, 0, 0); ST_A(0, 0, 0); ST_A(1, 0, 0);
  ST_B(0, 64, 1); ST_B(1, 64, 1); ST_B(2, 64, 1);
  ST_B(3, 64, 1); ST_A(0, 64, 1); ST_A(1, 64, 1);
  asm volatile("s_waitcnt vmcnt(6)" ::: "memory");
  __builtin_amdgcn_s_barrier();

#define PHASE_B(p)                                                                 \
  {                                                                                \
    constexpr int kk = (p);                                                        \
    bf16x8 af[4], bf[4];                                                           \
    _Pragma("unroll") for (int m = 0; m < 4; ++m)                                  \
      af[m] = *(const bf16x8*)(cb + (wm * 64 + m * 16 + l15) * 128 + coff[kk]);    \
    _Pragma("unroll") for (int n = 0; n < 4; ++n)                                  \
      bf[n] = *(const bf16x8*)(cb + ASZ + (wn * 64 + n * 16 + l15) * 128 +         \
                               coff[kk]);                                          \
    if (iss) {                                                                     \
      if ((p) == 0) { ST_B(0, kbn, nb); ST_B(1, kbn, nb); ST_B(2, kbn, nb); }      \
      else { ST_B(3, kbn, nb); ST_A(0, kbn, nb); ST_A(1, kbn, nb); }               \
    }                                                                              \
    __builtin_amdgcn_s_barrier();                                                  \
    asm volatile("s_waitcnt lgkmcnt(0)" ::: "memory");                             \
    __builtin_amdgcn_sched_barrier(0);                                             \
    __builtin_amdgcn_s_setprio(1);                                                 \
    _Pragma("unroll") for (int m = 0; m < 4; ++m)                                  \
      _Pragma("unroll") for (int n = 0; n < 4; ++n)                                \
        acc[m][n] = __builtin_amdgcn_mfma_f32_16x16x32_bf16(                       \
            af[m], bf[n], acc[m][n], 0, 0, 0);                                     \
    __builtin_amdgcn_s_setprio(0);                                                 \
    if ((p) == 1) {                                                                \
      if (iss) asm volatile("s_waitcnt vmcnt(6)" ::: "memory");                    \
      else asm volatile("s_waitcnt vmcnt(0)" ::: "memory");                        \
    }                                                                              \
    __builtin_amdgcn_s_barrier();                                                  \
  }

  for (int kt = 0; kt < NTm; ++kt) {
    const char* cb = smem + (kt % 3) * TILE;
    const int nb = (kt + 2) % 3;
    const int kbn = (kt + 2) << 6;
    const bool iss = (kt + 2 < NTm);
    PHASE_B(0) PHASE_B(1)
  }
#undef PHASE_B
#undef ST_A
#undef ST_B

#pragma unroll
  for (int mf = 0; mf < 4; ++mf) {
#pragma unroll
    for (int nf = 0; nf < 4; ++nf) {
      const int col = n0 + wn * 64 + nf * 16 + l15;
      const float bb = bias[col];
#pragma unroll
      for (int r = 0; r < 4; ++r) {
        const int row = m0 + wm * 64 + mf * 16 + l4 * 4 + r;
        out[(size_t)row * N + col] = acc[mf][nf][r] + bb + res[(size_t)row * N + col];
      }
    }
  }
}

// ---------------------------------------------------------------------------
// Flash attention v7: 512 threads / 8 waves / QBLK=256 (wave keeps 32 q-rows,
// per-wave code identical to v6). Grid 512 blocks = exactly 2 blocks/CU, all
// co-resident; system barrier-rounds halve (32K -> 16K); K-stage = 1
// global_load_lds/thread, V-gather = 8 loads/thread.
// ---------------------------------------------------------------------------
#define SCL 0.18033688011112042f  // 0.125 * log2(e)
#define NT (SEQ / 64)

__global__ __launch_bounds__(512) void flash_attn(
    const bf16* __restrict__ Q, const bf16* __restrict__ K,
    const bf16* __restrict__ V, bf16* __restrict__ O) {
  __shared__ char smem[32768];  // K dbuf @0..16K, Vt dbuf @16K..32K
  const int t = threadIdx.x;
  const int w = t >> 6, l = t & 63;
  const int l15 = l & 15, l4 = l >> 4;
  // XCD swizzle over 512 blocks (512 % 8 == 0)
  const int bid0 = blockIdx.y * 8 + blockIdx.x;
  const int bid = (bid0 & 7) * 64 + (bid0 >> 3);
  const int bx = bid & 7, bh = bid >> 3;
  const size_t base = (size_t)bh * (SEQ * HEAD_DIM);
  const int q0 = bx * 256 + w * 32;

  int krow[4], kswz[4];
#pragma unroll
  for (int ni = 0; ni < 4; ++ni) {
    const int kr = (ni >> 1) * 32 + (ni & 1) * 4 + (l15 >> 2) * 8 + (l15 & 3);
    krow[ni] = kr * 128;
    kswz[ni] = ((kr & 3) | (((kr >> 3) & 1) << 2)) << 4;
  }

  bf16x8 qf[2][2];
#pragma unroll
  for (int mi = 0; mi < 2; ++mi)
#pragma unroll
    for (int kk = 0; kk < 2; ++kk)
      qf[mi][kk] = *(const bf16x8*)&Q[base + (size_t)(q0 + mi * 16 + l15) * 64 + kk * 32 + l4 * 8];

  bf16x8 ones;
#pragma unroll
  for (int j = 0; j < 8; ++j) ones[j] = (short)0x3F80;  // bf16 1.0

  f32x4 accO[2][4] = {};
  float m_run[2], l_run[2];
#pragma unroll
  for (int mi = 0; mi < 2; ++mi) { m_run[mi] = -1e30f; l_run[mi] = 0.f; }

  short vg[8];

  // staging geometry (512 threads):
  // K: thread t covers row r0 = t>>3, 16B chunk (t&7) with inverse swizzle.
  // V: thread t covers d-column dv = t&63, k = kb8..kb8+7 where kb8 = (t>>6)*8.
  const int r0 = t >> 3;
  const int c0 = 8 * ((t & 7) ^ ((r0 & 3) | (((r0 >> 3) & 1) << 2)));
  const short* kg = (const short*)K + base + r0 * 64 + c0;
  const int dv = t & 63;
  const int kb8 = (t >> 6) * 8;
  const short* vp = (const short*)V + base + (size_t)kb8 * 64 + dv;
  const int vtbyte = dv * 128 + ((kb8 * 2) ^ ((dv & 7) << 4));

#define STAGE_K(bufofs)                                          \
  {                                                              \
    gload16(kg, (void*)(smem + (bufofs) + w * 1024));            \
    kg += 4096;                                                  \
  }

#define V_GATHER()                                               \
  {                                                              \
    _Pragma("unroll") for (int j_ = 0; j_ < 8; ++j_)             \
        vg[j_] = vp[j_ * 64];                                    \
    vp += 4096;                                                  \
  }

#define VT_WRITE(bufofs)                                         \
  {                                                              \
    bf16x8 vv;                                                   \
    _Pragma("unroll") for (int j_ = 0; j_ < 8; ++j_)             \
        vv[j_] = vg[j_];                                         \
    *(bf16x8*)(smem + (bufofs) + vtbyte) = vv;                   \
  }

  STAGE_K(0);
  V_GATHER();
  VT_WRITE(16384);
  __syncthreads();

  for (int it = 0; it < NT; ++it) {
    const int cur = it & 1;
    const char* Kb = (const char*)smem + cur * 8192;
    const char* Vb = (const char*)smem + 16384 + cur * 8192;
    const bool pre = (it + 1 < NT);
    if (pre) {
      STAGE_K((cur ^ 1) * 8192);
      V_GATHER();
    }

    // ---- QK^T (swapped) + softmax ----
    bf16x8 kf[2][4];
#pragma unroll
    for (int kk = 0; kk < 2; ++kk)
#pragma unroll
      for (int ni = 0; ni < 4; ++ni)
        kf[kk][ni] = *(const bf16x8*)(Kb + krow[ni] + ((kk * 64 + l4 * 16) ^ kswz[ni]));

    unsigned pw[2][8];
#pragma unroll
    for (int mi = 0; mi < 2; ++mi) {
      f32x4 s[4] = {};
      __builtin_amdgcn_s_setprio(1);
#pragma unroll
      for (int kk = 0; kk < 2; ++kk)
#pragma unroll
        for (int ni = 0; ni < 4; ++ni)
          s[ni] = __builtin_amdgcn_mfma_f32_16x16x32_bf16(kf[kk][ni], qf[mi][kk], s[ni], 0, 0, 0);
      __builtin_amdgcn_s_setprio(0);

      // row max: max3 tree over 16 in-lane values + 2 shuffles
      const float t0 = max3f(s[0][0], s[0][1], s[0][2]);
      const float t1 = max3f(s[0][3], s[1][0], s[1][1]);
      const float t2 = max3f(s[1][2], s[1][3], s[2][0]);
      const float t3 = max3f(s[2][1], s[2][2], s[2][3]);
      const float t4 = max3f(s[3][0], s[3][1], s[3][2]);
      float mx = fmaxf(max3f(t1, t2, t3), fmaxf(t4, fmaxf(t0, s[3][3])));
      mx = fmaxf(mx, __shfl_xor(mx, 16));
      mx = fmaxf(mx, __shfl_xor(mx, 32));
      const float mxs = mx * SCL;
      // defer-rescale (T13)
      if (__any(mxs > m_run[mi] + 8.f)) {
        const float mn = fmaxf(m_run[mi], mxs);
        const float c = fexp2(m_run[mi] - mn);
        m_run[mi] = mn;
        l_run[mi] *= c;
#pragma unroll
        for (int ni = 0; ni < 4; ++ni)
#pragma unroll
          for (int r = 0; r < 4; ++r) accO[mi][ni][r] *= c;
      }
#pragma unroll
      for (int ni = 0; ni < 4; ++ni)
#pragma unroll
        for (int r = 0; r < 4; ++r)
          s[ni][r] = fexp2(fmaf(s[ni][r], SCL, -m_run[mi]));
#pragma unroll
      for (int kk = 0; kk < 2; ++kk)
#pragma unroll
        for (int jj = 0; jj < 4; ++jj) {
          const int ni = 2 * kk + (jj >> 1);
          pw[mi][kk * 4 + jj] = pkbf16(s[ni][2 * (jj & 1)], s[ni][2 * (jj & 1) + 1]);
        }
    }

    // ---- PV: O^T += V^T P, rowsum via MFMA-with-ones ----
    f32x4 zz[2] = {};
#pragma unroll
    for (int kk = 0; kk < 2; ++kk) {
      bf16x8 vf[4];
#pragma unroll
      for (int ni = 0; ni < 4; ++ni)
        vf[ni] = *(const bf16x8*)(Vb + (ni * 16 + l15) * 128 +
                                  ((kk * 64 + l4 * 16) ^ ((l15 & 7) << 4)));
#pragma unroll
      for (int mi = 0; mi < 2; ++mi) {
        union { unsigned u[4]; bf16x8 h; } pb;
#pragma unroll
        for (int jj = 0; jj < 4; ++jj) pb.u[jj] = pw[mi][kk * 4 + jj];
        __builtin_amdgcn_s_setprio(1);
#pragma unroll
        for (int ni = 0; ni < 4; ++ni)
          accO[mi][ni] = __builtin_amdgcn_mfma_f32_16x16x32_bf16(vf[ni], pb.h, accO[mi][ni], 0, 0, 0);
        zz[mi] = __builtin_amdgcn_mfma_f32_16x16x32_bf16(ones, pb.h, zz[mi], 0, 0, 0);
        __builtin_amdgcn_s_setprio(0);
      }
    }
#pragma unroll
    for (int mi = 0; mi < 2; ++mi) l_run[mi] += zz[mi][0];

    if (pre) VT_WRITE(16384 + (cur ^ 1) * 8192);
    __syncthreads();
  }

  // ---- epilogue: bounce O^T through LDS (4 KB/wave) for coalesced stores ----
  char* ob = smem + w * 4096;
#pragma unroll
  for (int mi = 0; mi < 2; ++mi) {
    const float inv = 1.f / l_run[mi];
    const int qr = mi * 16 + l15;
    const int sw = (qr & 7) << 4;
#pragma unroll
    for (int ni = 0; ni < 4; ++ni)
#pragma unroll
      for (int rr = 0; rr < 2; ++rr) {
        const unsigned pk = pkbf16(accO[mi][ni][2 * rr] * inv, accO[mi][ni][2 * rr + 1] * inv);
        *(unsigned*)(ob + qr * 128 + ((ni * 32 + l4 * 8 + 4 * rr) ^ sw)) = pk;
      }
  }
  asm volatile("s_waitcnt lgkmcnt(0)" ::: "memory");
  __builtin_amdgcn_sched_barrier(0);

  const int b = bh >> 4, h = bh & 15;
  const int hr = l >> 1, hf = l & 1;
  const size_t orow = ((size_t)b * SEQ + bx * 256 + w * 32 + hr) * D_MODEL + h * HEAD_DIM + hf * 32;
#pragma unroll
  for (int c = 0; c < 4; ++c) {
    bf16x8 vv = *(const bf16x8*)(ob + hr * 128 + (((hf * 64) + c * 16) ^ ((hr & 7) << 4)));
    *(bf16x8*)&O[orow + c * 8] = vv;
  }
}

// ---------------------------------------------------------------------------
extern "C" void kernel_launch(void* const* d_in, const int* in_sizes, int n_in,
                              void* d_out, int out_size, void* d_ws, size_t ws_size,
                              hipStream_t stream) {
  const float* x     = (const float*)d_in[0];
  const float* Wq    = (const float*)d_in[1];
  const float* bq    = (const float*)d_in[2];
  const float* Wk    = (const float*)d_in[3];
  const float* bk    = (const float*)d_in[4];
  const float* Wv    = (const float*)d_in[5];
  const float* bv    = (const float*)d_in[6];
  const float* Wo    = (const float*)d_in[7];
  const float* bo    = (const float*)d_in[8];
  const float* W1    = (const float*)d_in[9];
  const float* b1    = (const float*)d_in[10];
  const float* W2    = (const float*)d_in[11];
  const float* b2    = (const float*)d_in[12];
  const float* ln1_g = (const float*)d_in[13];
  const float* ln1_b = (const float*)d_in[14];
  const float* ln2_g = (const float*)d_in[15];
  const float* ln2_b = (const float*)d_in[16];

  const size_t MB = 1ull << 20;
  char* ws = (char*)d_ws;
  bf16* wqkv = (bf16*)(ws + 0 * MB);    // 6 MB: [Wq;Wk;Wv] rows, K-contig
  bf16* wo_b = (bf16*)(ws + 6 * MB);
  bf16* w1_b = (bf16*)(ws + 8 * MB);    // 8 MB
  bf16* w2_b = (bf16*)(ws + 16 * MB);   // 8 MB
  bf16* xn   = (bf16*)(ws + 24 * MB);   // 16 MB: xn / attn_out / xn2
  bf16* qb   = (bf16*)(ws + 40 * MB);   // 16 MB (q,k,v contiguous)
  bf16* kbuf = (bf16*)(ws + 56 * MB);   // 16 MB
  bf16* vb   = (bf16*)(ws + 72 * MB);   // 16 MB
  bf16* hb   = (bf16*)(ws + 40 * MB);   // 64 MB (reuses q/k/v after attention)
  float* x1  = (float*)(ws + 104 * MB); // 32 MB

  cvt_all<<<12288, 256, 0, stream>>>(W1, W2, Wq, Wk, Wv, Wo, w1_b, w2_b, wqkv, wo_b);

  layernorm_kernel<<<NTOK, 256, 0, stream>>>(x, ln1_g, ln1_b, xn);

  // QKV fused: [8192,3072] = xn @ wqkv^T -> permuted/split q/k/v
  gemmA<0><<<dim3(3072 / 256, NTOK / 256), 512, 0, stream>>>(
      xn, wqkv, bq, bk, bv, qb, NTOK, 3072, 1024);

  flash_attn<<<dim3(SEQ / 256, 4 * NHEAD), 512, 0, stream>>>(qb, kbuf, vb, xn);

  // Wo + residual(x) -> x1 (fp32)
  gemmB<<<dim3(1024 / 256, NTOK / 128), 512, 0, stream>>>(
      xn, wo_b, bo, x, x1, NTOK, 1024, 1024);

  layernorm_kernel<<<NTOK, 256, 0, stream>>>(x1, ln2_g, ln2_b, xn);

  // FFN1 (ReLU) -> hb
  gemmA<1><<<dim3(D_FF / 256, NTOK / 256), 512, 0, stream>>>(
      xn, w1_b, b1, b1, b1, hb, NTOK, D_FF, 1024);

  // FFN2 + residual(x1) -> d_out (fp32)
  gemmB<<<dim3(1024 / 256, NTOK / 128), 512, 0, stream>>>(
      hb, w2_b, b2, x1, (float*)d_out, NTOK, 1024, D_FF);
}